// Round 1
// baseline (1143.842 us; speedup 1.0000x reference)
//
#include <hip/hip_runtime.h>
#include <math.h>

#define D 128
#define ED 64
#define HD 32

// ---------- CSR build ----------
__global__ __launch_bounds__(256)
void count_kernel(const int* __restrict__ dst, int* __restrict__ cnt, int E) {
  int e = blockIdx.x * 256 + threadIdx.x;
  if (e < E) atomicAdd(&cnt[dst[e]], 1);
}

__global__ __launch_bounds__(1024)
void scan_kernel(const int* __restrict__ cnt, int* __restrict__ rowptr, int n) {
  __shared__ int part[1024];
  int t = threadIdx.x;
  int chunk = (n + 1023) >> 10;
  int b = t * chunk, e = min(b + chunk, n);
  int s = 0;
  for (int i = b; i < e; ++i) s += cnt[i];
  part[t] = s;
  __syncthreads();
  for (int off = 1; off < 1024; off <<= 1) {
    int add = (t >= off) ? part[t - off] : 0;
    __syncthreads();
    part[t] += add;
    __syncthreads();
  }
  int run = part[t] - s;
  for (int i = b; i < e; ++i) { rowptr[i] = run; run += cnt[i]; }
  if (t == 1023) rowptr[n] = part[1023];
}

__global__ __launch_bounds__(256)
void fill_kernel(const int* __restrict__ dst, const int* __restrict__ rowptr,
                 int* __restrict__ cursor, int* __restrict__ eorder, int E) {
  int e = blockIdx.x * 256 + threadIdx.x;
  if (e < E) {
    int d = dst[e];
    int p = atomicAdd(&cursor[d], 1);
    eorder[rowptr[d] + p] = e;
  }
}

// ---------- M[d,h] = sum_c We[d, h*C+c] * ae[h,c] ----------
template<int H>
__global__ void prep_M_kernel(const float* __restrict__ We, const float* __restrict__ ae,
                              float* __restrict__ M) {
  constexpr int C = D / H;
  int t = threadIdx.x;
  if (t < HD * H) {
    int d = t / H, h = t - d * H;
    float s = 0.f;
    for (int c = 0; c < C; ++c) s += We[d * D + h * C + c] * ae[h * C + c];
    M[d * H + h] = s;
  }
}

// ---------- xs = x @ W  (fp32, W in LDS, x broadcast via readlane shuffles) ----------
__global__ __launch_bounds__(256)
void node_gemm_kernel(const float* __restrict__ x, const float* __restrict__ W,
                      float* __restrict__ xs, int n) {
  __shared__ float Wl[D * D];
  int t = threadIdx.x;
  for (int i = t; i < D * D; i += 256) Wl[i] = W[i];
  __syncthreads();
  int lane = t & 63;
  int w = t >> 6;                 // wave in block: 0..3
  int nsub = w >> 1;              // node within pair
  int c = lane + 64 * (w & 1);    // output channel
  for (int n0 = blockIdx.x * 2; n0 < n; n0 += gridDim.x * 2) {
    int node = n0 + nsub;
    if (node >= n) continue;      // wave-uniform, no barrier in loop
    float xa = x[(size_t)node * D + lane];
    float xb = x[(size_t)node * D + 64 + lane];
    float acc = 0.f;
#pragma unroll
    for (int k = 0; k < 64; ++k) acc = fmaf(__shfl(xa, k), Wl[k * D + c], acc);
#pragma unroll
    for (int k = 0; k < 64; ++k) acc = fmaf(__shfl(xb, k), Wl[(64 + k) * D + c], acc);
    xs[(size_t)node * D + c] = acc;
  }
}

// ---------- per-node attention logits + order score ----------
template<int H>
__global__ __launch_bounds__(256)
void node_al_kernel(const float* __restrict__ xs, const float* __restrict__ x,
                    const float* __restrict__ a_s, const float* __restrict__ a_d,
                    const float* __restrict__ ow, const float* __restrict__ ob,
                    float* __restrict__ al_src, float* __restrict__ al_dst,
                    float* __restrict__ escore, int n) {
  int wid = blockIdx.x * 4 + (threadIdx.x >> 6);
  int lane = threadIdx.x & 63;
  if (wid >= n) return;
  float x0 = xs[(size_t)wid * D + lane], x1 = xs[(size_t)wid * D + 64 + lane];
  float s0 = x0 * a_s[lane], s1 = x1 * a_s[64 + lane];
  float d0 = x0 * a_d[lane], d1 = x1 * a_d[64 + lane];
  float xr0 = x[(size_t)wid * D + lane], xr1 = x[(size_t)wid * D + 64 + lane];
  float sc = xr0 * ow[lane] + xr1 * ow[64 + lane];
#pragma unroll
  for (int off = 32; off >= 1; off >>= 1) sc += __shfl_xor(sc, off);
  if (H == 4) {
#pragma unroll
    for (int off = 16; off >= 1; off >>= 1) {
      s0 += __shfl_xor(s0, off); s1 += __shfl_xor(s1, off);
      d0 += __shfl_xor(d0, off); d1 += __shfl_xor(d1, off);
    }
    if (lane == 0) {
      al_src[wid * 4 + 0] = s0; al_src[wid * 4 + 2] = s1;
      al_dst[wid * 4 + 0] = d0; al_dst[wid * 4 + 2] = d1;
    } else if (lane == 32) {
      al_src[wid * 4 + 1] = s0; al_src[wid * 4 + 3] = s1;
      al_dst[wid * 4 + 1] = d0; al_dst[wid * 4 + 3] = d1;
    }
  } else {
    float sa = s0 + s1, da = d0 + d1;
#pragma unroll
    for (int off = 32; off >= 1; off >>= 1) { sa += __shfl_xor(sa, off); da += __shfl_xor(da, off); }
    if (lane == 0) { al_src[wid] = sa; al_dst[wid] = da; }
  }
  if (lane == 0) escore[wid] = expf(sc + ob[0]);
}

// ---------- per-edge: te, al_e, exp(alpha); accumulate den & sum_ale ----------
template<int H>
__global__ __launch_bounds__(256)
void edge_kernel(const int* __restrict__ src, const int* __restrict__ dst,
                 const float* __restrict__ ea, const float* __restrict__ ew,
                 const float* __restrict__ eb, const float* __restrict__ M,
                 const float* __restrict__ al_src, const float* __restrict__ al_dst,
                 const float* __restrict__ escore,
                 float* __restrict__ exv, float* __restrict__ den,
                 float* __restrict__ sum_ale, int E) {
  __shared__ float ewl[ED * HD];
  __shared__ float ebl[HD];
  __shared__ float Ml[HD * H];
  int t = threadIdx.x;
  for (int i = t; i < ED * HD; i += 256) ewl[i] = ew[i];
  if (t < HD) ebl[t] = eb[t];
  if (t < HD * H) Ml[t] = M[t];
  __syncthreads();
  for (int e = blockIdx.x * 256 + t; e < E; e += gridDim.x * 256) {
    int s = src[e], d = dst[e];
    float esc = escore[s];
    float te[HD];
#pragma unroll
    for (int j = 0; j < HD; ++j) te[j] = ebl[j];
    const float4* ea4 = (const float4*)(ea + (size_t)e * ED);
    for (int k4 = 0; k4 < ED / 4; ++k4) {
      float4 v = ea4[k4];
      const float* w0 = &ewl[(k4 * 4 + 0) * HD];
      const float* w1 = &ewl[(k4 * 4 + 1) * HD];
      const float* w2 = &ewl[(k4 * 4 + 2) * HD];
      const float* w3 = &ewl[(k4 * 4 + 3) * HD];
#pragma unroll
      for (int j = 0; j < HD; ++j)
        te[j] += v.x * w0[j] + v.y * w1[j] + v.z * w2[j] + v.w * w3[j];
    }
#pragma unroll
    for (int j = 0; j < HD; ++j) { float v = te[j]; te[j] = (v > 0.f ? v : 0.f) * esc; }
    float ale[H];
#pragma unroll
    for (int h = 0; h < H; ++h) {
      float a = 0.f;
#pragma unroll
      for (int j = 0; j < HD; ++j) a += te[j] * Ml[j * H + h];
      ale[h] = a;
    }
#pragma unroll
    for (int h = 0; h < H; ++h) {
      float a = al_src[(size_t)s * H + h] + al_dst[(size_t)d * H + h] + ale[h];
      float lr = a > 0.f ? a : 0.2f * a;
      float ev = expf(lr);
      exv[(size_t)e * H + h] = ev;
      atomicAdd(&den[(size_t)d * H + h], ev);
      atomicAdd(&sum_ale[(size_t)d * H + h], ale[h]);
    }
  }
}

// ---------- self-loop term + inverse denominator ----------
template<int H>
__global__ __launch_bounds__(256)
void loop_kernel(const int* __restrict__ cnt,
                 const float* __restrict__ al_src, const float* __restrict__ al_dst,
                 const float* __restrict__ sum_ale, const float* __restrict__ den,
                 float* __restrict__ exl, float* __restrict__ dinv, int n) {
  int i = blockIdx.x * 256 + threadIdx.x;
  if (i >= n * H) return;
  int node = i / H;
  int c = cnt[node];
  float cf = (float)(c > 1 ? c : 1);
  float al = sum_ale[i] / cf;
  float a = al_src[i] + al_dst[i] + al;
  float lr = a > 0.f ? a : 0.2f * a;
  float ev = expf(lr);
  exl[i] = ev;
  dinv[i] = 1.f / (den[i] + ev + 1e-16f);
}

// ---------- CSR aggregation + bias + residual (+relu / +orig) ----------
template<int H, bool RELU, bool ADD_ORIG>
__global__ __launch_bounds__(256)
void agg_kernel(const int* __restrict__ rowptr, const int* __restrict__ eorder,
                const int* __restrict__ src,
                const float* __restrict__ xs, const float* __restrict__ exv,
                const float* __restrict__ exl, const float* __restrict__ dinv,
                const float* __restrict__ bias, const float* __restrict__ xin,
                const float* __restrict__ orig, float* __restrict__ out, int n) {
  constexpr int C = D / H;
  int wid = blockIdx.x * 4 + (threadIdx.x >> 6);
  int lane = threadIdx.x & 63;
  if (wid >= n) return;
  int h0 = (2 * lane) / C;  // both channels of this lane share a head (C even)
  float di = dinv[(size_t)wid * H + h0];
  const float2* xs2 = (const float2*)xs;
  float ax = 0.f, ay = 0.f;
  int b = rowptr[wid], e = rowptr[wid + 1];
  for (int idx = b; idx < e; ++idx) {
    int ed = eorder[idx];
    int s = src[ed];
    float coef = exv[(size_t)ed * H + h0] * di;
    float2 v = xs2[(size_t)s * 64 + lane];
    ax = fmaf(coef, v.x, ax); ay = fmaf(coef, v.y, ay);
  }
  {
    float coef = exl[(size_t)wid * H + h0] * di;
    float2 v = xs2[(size_t)wid * 64 + lane];
    ax = fmaf(coef, v.x, ax); ay = fmaf(coef, v.y, ay);
  }
  float2 bi = ((const float2*)bias)[lane];
  float2 xi = ((const float2*)xin)[(size_t)wid * 64 + lane];
  ax += bi.x + xi.x; ay += bi.y + xi.y;
  if (ADD_ORIG) {
    float2 og = ((const float2*)orig)[(size_t)wid * 64 + lane];
    ax += og.x; ay += og.y;
  }
  if (RELU) { ax = fmaxf(ax, 0.f); ay = fmaxf(ay, 0.f); }
  ((float2*)out)[(size_t)wid * 64 + lane] = make_float2(ax, ay);
}

extern "C" void kernel_launch(void* const* d_in, const int* in_sizes, int n_in,
                              void* d_out, int out_size, void* d_ws, size_t ws_size,
                              hipStream_t stream) {
  const float* x   = (const float*)d_in[0];
  const int*   ei  = (const int*)d_in[1];
  const float* ea  = (const float*)d_in[2];
  const float* ew0 = (const float*)d_in[3];
  const float* eb0 = (const float*)d_in[4];
  const float* ew1 = (const float*)d_in[5];
  const float* eb1 = (const float*)d_in[6];
  const float* ow0 = (const float*)d_in[7];
  const float* ob0 = (const float*)d_in[8];
  const float* ow1 = (const float*)d_in[9];
  const float* ob1 = (const float*)d_in[10];
  const float* g0W = (const float*)d_in[11];
  const float* g0as= (const float*)d_in[12];
  const float* g0ad= (const float*)d_in[13];
  const float* g0We= (const float*)d_in[14];
  const float* g0ae= (const float*)d_in[15];
  const float* g0b = (const float*)d_in[16];
  const float* g1W = (const float*)d_in[17];
  const float* g1as= (const float*)d_in[18];
  const float* g1ad= (const float*)d_in[19];
  const float* g1We= (const float*)d_in[20];
  const float* g1ae= (const float*)d_in[21];
  const float* g1b = (const float*)d_in[22];
  float* out = (float*)d_out;

  const int N = in_sizes[0] / D;
  const int E = in_sizes[1] / 2;
  const int* srcp = ei;
  const int* dstp = ei + E;

  char* w = (char*)d_ws;
  size_t off = 0;
  auto alloc = [&](size_t bytes) {
    void* p = w + off;
    off += (bytes + 255) & ~(size_t)255;
    return p;
  };
  float* xs      = (float*)alloc((size_t)N * D * 4);
  float* exv     = (float*)alloc((size_t)E * 4 * 4);
  float* al_src  = (float*)alloc((size_t)N * 4 * 4);
  float* al_dst  = (float*)alloc((size_t)N * 4 * 4);
  float* escore  = (float*)alloc((size_t)N * 4);
  float* sum_ale = (float*)alloc((size_t)N * 4 * 4);
  float* den     = (float*)alloc((size_t)N * 4 * 4);
  float* exl     = (float*)alloc((size_t)N * 4 * 4);
  float* dinv    = (float*)alloc((size_t)N * 4 * 4);
  float* M0      = (float*)alloc(HD * 4 * 4);
  float* M1      = (float*)alloc(HD * 4);
  int*   cnt     = (int*)alloc((size_t)N * 4);
  int*   rowptr  = (int*)alloc((size_t)(N + 1) * 4);
  int*   cursor  = (int*)alloc((size_t)N * 4);
  int*   eorder  = (int*)alloc((size_t)E * 4);

  int egrid  = (E + 255) / 256;
  int ngrid4 = (N + 3) / 4;

  // ---- CSR build (shared by both layers) ----
  hipMemsetAsync(cnt, 0, (size_t)N * 4, stream);
  hipMemsetAsync(cursor, 0, (size_t)N * 4, stream);
  count_kernel<<<egrid, 256, 0, stream>>>(dstp, cnt, E);
  scan_kernel<<<1, 1024, 0, stream>>>(cnt, rowptr, N);
  fill_kernel<<<egrid, 256, 0, stream>>>(dstp, rowptr, cursor, eorder, E);
  prep_M_kernel<4><<<1, 128, 0, stream>>>(g0We, g0ae, M0);
  prep_M_kernel<1><<<1, 32, 0, stream>>>(g1We, g1ae, M1);

  // ---- layer 0 (H=4, C=32), output -> d_out (used as x1) ----
  node_gemm_kernel<<<512, 256, 0, stream>>>(x, g0W, xs, N);
  node_al_kernel<4><<<ngrid4, 256, 0, stream>>>(xs, x, g0as, g0ad, ow0, ob0,
                                                al_src, al_dst, escore, N);
  hipMemsetAsync(den, 0, (size_t)N * 4 * 4, stream);
  hipMemsetAsync(sum_ale, 0, (size_t)N * 4 * 4, stream);
  edge_kernel<4><<<egrid, 256, 0, stream>>>(srcp, dstp, ea, ew0, eb0, M0,
                                            al_src, al_dst, escore,
                                            exv, den, sum_ale, E);
  loop_kernel<4><<<(N * 4 + 255) / 256, 256, 0, stream>>>(cnt, al_src, al_dst,
                                                          sum_ale, den, exl, dinv, N);
  agg_kernel<4, true, false><<<ngrid4, 256, 0, stream>>>(rowptr, eorder, srcp,
                                                         xs, exv, exl, dinv,
                                                         g0b, x, nullptr, out, N);

  // ---- layer 1 (H=1, C=128), input = d_out, output = d_out (+original x) ----
  node_gemm_kernel<<<512, 256, 0, stream>>>(out, g1W, xs, N);
  node_al_kernel<1><<<ngrid4, 256, 0, stream>>>(xs, out, g1as, g1ad, ow1, ob1,
                                                al_src, al_dst, escore, N);
  hipMemsetAsync(den, 0, (size_t)N * 4, stream);
  hipMemsetAsync(sum_ale, 0, (size_t)N * 4, stream);
  edge_kernel<1><<<egrid, 256, 0, stream>>>(srcp, dstp, ea, ew1, eb1, M1,
                                            al_src, al_dst, escore,
                                            exv, den, sum_ale, E);
  loop_kernel<1><<<(N + 255) / 256, 256, 0, stream>>>(cnt, al_src, al_dst,
                                                      sum_ale, den, exl, dinv, N);
  agg_kernel<1, false, true><<<ngrid4, 256, 0, stream>>>(rowptr, eorder, srcp,
                                                         xs, exv, exl, dinv,
                                                         g1b, out, x, out, N);
}

// Round 2
// 871.916 us; speedup vs baseline: 1.3119x; 1.3119x over previous
//
#include <hip/hip_runtime.h>
#include <math.h>

#define D 128
#define ED 64
#define HD 32

// ---------- CSR build ----------
__global__ __launch_bounds__(256)
void count_kernel(const int* __restrict__ dst, int* __restrict__ cnt, int E) {
  int e = blockIdx.x * 256 + threadIdx.x;
  if (e < E) atomicAdd(&cnt[dst[e]], 1);
}

__global__ __launch_bounds__(1024)
void scan_kernel(const int* __restrict__ cnt, int* __restrict__ rowptr, int n) {
  __shared__ int part[1024];
  int t = threadIdx.x;
  int chunk = (n + 1023) >> 10;
  int b = t * chunk, e = min(b + chunk, n);
  int s = 0;
  for (int i = b; i < e; ++i) s += cnt[i];
  part[t] = s;
  __syncthreads();
  for (int off = 1; off < 1024; off <<= 1) {
    int add = (t >= off) ? part[t - off] : 0;
    __syncthreads();
    part[t] += add;
    __syncthreads();
  }
  int run = part[t] - s;
  for (int i = b; i < e; ++i) { rowptr[i] = run; run += cnt[i]; }
  if (t == 1023) rowptr[n] = part[1023];
}

// fill: perm[e] = CSR slot of edge e; src_ord[slot] = src[e]
__global__ __launch_bounds__(256)
void fill_kernel(const int* __restrict__ src, const int* __restrict__ dst,
                 const int* __restrict__ rowptr, int* __restrict__ cursor,
                 int* __restrict__ perm, int* __restrict__ src_ord, int E) {
  int e = blockIdx.x * 256 + threadIdx.x;
  if (e < E) {
    int d = dst[e];
    int p = atomicAdd(&cursor[d], 1);
    int slot = rowptr[d] + p;
    perm[e] = slot;
    src_ord[slot] = src[e];
  }
}

// ---------- M[d,h] = sum_c We[d, h*C+c] * ae[h,c] ----------
template<int H>
__global__ void prep_M_kernel(const float* __restrict__ We, const float* __restrict__ ae,
                              float* __restrict__ M) {
  constexpr int C = D / H;
  int t = threadIdx.x;
  if (t < HD * H) {
    int d = t / H, h = t - d * H;
    float s = 0.f;
    for (int c = 0; c < C; ++c) s += We[d * D + h * C + c] * ae[h * C + c];
    M[d * H + h] = s;
  }
}

// ---------- xs = x @ W  (fp32, W in LDS, x broadcast via readlane shuffles) ----------
__global__ __launch_bounds__(256)
void node_gemm_kernel(const float* __restrict__ x, const float* __restrict__ W,
                      float* __restrict__ xs, int n) {
  __shared__ float Wl[D * D];
  int t = threadIdx.x;
  for (int i = t; i < D * D; i += 256) Wl[i] = W[i];
  __syncthreads();
  int lane = t & 63;
  int w = t >> 6;                 // wave in block: 0..3
  int nsub = w >> 1;              // node within pair
  int c = lane + 64 * (w & 1);    // output channel
  for (int n0 = blockIdx.x * 2; n0 < n; n0 += gridDim.x * 2) {
    int node = n0 + nsub;
    if (node >= n) continue;      // wave-uniform, no barrier in loop
    float xa = x[(size_t)node * D + lane];
    float xb = x[(size_t)node * D + 64 + lane];
    float acc = 0.f;
#pragma unroll
    for (int k = 0; k < 64; ++k) acc = fmaf(__shfl(xa, k), Wl[k * D + c], acc);
#pragma unroll
    for (int k = 0; k < 64; ++k) acc = fmaf(__shfl(xb, k), Wl[(64 + k) * D + c], acc);
    xs[(size_t)node * D + c] = acc;
  }
}

// ---------- per-node attention logits + order score ----------
template<int H>
__global__ __launch_bounds__(256)
void node_al_kernel(const float* __restrict__ xs, const float* __restrict__ x,
                    const float* __restrict__ a_s, const float* __restrict__ a_d,
                    const float* __restrict__ ow, const float* __restrict__ ob,
                    float* __restrict__ al_src, float* __restrict__ al_dst,
                    float* __restrict__ escore, int n) {
  int wid = blockIdx.x * 4 + (threadIdx.x >> 6);
  int lane = threadIdx.x & 63;
  if (wid >= n) return;
  float x0 = xs[(size_t)wid * D + lane], x1 = xs[(size_t)wid * D + 64 + lane];
  float s0 = x0 * a_s[lane], s1 = x1 * a_s[64 + lane];
  float d0 = x0 * a_d[lane], d1 = x1 * a_d[64 + lane];
  float xr0 = x[(size_t)wid * D + lane], xr1 = x[(size_t)wid * D + 64 + lane];
  float sc = xr0 * ow[lane] + xr1 * ow[64 + lane];
#pragma unroll
  for (int off = 32; off >= 1; off >>= 1) sc += __shfl_xor(sc, off);
  if (H == 4) {
#pragma unroll
    for (int off = 16; off >= 1; off >>= 1) {
      s0 += __shfl_xor(s0, off); s1 += __shfl_xor(s1, off);
      d0 += __shfl_xor(d0, off); d1 += __shfl_xor(d1, off);
    }
    if (lane == 0) {
      al_src[wid * 4 + 0] = s0; al_src[wid * 4 + 2] = s1;
      al_dst[wid * 4 + 0] = d0; al_dst[wid * 4 + 2] = d1;
    } else if (lane == 32) {
      al_src[wid * 4 + 1] = s0; al_src[wid * 4 + 3] = s1;
      al_dst[wid * 4 + 1] = d0; al_dst[wid * 4 + 3] = d1;
    }
  } else {
    float sa = s0 + s1, da = d0 + d1;
#pragma unroll
    for (int off = 32; off >= 1; off >>= 1) { sa += __shfl_xor(sa, off); da += __shfl_xor(da, off); }
    if (lane == 0) { al_src[wid] = sa; al_dst[wid] = da; }
  }
  if (lane == 0) escore[wid] = expf(sc + ob[0]);
}

// ---------- per-edge: te -> ale, exp(alpha); scatter into dst-order. NO atomics ----------
template<int H>
__global__ __launch_bounds__(256)
void edge_kernel(const int* __restrict__ src, const int* __restrict__ dst,
                 const float* __restrict__ ea, const float* __restrict__ ew,
                 const float* __restrict__ eb, const float* __restrict__ M,
                 const float* __restrict__ al_src, const float* __restrict__ al_dst,
                 const float* __restrict__ escore, const int* __restrict__ perm,
                 float* __restrict__ exv, float* __restrict__ alev, int E) {
  __shared__ float ewl[ED * HD];
  __shared__ float ebl[HD];
  __shared__ float Ml[HD * H];
  int t = threadIdx.x;
  for (int i = t; i < ED * HD; i += 256) ewl[i] = ew[i];
  if (t < HD) ebl[t] = eb[t];
  if (t < HD * H) Ml[t] = M[t];
  __syncthreads();
  for (int e = blockIdx.x * 256 + t; e < E; e += gridDim.x * 256) {
    int s = src[e], d = dst[e];
    float esc = escore[s];
    float te[HD];
#pragma unroll
    for (int j = 0; j < HD; ++j) te[j] = ebl[j];
    const float4* ea4 = (const float4*)(ea + (size_t)e * ED);
    for (int k4 = 0; k4 < ED / 4; ++k4) {
      float4 v = ea4[k4];
      const float* w0 = &ewl[(k4 * 4 + 0) * HD];
      const float* w1 = &ewl[(k4 * 4 + 1) * HD];
      const float* w2 = &ewl[(k4 * 4 + 2) * HD];
      const float* w3 = &ewl[(k4 * 4 + 3) * HD];
#pragma unroll
      for (int j = 0; j < HD; ++j)
        te[j] += v.x * w0[j] + v.y * w1[j] + v.z * w2[j] + v.w * w3[j];
    }
#pragma unroll
    for (int j = 0; j < HD; ++j) { float v = te[j]; te[j] = (v > 0.f ? v : 0.f) * esc; }
    float ale[H], ev[H];
#pragma unroll
    for (int h = 0; h < H; ++h) {
      float a = 0.f;
#pragma unroll
      for (int j = 0; j < HD; ++j) a += te[j] * Ml[j * H + h];
      ale[h] = a;
    }
#pragma unroll
    for (int h = 0; h < H; ++h) {
      float a = al_src[(size_t)s * H + h] + al_dst[(size_t)d * H + h] + ale[h];
      float lr = a > 0.f ? a : 0.2f * a;
      ev[h] = expf(lr);
    }
    size_t p = (size_t)perm[e] * H;
    if (H == 4) {
      *(float4*)(exv + p)  = make_float4(ev[0], ev[1], ev[2], ev[3]);
      *(float4*)(alev + p) = make_float4(ale[0], ale[1], ale[2], ale[3]);
    } else {
      exv[p] = ev[0];
      alev[p] = ale[0];
    }
  }
}

// ---------- CSR aggregation + online den/sum_ale + self-loop + bias + residual ----------
template<int H, bool RELU, bool ADD_ORIG>
__global__ __launch_bounds__(256)
void agg_kernel(const int* __restrict__ rowptr, const int* __restrict__ src_ord,
                const float* __restrict__ xs, const float* __restrict__ exv,
                const float* __restrict__ alev,
                const float* __restrict__ al_src, const float* __restrict__ al_dst,
                const float* __restrict__ bias, const float* __restrict__ xin,
                const float* __restrict__ orig, float* __restrict__ out, int n) {
  constexpr int C = D / H;
  int wid = blockIdx.x * 4 + (threadIdx.x >> 6);
  int lane = threadIdx.x & 63;
  if (wid >= n) return;
  int h0 = (2 * lane) / C;  // both channels of this lane share a head (C even)
  const float2* xs2 = (const float2*)xs;
  float ax = 0.f, ay = 0.f, den = 0.f, sale = 0.f;
  int b = rowptr[wid], e = rowptr[wid + 1];
  for (int idx = b; idx < e; ++idx) {
    int s = src_ord[idx];
    float ev = exv[(size_t)idx * H + h0];
    float al = alev[(size_t)idx * H + h0];
    float2 v = xs2[(size_t)s * 64 + lane];
    ax = fmaf(ev, v.x, ax); ay = fmaf(ev, v.y, ay);
    den += ev; sale += al;
  }
  // self-loop: attr = mean of incoming ale (linear in attr)
  int deg = e - b;
  float la = sale / (float)(deg > 1 ? deg : 1);
  float a = al_src[(size_t)wid * H + h0] + al_dst[(size_t)wid * H + h0] + la;
  float lr = a > 0.f ? a : 0.2f * a;
  float evl = expf(lr);
  {
    float2 v = xs2[(size_t)wid * 64 + lane];
    ax = fmaf(evl, v.x, ax); ay = fmaf(evl, v.y, ay);
  }
  float dinv = 1.f / (den + evl + 1e-16f);
  float2 bi = ((const float2*)bias)[lane];
  float2 xi = ((const float2*)xin)[(size_t)wid * 64 + lane];
  ax = ax * dinv + bi.x + xi.x;
  ay = ay * dinv + bi.y + xi.y;
  if (ADD_ORIG) {
    float2 og = ((const float2*)orig)[(size_t)wid * 64 + lane];
    ax += og.x; ay += og.y;
  }
  if (RELU) { ax = fmaxf(ax, 0.f); ay = fmaxf(ay, 0.f); }
  ((float2*)out)[(size_t)wid * 64 + lane] = make_float2(ax, ay);
}

extern "C" void kernel_launch(void* const* d_in, const int* in_sizes, int n_in,
                              void* d_out, int out_size, void* d_ws, size_t ws_size,
                              hipStream_t stream) {
  const float* x   = (const float*)d_in[0];
  const int*   ei  = (const int*)d_in[1];
  const float* ea  = (const float*)d_in[2];
  const float* ew0 = (const float*)d_in[3];
  const float* eb0 = (const float*)d_in[4];
  const float* ew1 = (const float*)d_in[5];
  const float* eb1 = (const float*)d_in[6];
  const float* ow0 = (const float*)d_in[7];
  const float* ob0 = (const float*)d_in[8];
  const float* ow1 = (const float*)d_in[9];
  const float* ob1 = (const float*)d_in[10];
  const float* g0W = (const float*)d_in[11];
  const float* g0as= (const float*)d_in[12];
  const float* g0ad= (const float*)d_in[13];
  const float* g0We= (const float*)d_in[14];
  const float* g0ae= (const float*)d_in[15];
  const float* g0b = (const float*)d_in[16];
  const float* g1W = (const float*)d_in[17];
  const float* g1as= (const float*)d_in[18];
  const float* g1ad= (const float*)d_in[19];
  const float* g1We= (const float*)d_in[20];
  const float* g1ae= (const float*)d_in[21];
  const float* g1b = (const float*)d_in[22];
  float* out = (float*)d_out;

  const int N = in_sizes[0] / D;
  const int E = in_sizes[1] / 2;
  const int* srcp = ei;
  const int* dstp = ei + E;

  char* w = (char*)d_ws;
  size_t off = 0;
  auto alloc = [&](size_t bytes) {
    void* p = w + off;
    off += (bytes + 255) & ~(size_t)255;
    return p;
  };
  float* xs      = (float*)alloc((size_t)N * D * 4);
  float* exv     = (float*)alloc((size_t)E * 4 * 4);
  float* alev    = (float*)alloc((size_t)E * 4 * 4);
  float* al_src  = (float*)alloc((size_t)N * 4 * 4);
  float* al_dst  = (float*)alloc((size_t)N * 4 * 4);
  float* escore  = (float*)alloc((size_t)N * 4);
  float* M0      = (float*)alloc(HD * 4 * 4);
  float* M1      = (float*)alloc(HD * 4);
  int*   cnt     = (int*)alloc((size_t)N * 4);
  int*   rowptr  = (int*)alloc((size_t)(N + 1) * 4);
  int*   cursor  = (int*)alloc((size_t)N * 4);
  int*   perm    = (int*)alloc((size_t)E * 4);
  int*   src_ord = (int*)alloc((size_t)E * 4);

  int egrid  = (E + 255) / 256;
  int ngrid4 = (N + 3) / 4;

  // ---- CSR build (shared by both layers) ----
  hipMemsetAsync(cnt, 0, (size_t)N * 4, stream);
  hipMemsetAsync(cursor, 0, (size_t)N * 4, stream);
  count_kernel<<<egrid, 256, 0, stream>>>(dstp, cnt, E);
  scan_kernel<<<1, 1024, 0, stream>>>(cnt, rowptr, N);
  fill_kernel<<<egrid, 256, 0, stream>>>(srcp, dstp, rowptr, cursor, perm, src_ord, E);
  prep_M_kernel<4><<<1, 128, 0, stream>>>(g0We, g0ae, M0);
  prep_M_kernel<1><<<1, 32, 0, stream>>>(g1We, g1ae, M1);

  // ---- layer 0 (H=4, C=32), output -> d_out (used as x1) ----
  node_gemm_kernel<<<512, 256, 0, stream>>>(x, g0W, xs, N);
  node_al_kernel<4><<<ngrid4, 256, 0, stream>>>(xs, x, g0as, g0ad, ow0, ob0,
                                                al_src, al_dst, escore, N);
  edge_kernel<4><<<egrid, 256, 0, stream>>>(srcp, dstp, ea, ew0, eb0, M0,
                                            al_src, al_dst, escore, perm,
                                            exv, alev, E);
  agg_kernel<4, true, false><<<ngrid4, 256, 0, stream>>>(rowptr, src_ord,
                                                         xs, exv, alev,
                                                         al_src, al_dst,
                                                         g0b, x, nullptr, out, N);

  // ---- layer 1 (H=1, C=128), input = d_out, output = d_out (+original x) ----
  node_gemm_kernel<<<512, 256, 0, stream>>>(out, g1W, xs, N);
  node_al_kernel<1><<<ngrid4, 256, 0, stream>>>(xs, out, g1as, g1ad, ow1, ob1,
                                                al_src, al_dst, escore, N);
  edge_kernel<1><<<egrid, 256, 0, stream>>>(srcp, dstp, ea, ew1, eb1, M1,
                                            al_src, al_dst, escore, perm,
                                            exv, alev, E);
  agg_kernel<1, false, true><<<ngrid4, 256, 0, stream>>>(rowptr, src_ord,
                                                         xs, exv, alev,
                                                         al_src, al_dst,
                                                         g1b, out, x, out, N);
}

// Round 3
// 559.625 us; speedup vs baseline: 2.0439x; 1.5580x over previous
//
#include <hip/hip_runtime.h>
#include <math.h>

#define D 128
#define ED 64
#define HD 32

typedef short s16x8 __attribute__((ext_vector_type(8)));
typedef float f32x4 __attribute__((ext_vector_type(4)));

// f32 -> bf16 bits, round-to-nearest-even
static __device__ inline unsigned short f2b(float f) {
  unsigned int u = __float_as_uint(f);
  unsigned int r = (u + 0x7fff + ((u >> 16) & 1)) >> 16;
  return (unsigned short)r;
}

// ---------- CSR build ----------
__global__ __launch_bounds__(256)
void count_kernel(const int* __restrict__ dst, int* __restrict__ cnt, int E) {
  int e = blockIdx.x * 256 + threadIdx.x;
  if (e < E) atomicAdd(&cnt[dst[e]], 1);
}

__global__ __launch_bounds__(1024)
void scan_kernel(const int* __restrict__ cnt, int* __restrict__ rowptr, int n) {
  __shared__ int part[1024];
  int t = threadIdx.x;
  int chunk = (n + 1023) >> 10;
  int b = t * chunk, e = min(b + chunk, n);
  int s = 0;
  for (int i = b; i < e; ++i) s += cnt[i];
  part[t] = s;
  __syncthreads();
  for (int off = 1; off < 1024; off <<= 1) {
    int add = (t >= off) ? part[t - off] : 0;
    __syncthreads();
    part[t] += add;
    __syncthreads();
  }
  int run = part[t] - s;
  for (int i = b; i < e; ++i) { rowptr[i] = run; run += cnt[i]; }
  if (t == 1023) rowptr[n] = part[1023];
}

// fill: perm[e] = CSR slot of edge e; src_ord[slot] = src[e]
__global__ __launch_bounds__(256)
void fill_kernel(const int* __restrict__ src, const int* __restrict__ dst,
                 const int* __restrict__ rowptr, int* __restrict__ cursor,
                 int* __restrict__ perm, int* __restrict__ src_ord, int E) {
  int e = blockIdx.x * 256 + threadIdx.x;
  if (e < E) {
    int d = dst[e];
    int p = atomicAdd(&cursor[d], 1);
    int slot = rowptr[d] + p;
    perm[e] = slot;
    src_ord[slot] = src[e];
  }
}

// ---------- M[d,h] = sum_c We[d, h*C+c] * ae[h,c] ----------
template<int H>
__global__ void prep_M_kernel(const float* __restrict__ We, const float* __restrict__ ae,
                              float* __restrict__ M) {
  constexpr int C = D / H;
  int t = threadIdx.x;
  if (t < HD * H) {
    int d = t / H, h = t - d * H;
    float s = 0.f;
    for (int c = 0; c < C; ++c) s += We[d * D + h * C + c] * ae[h * C + c];
    M[d * H + h] = s;
  }
}

// ---------- Wt[n][k] = bf16(W[k][n])  (transpose+convert, 128x128) ----------
__global__ __launch_bounds__(256)
void prep_Wt_kernel(const float* __restrict__ W, unsigned short* __restrict__ Wt) {
  int id = blockIdx.x * 256 + threadIdx.x;   // 0..16383
  int nn = id >> 7, k = id & 127;
  Wt[id] = f2b(W[k * D + nn]);
}

// ---------- xs = x @ W via MFMA bf16 (no LDS, no barriers) ----------
// block = 256 thr = 4 waves; each wave: 16 nodes x 128 cols.
// A: row=lane&15, k=(lane>>4)*8+j (f32 loaded, converted in-reg)
// B: col=lane&15, k=(lane>>4)*8+j (16B contiguous from Wt[n][k])
// D: col=lane&15, row=(lane>>4)*4+r
__global__ __launch_bounds__(256)
void node_gemm_mfma(const float* __restrict__ x, const unsigned short* __restrict__ Wt,
                    float* __restrict__ xs, int n) {
  int wave = threadIdx.x >> 6;
  int lane = threadIdx.x & 63;
  int q = lane >> 4;
  int l16 = lane & 15;
  int base = blockIdx.x * 64 + wave * 16;
  int rowRaw = base + l16;
  int row = rowRaw < n ? rowRaw : n - 1;
  const float* xrow = x + (size_t)row * D;
  s16x8 a[4];
#pragma unroll
  for (int kk = 0; kk < 4; ++kk) {
    int kb = kk * 32 + q * 8;
    float4 v0 = *(const float4*)(xrow + kb);
    float4 v1 = *(const float4*)(xrow + kb + 4);
    s16x8 t;
    t[0] = (short)f2b(v0.x); t[1] = (short)f2b(v0.y);
    t[2] = (short)f2b(v0.z); t[3] = (short)f2b(v0.w);
    t[4] = (short)f2b(v1.x); t[5] = (short)f2b(v1.y);
    t[6] = (short)f2b(v1.z); t[7] = (short)f2b(v1.w);
    a[kk] = t;
  }
  f32x4 acc[8];
#pragma unroll
  for (int nf = 0; nf < 8; ++nf) { f32x4 z = {0.f, 0.f, 0.f, 0.f}; acc[nf] = z; }
#pragma unroll
  for (int kk = 0; kk < 4; ++kk) {
    int kb = kk * 32 + q * 8;
#pragma unroll
    for (int nf = 0; nf < 8; ++nf) {
      s16x8 b = *(const s16x8*)(Wt + (size_t)(nf * 16 + l16) * D + kb);
      acc[nf] = __builtin_amdgcn_mfma_f32_16x16x32_bf16(a[kk], b, acc[nf], 0, 0, 0);
    }
  }
#pragma unroll
  for (int nf = 0; nf < 8; ++nf) {
#pragma unroll
    for (int r = 0; r < 4; ++r) {
      int rr = base + q * 4 + r;
      if (rr < n) xs[(size_t)rr * D + nf * 16 + l16] = acc[nf][r];
    }
  }
}

// ---------- per-node attention logits + order score ----------
template<int H>
__global__ __launch_bounds__(256)
void node_al_kernel(const float* __restrict__ xs, const float* __restrict__ x,
                    const float* __restrict__ a_s, const float* __restrict__ a_d,
                    const float* __restrict__ ow, const float* __restrict__ ob,
                    float* __restrict__ al_src, float* __restrict__ al_dst,
                    float* __restrict__ escore, int n) {
  int wid = blockIdx.x * 4 + (threadIdx.x >> 6);
  int lane = threadIdx.x & 63;
  if (wid >= n) return;
  float x0 = xs[(size_t)wid * D + lane], x1 = xs[(size_t)wid * D + 64 + lane];
  float s0 = x0 * a_s[lane], s1 = x1 * a_s[64 + lane];
  float d0 = x0 * a_d[lane], d1 = x1 * a_d[64 + lane];
  float xr0 = x[(size_t)wid * D + lane], xr1 = x[(size_t)wid * D + 64 + lane];
  float sc = xr0 * ow[lane] + xr1 * ow[64 + lane];
#pragma unroll
  for (int off = 32; off >= 1; off >>= 1) sc += __shfl_xor(sc, off);
  if (H == 4) {
#pragma unroll
    for (int off = 16; off >= 1; off >>= 1) {
      s0 += __shfl_xor(s0, off); s1 += __shfl_xor(s1, off);
      d0 += __shfl_xor(d0, off); d1 += __shfl_xor(d1, off);
    }
    if (lane == 0) {
      al_src[wid * 4 + 0] = s0; al_src[wid * 4 + 2] = s1;
      al_dst[wid * 4 + 0] = d0; al_dst[wid * 4 + 2] = d1;
    } else if (lane == 32) {
      al_src[wid * 4 + 1] = s0; al_src[wid * 4 + 3] = s1;
      al_dst[wid * 4 + 1] = d0; al_dst[wid * 4 + 3] = d1;
    }
  } else {
    float sa = s0 + s1, da = d0 + d1;
#pragma unroll
    for (int off = 32; off >= 1; off >>= 1) { sa += __shfl_xor(sa, off); da += __shfl_xor(da, off); }
    if (lane == 0) { al_src[wid] = sa; al_dst[wid] = da; }
  }
  if (lane == 0) escore[wid] = expf(sc + ob[0]);
}

// ---------- per-edge: te -> ale, exp(alpha); scatter into dst-order. NO atomics ----------
template<int H>
__global__ __launch_bounds__(256)
void edge_kernel(const int* __restrict__ src, const int* __restrict__ dst,
                 const float* __restrict__ ea, const float* __restrict__ ew,
                 const float* __restrict__ eb, const float* __restrict__ M,
                 const float* __restrict__ al_src, const float* __restrict__ al_dst,
                 const float* __restrict__ escore, const int* __restrict__ perm,
                 float* __restrict__ exv, float* __restrict__ alev, int E) {
  __shared__ float ewl[ED * HD];
  __shared__ float ebl[HD];
  __shared__ float Ml[HD * H];
  int t = threadIdx.x;
  for (int i = t; i < ED * HD; i += 256) ewl[i] = ew[i];
  if (t < HD) ebl[t] = eb[t];
  if (t < HD * H) Ml[t] = M[t];
  __syncthreads();
  for (int e = blockIdx.x * 256 + t; e < E; e += gridDim.x * 256) {
    int s = src[e], d = dst[e];
    float esc = escore[s];
    float te[HD];
#pragma unroll
    for (int j = 0; j < HD; ++j) te[j] = ebl[j];
    const float4* ea4 = (const float4*)(ea + (size_t)e * ED);
    for (int k4 = 0; k4 < ED / 4; ++k4) {
      float4 v = ea4[k4];
      const float* w0 = &ewl[(k4 * 4 + 0) * HD];
      const float* w1 = &ewl[(k4 * 4 + 1) * HD];
      const float* w2 = &ewl[(k4 * 4 + 2) * HD];
      const float* w3 = &ewl[(k4 * 4 + 3) * HD];
#pragma unroll
      for (int j = 0; j < HD; ++j)
        te[j] += v.x * w0[j] + v.y * w1[j] + v.z * w2[j] + v.w * w3[j];
    }
#pragma unroll
    for (int j = 0; j < HD; ++j) { float v = te[j]; te[j] = (v > 0.f ? v : 0.f) * esc; }
    float ale[H], ev[H];
#pragma unroll
    for (int h = 0; h < H; ++h) {
      float a = 0.f;
#pragma unroll
      for (int j = 0; j < HD; ++j) a += te[j] * Ml[j * H + h];
      ale[h] = a;
    }
#pragma unroll
    for (int h = 0; h < H; ++h) {
      float a = al_src[(size_t)s * H + h] + al_dst[(size_t)d * H + h] + ale[h];
      float lr = a > 0.f ? a : 0.2f * a;
      ev[h] = expf(lr);
    }
    size_t p = (size_t)perm[e] * H;
    if (H == 4) {
      *(float4*)(exv + p)  = make_float4(ev[0], ev[1], ev[2], ev[3]);
      *(float4*)(alev + p) = make_float4(ale[0], ale[1], ale[2], ale[3]);
    } else {
      exv[p] = ev[0];
      alev[p] = ale[0];
    }
  }
}

// ---------- CSR aggregation + online den/sum_ale + self-loop + bias + residual ----------
template<int H, bool RELU, bool ADD_ORIG>
__global__ __launch_bounds__(256)
void agg_kernel(const int* __restrict__ rowptr, const int* __restrict__ src_ord,
                const float* __restrict__ xs, const float* __restrict__ exv,
                const float* __restrict__ alev,
                const float* __restrict__ al_src, const float* __restrict__ al_dst,
                const float* __restrict__ bias, const float* __restrict__ xin,
                const float* __restrict__ orig, float* __restrict__ out, int n) {
  constexpr int C = D / H;
  int wid = blockIdx.x * 4 + (threadIdx.x >> 6);
  int lane = threadIdx.x & 63;
  if (wid >= n) return;
  int h0 = (2 * lane) / C;  // both channels of this lane share a head (C even)
  const float2* xs2 = (const float2*)xs;
  float ax = 0.f, ay = 0.f, den = 0.f, sale = 0.f;
  int b = rowptr[wid], e = rowptr[wid + 1];
  for (int idx = b; idx < e; ++idx) {
    int s = src_ord[idx];
    float ev = exv[(size_t)idx * H + h0];
    float al = alev[(size_t)idx * H + h0];
    float2 v = xs2[(size_t)s * 64 + lane];
    ax = fmaf(ev, v.x, ax); ay = fmaf(ev, v.y, ay);
    den += ev; sale += al;
  }
  // self-loop: attr = mean of incoming ale (linear in attr)
  int deg = e - b;
  float la = sale / (float)(deg > 1 ? deg : 1);
  float a = al_src[(size_t)wid * H + h0] + al_dst[(size_t)wid * H + h0] + la;
  float lr = a > 0.f ? a : 0.2f * a;
  float evl = expf(lr);
  {
    float2 v = xs2[(size_t)wid * 64 + lane];
    ax = fmaf(evl, v.x, ax); ay = fmaf(evl, v.y, ay);
  }
  float dinv = 1.f / (den + evl + 1e-16f);
  float2 bi = ((const float2*)bias)[lane];
  float2 xi = ((const float2*)xin)[(size_t)wid * 64 + lane];
  ax = ax * dinv + bi.x + xi.x;
  ay = ay * dinv + bi.y + xi.y;
  if (ADD_ORIG) {
    float2 og = ((const float2*)orig)[(size_t)wid * 64 + lane];
    ax += og.x; ay += og.y;
  }
  if (RELU) { ax = fmaxf(ax, 0.f); ay = fmaxf(ay, 0.f); }
  ((float2*)out)[(size_t)wid * 64 + lane] = make_float2(ax, ay);
}

extern "C" void kernel_launch(void* const* d_in, const int* in_sizes, int n_in,
                              void* d_out, int out_size, void* d_ws, size_t ws_size,
                              hipStream_t stream) {
  const float* x   = (const float*)d_in[0];
  const int*   ei  = (const int*)d_in[1];
  const float* ea  = (const float*)d_in[2];
  const float* ew0 = (const float*)d_in[3];
  const float* eb0 = (const float*)d_in[4];
  const float* ew1 = (const float*)d_in[5];
  const float* eb1 = (const float*)d_in[6];
  const float* ow0 = (const float*)d_in[7];
  const float* ob0 = (const float*)d_in[8];
  const float* ow1 = (const float*)d_in[9];
  const float* ob1 = (const float*)d_in[10];
  const float* g0W = (const float*)d_in[11];
  const float* g0as= (const float*)d_in[12];
  const float* g0ad= (const float*)d_in[13];
  const float* g0We= (const float*)d_in[14];
  const float* g0ae= (const float*)d_in[15];
  const float* g0b = (const float*)d_in[16];
  const float* g1W = (const float*)d_in[17];
  const float* g1as= (const float*)d_in[18];
  const float* g1ad= (const float*)d_in[19];
  const float* g1We= (const float*)d_in[20];
  const float* g1ae= (const float*)d_in[21];
  const float* g1b = (const float*)d_in[22];
  float* out = (float*)d_out;

  const int N = in_sizes[0] / D;
  const int E = in_sizes[1] / 2;
  const int* srcp = ei;
  const int* dstp = ei + E;

  char* w = (char*)d_ws;
  size_t off = 0;
  auto alloc = [&](size_t bytes) {
    void* p = w + off;
    off += (bytes + 255) & ~(size_t)255;
    return p;
  };
  float* xs      = (float*)alloc((size_t)N * D * 4);
  float* exv     = (float*)alloc((size_t)E * 4 * 4);
  float* alev    = (float*)alloc((size_t)E * 4 * 4);
  float* al_src  = (float*)alloc((size_t)N * 4 * 4);
  float* al_dst  = (float*)alloc((size_t)N * 4 * 4);
  float* escore  = (float*)alloc((size_t)N * 4);
  float* M0      = (float*)alloc(HD * 4 * 4);
  float* M1      = (float*)alloc(HD * 4);
  unsigned short* Wt0 = (unsigned short*)alloc((size_t)D * D * 2);
  unsigned short* Wt1 = (unsigned short*)alloc((size_t)D * D * 2);
  int*   cnt     = (int*)alloc((size_t)N * 4);
  int*   rowptr  = (int*)alloc((size_t)(N + 1) * 4);
  int*   cursor  = (int*)alloc((size_t)N * 4);
  int*   perm    = (int*)alloc((size_t)E * 4);
  int*   src_ord = (int*)alloc((size_t)E * 4);

  int egrid  = (E + 255) / 256;
  int ngrid4 = (N + 3) / 4;
  int ggrid  = (N + 63) / 64;

  // ---- CSR build (shared by both layers) + weight prep ----
  hipMemsetAsync(cnt, 0, (size_t)N * 4, stream);
  hipMemsetAsync(cursor, 0, (size_t)N * 4, stream);
  count_kernel<<<egrid, 256, 0, stream>>>(dstp, cnt, E);
  scan_kernel<<<1, 1024, 0, stream>>>(cnt, rowptr, N);
  fill_kernel<<<egrid, 256, 0, stream>>>(srcp, dstp, rowptr, cursor, perm, src_ord, E);
  prep_M_kernel<4><<<1, 128, 0, stream>>>(g0We, g0ae, M0);
  prep_M_kernel<1><<<1, 32, 0, stream>>>(g1We, g1ae, M1);
  prep_Wt_kernel<<<64, 256, 0, stream>>>(g0W, Wt0);
  prep_Wt_kernel<<<64, 256, 0, stream>>>(g1W, Wt1);

  // ---- layer 0 (H=4, C=32), output -> d_out (used as x1) ----
  node_gemm_mfma<<<ggrid, 256, 0, stream>>>(x, Wt0, xs, N);
  node_al_kernel<4><<<ngrid4, 256, 0, stream>>>(xs, x, g0as, g0ad, ow0, ob0,
                                                al_src, al_dst, escore, N);
  edge_kernel<4><<<egrid, 256, 0, stream>>>(srcp, dstp, ea, ew0, eb0, M0,
                                            al_src, al_dst, escore, perm,
                                            exv, alev, E);
  agg_kernel<4, true, false><<<ngrid4, 256, 0, stream>>>(rowptr, src_ord,
                                                         xs, exv, alev,
                                                         al_src, al_dst,
                                                         g0b, x, nullptr, out, N);

  // ---- layer 1 (H=1, C=128), input = d_out, output = d_out (+original x) ----
  node_gemm_mfma<<<ggrid, 256, 0, stream>>>(out, Wt1, xs, N);
  node_al_kernel<1><<<ngrid4, 256, 0, stream>>>(xs, out, g1as, g1ad, ow1, ob1,
                                                al_src, al_dst, escore, N);
  edge_kernel<1><<<egrid, 256, 0, stream>>>(srcp, dstp, ea, ew1, eb1, M1,
                                            al_src, al_dst, escore, perm,
                                            exv, alev, E);
  agg_kernel<1, false, true><<<ngrid4, 256, 0, stream>>>(rowptr, src_ord,
                                                         xs, exv, alev,
                                                         al_src, al_dst,
                                                         g1b, out, x, out, N);
}

// Round 4
// 498.162 us; speedup vs baseline: 2.2961x; 1.1234x over previous
//
#include <hip/hip_runtime.h>
#include <math.h>

#define D 128
#define ED 64
#define HD 32

typedef short s16x8 __attribute__((ext_vector_type(8)));
typedef float f32x4 __attribute__((ext_vector_type(4)));

// f32 -> bf16 bits, round-to-nearest-even
static __device__ inline unsigned short f2b(float f) {
  unsigned int u = __float_as_uint(f);
  unsigned int r = (u + 0x7fff + ((u >> 16) & 1)) >> 16;
  return (unsigned short)r;
}

// ---------- CSR build ----------
__global__ __launch_bounds__(256)
void count_kernel(const int* __restrict__ dst, int* __restrict__ cnt, int E) {
  int e = blockIdx.x * 256 + threadIdx.x;
  if (e < E) atomicAdd(&cnt[dst[e]], 1);
}

__global__ __launch_bounds__(1024)
void scan_kernel(const int* __restrict__ cnt, int* __restrict__ rowptr, int n) {
  __shared__ int part[1024];
  int t = threadIdx.x;
  int chunk = (n + 1023) >> 10;
  int b = t * chunk, e = min(b + chunk, n);
  int s = 0;
  for (int i = b; i < e; ++i) s += cnt[i];
  part[t] = s;
  __syncthreads();
  for (int off = 1; off < 1024; off <<= 1) {
    int add = (t >= off) ? part[t - off] : 0;
    __syncthreads();
    part[t] += add;
    __syncthreads();
  }
  int run = part[t] - s;
  for (int i = b; i < e; ++i) { rowptr[i] = run; run += cnt[i]; }
  if (t == 1023) rowptr[n] = part[1023];
}

// fill: perm[e] = CSR slot of edge e; src_ord[slot] = src[e]
__global__ __launch_bounds__(256)
void fill_kernel(const int* __restrict__ src, const int* __restrict__ dst,
                 const int* __restrict__ rowptr, int* __restrict__ cursor,
                 int* __restrict__ perm, int* __restrict__ src_ord, int E) {
  int e = blockIdx.x * 256 + threadIdx.x;
  if (e < E) {
    int d = dst[e];
    int p = atomicAdd(&cursor[d], 1);
    int slot = rowptr[d] + p;
    perm[e] = slot;
    src_ord[slot] = src[e];
  }
}

// ---------- M[d,h] = sum_c We[d, h*C+c] * ae[h,c] ----------
template<int H>
__global__ void prep_M_kernel(const float* __restrict__ We, const float* __restrict__ ae,
                              float* __restrict__ M) {
  constexpr int C = D / H;
  int t = threadIdx.x;
  if (t < HD * H) {
    int d = t / H, h = t - d * H;
    float s = 0.f;
    for (int c = 0; c < C; ++c) s += We[d * D + h * C + c] * ae[h * C + c];
    M[d * H + h] = s;
  }
}

// ---------- Wt[n][k] = bf16(W[k][n])  (transpose+convert, 128x128) ----------
__global__ __launch_bounds__(256)
void prep_Wt_kernel(const float* __restrict__ W, unsigned short* __restrict__ Wt) {
  int id = blockIdx.x * 256 + threadIdx.x;   // 0..16383
  int nn = id >> 7, k = id & 127;
  Wt[id] = f2b(W[k * D + nn]);
}

// ---------- ewt[col][k] = bf16(ew[k][col]), 32 cols x 64 k ----------
__global__ __launch_bounds__(256)
void prep_ewt_kernel(const float* __restrict__ ew, unsigned short* __restrict__ ewt) {
  int id = blockIdx.x * 256 + threadIdx.x;   // 0..2047
  if (id < HD * ED) {
    int col = id >> 6, k = id & 63;
    ewt[id] = f2b(ew[k * HD + col]);
  }
}

// ---------- xs = x @ W via MFMA bf16 (no LDS, no barriers) ----------
__global__ __launch_bounds__(256)
void node_gemm_mfma(const float* __restrict__ x, const unsigned short* __restrict__ Wt,
                    float* __restrict__ xs, int n) {
  int wave = threadIdx.x >> 6;
  int lane = threadIdx.x & 63;
  int q = lane >> 4;
  int l16 = lane & 15;
  int base = blockIdx.x * 64 + wave * 16;
  int rowRaw = base + l16;
  int row = rowRaw < n ? rowRaw : n - 1;
  const float* xrow = x + (size_t)row * D;
  s16x8 a[4];
#pragma unroll
  for (int kk = 0; kk < 4; ++kk) {
    int kb = kk * 32 + q * 8;
    float4 v0 = *(const float4*)(xrow + kb);
    float4 v1 = *(const float4*)(xrow + kb + 4);
    s16x8 t;
    t[0] = (short)f2b(v0.x); t[1] = (short)f2b(v0.y);
    t[2] = (short)f2b(v0.z); t[3] = (short)f2b(v0.w);
    t[4] = (short)f2b(v1.x); t[5] = (short)f2b(v1.y);
    t[6] = (short)f2b(v1.z); t[7] = (short)f2b(v1.w);
    a[kk] = t;
  }
  f32x4 acc[8];
#pragma unroll
  for (int nf = 0; nf < 8; ++nf) { f32x4 z = {0.f, 0.f, 0.f, 0.f}; acc[nf] = z; }
#pragma unroll
  for (int kk = 0; kk < 4; ++kk) {
    int kb = kk * 32 + q * 8;
#pragma unroll
    for (int nf = 0; nf < 8; ++nf) {
      s16x8 b = *(const s16x8*)(Wt + (size_t)(nf * 16 + l16) * D + kb);
      acc[nf] = __builtin_amdgcn_mfma_f32_16x16x32_bf16(a[kk], b, acc[nf], 0, 0, 0);
    }
  }
#pragma unroll
  for (int nf = 0; nf < 8; ++nf) {
#pragma unroll
    for (int r = 0; r < 4; ++r) {
      int rr = base + q * 4 + r;
      if (rr < n) xs[(size_t)rr * D + nf * 16 + l16] = acc[nf][r];
    }
  }
}

// ---------- per-node attention logits + order score ----------
template<int H>
__global__ __launch_bounds__(256)
void node_al_kernel(const float* __restrict__ xs, const float* __restrict__ x,
                    const float* __restrict__ a_s, const float* __restrict__ a_d,
                    const float* __restrict__ ow, const float* __restrict__ ob,
                    float* __restrict__ al_src, float* __restrict__ al_dst,
                    float* __restrict__ escore, int n) {
  int wid = blockIdx.x * 4 + (threadIdx.x >> 6);
  int lane = threadIdx.x & 63;
  if (wid >= n) return;
  float x0 = xs[(size_t)wid * D + lane], x1 = xs[(size_t)wid * D + 64 + lane];
  float s0 = x0 * a_s[lane], s1 = x1 * a_s[64 + lane];
  float d0 = x0 * a_d[lane], d1 = x1 * a_d[64 + lane];
  float xr0 = x[(size_t)wid * D + lane], xr1 = x[(size_t)wid * D + 64 + lane];
  float sc = xr0 * ow[lane] + xr1 * ow[64 + lane];
#pragma unroll
  for (int off = 32; off >= 1; off >>= 1) sc += __shfl_xor(sc, off);
  if (H == 4) {
#pragma unroll
    for (int off = 16; off >= 1; off >>= 1) {
      s0 += __shfl_xor(s0, off); s1 += __shfl_xor(s1, off);
      d0 += __shfl_xor(d0, off); d1 += __shfl_xor(d1, off);
    }
    if (lane == 0) {
      al_src[wid * 4 + 0] = s0; al_src[wid * 4 + 2] = s1;
      al_dst[wid * 4 + 0] = d0; al_dst[wid * 4 + 2] = d1;
    } else if (lane == 32) {
      al_src[wid * 4 + 1] = s0; al_src[wid * 4 + 3] = s1;
      al_dst[wid * 4 + 1] = d0; al_dst[wid * 4 + 3] = d1;
    }
  } else {
    float sa = s0 + s1, da = d0 + d1;
#pragma unroll
    for (int off = 32; off >= 1; off >>= 1) { sa += __shfl_xor(sa, off); da += __shfl_xor(da, off); }
    if (lane == 0) { al_src[wid] = sa; al_dst[wid] = da; }
  }
  if (lane == 0) escore[wid] = expf(sc + ob[0]);
}

// ---------- per-edge via MFMA: z = ea@ew (+eb, relu), ale = z@M * esc, alpha, exp ----------
// wave handles 64 edges in 4 sub-tiles of 16. No LDS, no barriers, no atomics.
template<int H>
__global__ __launch_bounds__(256)
void edge_mfma_kernel(const int* __restrict__ src, const int* __restrict__ dst,
                      const float* __restrict__ ea,
                      const unsigned short* __restrict__ ewt,   // [32][64] bf16
                      const float* __restrict__ eb,
                      const float* __restrict__ M,              // [32][H]
                      const float* __restrict__ al_src, const float* __restrict__ al_dst,
                      const float* __restrict__ escore, const int* __restrict__ perm,
                      float* __restrict__ exv, float* __restrict__ alev, int E) {
  int wave = threadIdx.x >> 6, lane = threadIdx.x & 63;
  int q = lane >> 4, l16 = lane & 15;
  int ebase = (blockIdx.x * 4 + wave) * 64;
  if (ebase >= E) return;
  // B fragments (held in regs for whole wave): col = cb*16+l16, k = kk*32+q*8+j
  s16x8 bf00 = *(const s16x8*)(ewt + (size_t)l16 * 64 + q * 8);
  s16x8 bf01 = *(const s16x8*)(ewt + (size_t)l16 * 64 + 32 + q * 8);
  s16x8 bf10 = *(const s16x8*)(ewt + (size_t)(16 + l16) * 64 + q * 8);
  s16x8 bf11 = *(const s16x8*)(ewt + (size_t)(16 + l16) * 64 + 32 + q * 8);
  float eb0 = eb[l16], eb1 = eb[16 + l16];
  float Mv0[H], Mv1[H];
#pragma unroll
  for (int h = 0; h < H; ++h) { Mv0[h] = M[l16 * H + h]; Mv1[h] = M[(16 + l16) * H + h]; }

#pragma unroll
  for (int st = 0; st < 4; ++st) {
    int eb_t = ebase + st * 16;
    int ea_row = eb_t + l16; if (ea_row > E - 1) ea_row = E - 1;
    const float* er = ea + (size_t)ea_row * ED;
    s16x8 a0, a1;
    {
      float4 v0 = *(const float4*)(er + q * 8);
      float4 v1 = *(const float4*)(er + q * 8 + 4);
      a0[0] = (short)f2b(v0.x); a0[1] = (short)f2b(v0.y);
      a0[2] = (short)f2b(v0.z); a0[3] = (short)f2b(v0.w);
      a0[4] = (short)f2b(v1.x); a0[5] = (short)f2b(v1.y);
      a0[6] = (short)f2b(v1.z); a0[7] = (short)f2b(v1.w);
      float4 w0 = *(const float4*)(er + 32 + q * 8);
      float4 w1 = *(const float4*)(er + 32 + q * 8 + 4);
      a1[0] = (short)f2b(w0.x); a1[1] = (short)f2b(w0.y);
      a1[2] = (short)f2b(w0.z); a1[3] = (short)f2b(w0.w);
      a1[4] = (short)f2b(w1.x); a1[5] = (short)f2b(w1.y);
      a1[6] = (short)f2b(w1.z); a1[7] = (short)f2b(w1.w);
    }
    f32x4 z0 = {0.f, 0.f, 0.f, 0.f}, z1 = {0.f, 0.f, 0.f, 0.f};
    z0 = __builtin_amdgcn_mfma_f32_16x16x32_bf16(a0, bf00, z0, 0, 0, 0);
    z0 = __builtin_amdgcn_mfma_f32_16x16x32_bf16(a1, bf01, z0, 0, 0, 0);
    z1 = __builtin_amdgcn_mfma_f32_16x16x32_bf16(a0, bf10, z1, 0, 0, 0);
    z1 = __builtin_amdgcn_mfma_f32_16x16x32_bf16(a1, bf11, z1, 0, 0, 0);
    // D layout: lane (q,l16) holds edge eb_t+q*4+r, channels l16 and 16+l16
    float mine = 0.f;
#pragma unroll
    for (int r = 0; r < 4; ++r) {
      float rz0 = fmaxf(z0[r] + eb0, 0.f);
      float rz1 = fmaxf(z1[r] + eb1, 0.f);
#pragma unroll
      for (int h = 0; h < H; ++h) {
        float v = rz0 * Mv0[h] + rz1 * Mv1[h];
        v += __shfl_xor(v, 1); v += __shfl_xor(v, 2);
        v += __shfl_xor(v, 4); v += __shfl_xor(v, 8);
        int idx = (H == 4) ? (r * 4 + h) : r;
        if (l16 == idx) mine = v;
      }
    }
    // lane (q,l16) -> edge eb_t + q*4 + r2, head h2
    int r2 = (H == 4) ? (l16 >> 2) : (l16 & 3);
    int h2 = (H == 4) ? (l16 & 3) : 0;
    int e = eb_t + q * 4 + r2;
    bool valid = (e < E) && (H == 4 || l16 < 4);
    int ec = e < E ? e : E - 1;
    int s = src[ec], dd = dst[ec];
    float alef = mine * escore[s];
    float aa = al_src[(size_t)s * H + h2] + al_dst[(size_t)dd * H + h2] + alef;
    float lr = aa > 0.f ? aa : 0.2f * aa;
    float ev = __expf(lr);
    int p = perm[ec];
    if (valid) {
      exv[(size_t)p * H + h2] = ev;
      alev[(size_t)p * H + h2] = alef;
    }
  }
}

// ---------- CSR aggregation + online den/sum_ale + self-loop + bias + residual ----------
template<int H, bool RELU, bool ADD_ORIG>
__global__ __launch_bounds__(256)
void agg_kernel(const int* __restrict__ rowptr, const int* __restrict__ src_ord,
                const float* __restrict__ xs, const float* __restrict__ exv,
                const float* __restrict__ alev,
                const float* __restrict__ al_src, const float* __restrict__ al_dst,
                const float* __restrict__ bias, const float* __restrict__ xin,
                const float* __restrict__ orig, float* __restrict__ out, int n) {
  constexpr int C = D / H;
  int wid = blockIdx.x * 4 + (threadIdx.x >> 6);
  int lane = threadIdx.x & 63;
  if (wid >= n) return;
  int h0 = (2 * lane) / C;  // both channels of this lane share a head (C even)
  const float2* xs2 = (const float2*)xs;
  float ax = 0.f, ay = 0.f, den = 0.f, sale = 0.f;
  int b = rowptr[wid], e = rowptr[wid + 1];
  for (int idx = b; idx < e; ++idx) {
    int s = src_ord[idx];
    float ev = exv[(size_t)idx * H + h0];
    float al = alev[(size_t)idx * H + h0];
    float2 v = xs2[(size_t)s * 64 + lane];
    ax = fmaf(ev, v.x, ax); ay = fmaf(ev, v.y, ay);
    den += ev; sale += al;
  }
  // self-loop: attr = mean of incoming ale (linear in attr)
  int deg = e - b;
  float la = sale / (float)(deg > 1 ? deg : 1);
  float a = al_src[(size_t)wid * H + h0] + al_dst[(size_t)wid * H + h0] + la;
  float lr = a > 0.f ? a : 0.2f * a;
  float evl = expf(lr);
  {
    float2 v = xs2[(size_t)wid * 64 + lane];
    ax = fmaf(evl, v.x, ax); ay = fmaf(evl, v.y, ay);
  }
  float dinv = 1.f / (den + evl + 1e-16f);
  float2 bi = ((const float2*)bias)[lane];
  float2 xi = ((const float2*)xin)[(size_t)wid * 64 + lane];
  ax = ax * dinv + bi.x + xi.x;
  ay = ay * dinv + bi.y + xi.y;
  if (ADD_ORIG) {
    float2 og = ((const float2*)orig)[(size_t)wid * 64 + lane];
    ax += og.x; ay += og.y;
  }
  if (RELU) { ax = fmaxf(ax, 0.f); ay = fmaxf(ay, 0.f); }
  ((float2*)out)[(size_t)wid * 64 + lane] = make_float2(ax, ay);
}

extern "C" void kernel_launch(void* const* d_in, const int* in_sizes, int n_in,
                              void* d_out, int out_size, void* d_ws, size_t ws_size,
                              hipStream_t stream) {
  const float* x   = (const float*)d_in[0];
  const int*   ei  = (const int*)d_in[1];
  const float* ea  = (const float*)d_in[2];
  const float* ew0 = (const float*)d_in[3];
  const float* eb0 = (const float*)d_in[4];
  const float* ew1 = (const float*)d_in[5];
  const float* eb1 = (const float*)d_in[6];
  const float* ow0 = (const float*)d_in[7];
  const float* ob0 = (const float*)d_in[8];
  const float* ow1 = (const float*)d_in[9];
  const float* ob1 = (const float*)d_in[10];
  const float* g0W = (const float*)d_in[11];
  const float* g0as= (const float*)d_in[12];
  const float* g0ad= (const float*)d_in[13];
  const float* g0We= (const float*)d_in[14];
  const float* g0ae= (const float*)d_in[15];
  const float* g0b = (const float*)d_in[16];
  const float* g1W = (const float*)d_in[17];
  const float* g1as= (const float*)d_in[18];
  const float* g1ad= (const float*)d_in[19];
  const float* g1We= (const float*)d_in[20];
  const float* g1ae= (const float*)d_in[21];
  const float* g1b = (const float*)d_in[22];
  float* out = (float*)d_out;

  const int N = in_sizes[0] / D;
  const int E = in_sizes[1] / 2;
  const int* srcp = ei;
  const int* dstp = ei + E;

  char* w = (char*)d_ws;
  size_t off = 0;
  auto alloc = [&](size_t bytes) {
    void* p = w + off;
    off += (bytes + 255) & ~(size_t)255;
    return p;
  };
  float* xs      = (float*)alloc((size_t)N * D * 4);
  float* exv     = (float*)alloc((size_t)E * 4 * 4);
  float* alev    = (float*)alloc((size_t)E * 4 * 4);
  float* al_src  = (float*)alloc((size_t)N * 4 * 4);
  float* al_dst  = (float*)alloc((size_t)N * 4 * 4);
  float* escore  = (float*)alloc((size_t)N * 4);
  float* M0      = (float*)alloc(HD * 4 * 4);
  float* M1      = (float*)alloc(HD * 4);
  unsigned short* Wt0 = (unsigned short*)alloc((size_t)D * D * 2);
  unsigned short* Wt1 = (unsigned short*)alloc((size_t)D * D * 2);
  unsigned short* ewt0 = (unsigned short*)alloc((size_t)HD * ED * 2);
  unsigned short* ewt1 = (unsigned short*)alloc((size_t)HD * ED * 2);
  int*   cnt     = (int*)alloc((size_t)N * 4);
  int*   rowptr  = (int*)alloc((size_t)(N + 1) * 4);
  int*   cursor  = (int*)alloc((size_t)N * 4);
  int*   perm    = (int*)alloc((size_t)E * 4);
  int*   src_ord = (int*)alloc((size_t)E * 4);

  int egrid  = (E + 255) / 256;
  int ngrid4 = (N + 3) / 4;
  int ggrid  = (N + 63) / 64;

  // ---- CSR build (shared by both layers) + weight prep ----
  hipMemsetAsync(cnt, 0, (size_t)N * 4, stream);
  hipMemsetAsync(cursor, 0, (size_t)N * 4, stream);
  count_kernel<<<egrid, 256, 0, stream>>>(dstp, cnt, E);
  scan_kernel<<<1, 1024, 0, stream>>>(cnt, rowptr, N);
  fill_kernel<<<egrid, 256, 0, stream>>>(srcp, dstp, rowptr, cursor, perm, src_ord, E);
  prep_M_kernel<4><<<1, 128, 0, stream>>>(g0We, g0ae, M0);
  prep_M_kernel<1><<<1, 32, 0, stream>>>(g1We, g1ae, M1);
  prep_Wt_kernel<<<64, 256, 0, stream>>>(g0W, Wt0);
  prep_Wt_kernel<<<64, 256, 0, stream>>>(g1W, Wt1);
  prep_ewt_kernel<<<8, 256, 0, stream>>>(ew0, ewt0);
  prep_ewt_kernel<<<8, 256, 0, stream>>>(ew1, ewt1);

  // ---- layer 0 (H=4, C=32), output -> d_out (used as x1) ----
  node_gemm_mfma<<<ggrid, 256, 0, stream>>>(x, Wt0, xs, N);
  node_al_kernel<4><<<ngrid4, 256, 0, stream>>>(xs, x, g0as, g0ad, ow0, ob0,
                                                al_src, al_dst, escore, N);
  edge_mfma_kernel<4><<<egrid, 256, 0, stream>>>(srcp, dstp, ea, ewt0, eb0, M0,
                                                 al_src, al_dst, escore, perm,
                                                 exv, alev, E);
  agg_kernel<4, true, false><<<ngrid4, 256, 0, stream>>>(rowptr, src_ord,
                                                         xs, exv, alev,
                                                         al_src, al_dst,
                                                         g0b, x, nullptr, out, N);

  // ---- layer 1 (H=1, C=128), input = d_out, output = d_out (+original x) ----
  node_gemm_mfma<<<ggrid, 256, 0, stream>>>(out, Wt1, xs, N);
  node_al_kernel<1><<<ngrid4, 256, 0, stream>>>(xs, out, g1as, g1ad, ow1, ob1,
                                                al_src, al_dst, escore, N);
  edge_mfma_kernel<1><<<egrid, 256, 0, stream>>>(srcp, dstp, ea, ewt1, eb1, M1,
                                                 al_src, al_dst, escore, perm,
                                                 exv, alev, E);
  agg_kernel<1, false, true><<<ngrid4, 256, 0, stream>>>(rowptr, src_ord,
                                                         xs, exv, alev,
                                                         al_src, al_dst,
                                                         g1b, out, x, out, N);
}

// Round 5
// 432.282 us; speedup vs baseline: 2.6461x; 1.1524x over previous
//
#include <hip/hip_runtime.h>
#include <math.h>

#define D 128
#define ED 64
#define HD 32

typedef short s16x8 __attribute__((ext_vector_type(8)));
typedef float f32x4 __attribute__((ext_vector_type(4)));

// f32 -> bf16 bits, round-to-nearest-even
static __device__ inline unsigned short f2b(float f) {
  unsigned int u = __float_as_uint(f);
  unsigned int r = (u + 0x7fff + ((u >> 16) & 1)) >> 16;
  return (unsigned short)r;
}

// ---------- CSR build ----------
__global__ __launch_bounds__(256)
void count_kernel(const int* __restrict__ dst, int* __restrict__ cnt, int E) {
  int e = blockIdx.x * 256 + threadIdx.x;
  if (e < E) atomicAdd(&cnt[dst[e]], 1);
}

__global__ __launch_bounds__(1024)
void scan_kernel(const int* __restrict__ cnt, int* __restrict__ rowptr, int n) {
  __shared__ int part[1024];
  int t = threadIdx.x;
  int chunk = (n + 1023) >> 10;
  int b = t * chunk, e = min(b + chunk, n);
  int s = 0;
  for (int i = b; i < e; ++i) s += cnt[i];
  part[t] = s;
  __syncthreads();
  for (int off = 1; off < 1024; off <<= 1) {
    int add = (t >= off) ? part[t - off] : 0;
    __syncthreads();
    part[t] += add;
    __syncthreads();
  }
  int run = part[t] - s;
  for (int i = b; i < e; ++i) { rowptr[i] = run; run += cnt[i]; }
  if (t == 1023) rowptr[n] = part[1023];
}

// fill: perm[e] = CSR slot of edge e; src_ord/dst_ord[slot] = src/dst
__global__ __launch_bounds__(256)
void fill_kernel(const int* __restrict__ src, const int* __restrict__ dst,
                 const int* __restrict__ rowptr, int* __restrict__ cursor,
                 int* __restrict__ perm, int* __restrict__ src_ord,
                 int* __restrict__ dst_ord, int E) {
  int e = blockIdx.x * 256 + threadIdx.x;
  if (e < E) {
    int d = dst[e];
    int p = atomicAdd(&cursor[d], 1);
    int slot = rowptr[d] + p;
    perm[e] = slot;
    src_ord[slot] = src[e];
    dst_ord[slot] = d;
  }
}

// ---------- M[d,h] = sum_c We[d, h*C+c] * ae[h,c] ----------
template<int H>
__global__ void prep_M_kernel(const float* __restrict__ We, const float* __restrict__ ae,
                              float* __restrict__ M) {
  constexpr int C = D / H;
  int t = threadIdx.x;
  if (t < HD * H) {
    int d = t / H, h = t - d * H;
    float s = 0.f;
    for (int c = 0; c < C; ++c) s += We[d * D + h * C + c] * ae[h * C + c];
    M[d * H + h] = s;
  }
}

// ---------- Wt[n][k] = bf16(W[k][n])  (transpose+convert, 128x128) ----------
__global__ __launch_bounds__(256)
void prep_Wt_kernel(const float* __restrict__ W, unsigned short* __restrict__ Wt) {
  int id = blockIdx.x * 256 + threadIdx.x;   // 0..16383
  int nn = id >> 7, k = id & 127;
  Wt[id] = f2b(W[k * D + nn]);
}

// ---------- permuted ewt: row i holds ew column ch(i), channels arranged so
// lane (q,l16)'s D rows map to channels q*8+0..7 (lo: +0..3, hi: +4..7) ----------
__global__ __launch_bounds__(256)
void prep_ewt_kernel(const float* __restrict__ ew, unsigned short* __restrict__ ewt) {
  int id = blockIdx.x * 256 + threadIdx.x;   // 0..2047
  if (id < HD * ED) {
    int i = id >> 6, k = id & 63;
    int ch = (i < 16) ? ((i >> 2) * 8 + (i & 3))
                      : (((i - 16) >> 2) * 8 + 4 + ((i - 16) & 3));
    ewt[id] = f2b(ew[k * HD + ch]);
  }
}

// ---------- xs = x @ W via MFMA bf16 (no LDS, no barriers) ----------
__global__ __launch_bounds__(256)
void node_gemm_mfma(const float* __restrict__ x, const unsigned short* __restrict__ Wt,
                    float* __restrict__ xs, int n) {
  int wave = threadIdx.x >> 6;
  int lane = threadIdx.x & 63;
  int q = lane >> 4;
  int l16 = lane & 15;
  int base = blockIdx.x * 64 + wave * 16;
  int rowRaw = base + l16;
  int row = rowRaw < n ? rowRaw : n - 1;
  const float* xrow = x + (size_t)row * D;
  s16x8 a[4];
#pragma unroll
  for (int kk = 0; kk < 4; ++kk) {
    int kb = kk * 32 + q * 8;
    float4 v0 = *(const float4*)(xrow + kb);
    float4 v1 = *(const float4*)(xrow + kb + 4);
    s16x8 t;
    t[0] = (short)f2b(v0.x); t[1] = (short)f2b(v0.y);
    t[2] = (short)f2b(v0.z); t[3] = (short)f2b(v0.w);
    t[4] = (short)f2b(v1.x); t[5] = (short)f2b(v1.y);
    t[6] = (short)f2b(v1.z); t[7] = (short)f2b(v1.w);
    a[kk] = t;
  }
  f32x4 acc[8];
#pragma unroll
  for (int nf = 0; nf < 8; ++nf) { f32x4 z = {0.f, 0.f, 0.f, 0.f}; acc[nf] = z; }
#pragma unroll
  for (int kk = 0; kk < 4; ++kk) {
    int kb = kk * 32 + q * 8;
#pragma unroll
    for (int nf = 0; nf < 8; ++nf) {
      s16x8 b = *(const s16x8*)(Wt + (size_t)(nf * 16 + l16) * D + kb);
      acc[nf] = __builtin_amdgcn_mfma_f32_16x16x32_bf16(a[kk], b, acc[nf], 0, 0, 0);
    }
  }
#pragma unroll
  for (int nf = 0; nf < 8; ++nf) {
#pragma unroll
    for (int r = 0; r < 4; ++r) {
      int rr = base + q * 4 + r;
      if (rr < n) xs[(size_t)rr * D + nf * 16 + l16] = acc[nf][r];
    }
  }
}

// ---------- per-node attention logits + order score ----------
template<int H>
__global__ __launch_bounds__(256)
void node_al_kernel(const float* __restrict__ xs, const float* __restrict__ x,
                    const float* __restrict__ a_s, const float* __restrict__ a_d,
                    const float* __restrict__ ow, const float* __restrict__ ob,
                    float* __restrict__ al_src, float* __restrict__ al_dst,
                    float* __restrict__ escore, int n) {
  int wid = blockIdx.x * 4 + (threadIdx.x >> 6);
  int lane = threadIdx.x & 63;
  if (wid >= n) return;
  float x0 = xs[(size_t)wid * D + lane], x1 = xs[(size_t)wid * D + 64 + lane];
  float s0 = x0 * a_s[lane], s1 = x1 * a_s[64 + lane];
  float d0 = x0 * a_d[lane], d1 = x1 * a_d[64 + lane];
  float xr0 = x[(size_t)wid * D + lane], xr1 = x[(size_t)wid * D + 64 + lane];
  float sc = xr0 * ow[lane] + xr1 * ow[64 + lane];
#pragma unroll
  for (int off = 32; off >= 1; off >>= 1) sc += __shfl_xor(sc, off);
  if (H == 4) {
#pragma unroll
    for (int off = 16; off >= 1; off >>= 1) {
      s0 += __shfl_xor(s0, off); s1 += __shfl_xor(s1, off);
      d0 += __shfl_xor(d0, off); d1 += __shfl_xor(d1, off);
    }
    if (lane == 0) {
      al_src[wid * 4 + 0] = s0; al_src[wid * 4 + 2] = s1;
      al_dst[wid * 4 + 0] = d0; al_dst[wid * 4 + 2] = d1;
    } else if (lane == 32) {
      al_src[wid * 4 + 1] = s0; al_src[wid * 4 + 3] = s1;
      al_dst[wid * 4 + 1] = d0; al_dst[wid * 4 + 3] = d1;
    }
  } else {
    float sa = s0 + s1, da = d0 + d1;
#pragma unroll
    for (int off = 32; off >= 1; off >>= 1) { sa += __shfl_xor(sa, off); da += __shfl_xor(da, off); }
    if (lane == 0) { al_src[wid] = sa; al_dst[wid] = da; }
  }
  if (lane == 0) escore[wid] = expf(sc + ob[0]);
}

// ---------- fused edge pass: both encoders, transposed MFMA + MFMA head-reduce ----------
// z^T[ch][edge] per 16-edge sub-tile; channel perm puts lane's 8 channels at k=q*8+j.
// Head-reduce via one MFMA with M-fragment (heads in rows 0..3 / row 0).
__global__ __launch_bounds__(256)
void edge_fused_kernel(const int* __restrict__ src, const int* __restrict__ dst,
                       const float* __restrict__ ea,
                       const unsigned short* __restrict__ ewt0p,
                       const unsigned short* __restrict__ ewt1p,
                       const float* __restrict__ eb0, const float* __restrict__ eb1,
                       const float* __restrict__ M0,   // [32][4]
                       const float* __restrict__ M1,   // [32]
                       const float* __restrict__ al_src0, const float* __restrict__ al_dst0,
                       const float* __restrict__ escore0, const int* __restrict__ perm,
                       float* __restrict__ exv0, float* __restrict__ alev0,
                       float* __restrict__ ale1raw, int E) {
  int wave = threadIdx.x >> 6, lane = threadIdx.x & 63;
  int q = lane >> 4, l16 = lane & 15;
  int ebase = (blockIdx.x * 4 + wave) * 64;
  if (ebase >= E) return;
  // encoder A-fragments (row = permuted channel, k = ea-dim)
  s16x8 a0l0 = *(const s16x8*)(ewt0p + l16 * 64 + q * 8);
  s16x8 a0l1 = *(const s16x8*)(ewt0p + l16 * 64 + 32 + q * 8);
  s16x8 a0h0 = *(const s16x8*)(ewt0p + (16 + l16) * 64 + q * 8);
  s16x8 a0h1 = *(const s16x8*)(ewt0p + (16 + l16) * 64 + 32 + q * 8);
  s16x8 a1l0 = *(const s16x8*)(ewt1p + l16 * 64 + q * 8);
  s16x8 a1l1 = *(const s16x8*)(ewt1p + l16 * 64 + 32 + q * 8);
  s16x8 a1h0 = *(const s16x8*)(ewt1p + (16 + l16) * 64 + q * 8);
  s16x8 a1h1 = *(const s16x8*)(ewt1p + (16 + l16) * 64 + 32 + q * 8);
  // biases in lane-channel order (lo: q*8+r, hi: q*8+4+r)
  float4 b0lo = *(const float4*)(eb0 + q * 8);
  float4 b0hi = *(const float4*)(eb0 + q * 8 + 4);
  float4 b1lo = *(const float4*)(eb1 + q * 8);
  float4 b1hi = *(const float4*)(eb1 + q * 8 + 4);
  // M fragments for the head-reduce MFMA: A[row=head][k=channel q*8+j]
  s16x8 mf0, mf1;
#pragma unroll
  for (int j = 0; j < 8; ++j) {
    mf0[j] = (l16 < 4) ? (short)f2b(M0[(q * 8 + j) * 4 + l16]) : (short)0;
    mf1[j] = (l16 == 0) ? (short)f2b(M1[q * 8 + j]) : (short)0;
  }
  // coalesced preload of per-edge metadata for the 64-edge tile
  int el = ebase + lane;
  int elc = el < E ? el : E - 1;
  int sv = src[elc], dv = dst[elc], pv = perm[elc];

#pragma unroll
  for (int st = 0; st < 4; ++st) {
    int eb_t = ebase + st * 16;
    int e16 = eb_t + l16;
    int ec = e16 < E ? e16 : E - 1;
    const float* er = ea + (size_t)ec * ED;
    float4 u0 = *(const float4*)(er + q * 8);
    float4 u1 = *(const float4*)(er + q * 8 + 4);
    float4 u2 = *(const float4*)(er + 32 + q * 8);
    float4 u3 = *(const float4*)(er + 32 + q * 8 + 4);
    s16x8 bk0, bk1;
    bk0[0] = (short)f2b(u0.x); bk0[1] = (short)f2b(u0.y);
    bk0[2] = (short)f2b(u0.z); bk0[3] = (short)f2b(u0.w);
    bk0[4] = (short)f2b(u1.x); bk0[5] = (short)f2b(u1.y);
    bk0[6] = (short)f2b(u1.z); bk0[7] = (short)f2b(u1.w);
    bk1[0] = (short)f2b(u2.x); bk1[1] = (short)f2b(u2.y);
    bk1[2] = (short)f2b(u2.z); bk1[3] = (short)f2b(u2.w);
    bk1[4] = (short)f2b(u3.x); bk1[5] = (short)f2b(u3.y);
    bk1[6] = (short)f2b(u3.z); bk1[7] = (short)f2b(u3.w);
    f32x4 zl0 = {0.f,0.f,0.f,0.f}, zh0 = {0.f,0.f,0.f,0.f};
    f32x4 zl1 = {0.f,0.f,0.f,0.f}, zh1 = {0.f,0.f,0.f,0.f};
    zl0 = __builtin_amdgcn_mfma_f32_16x16x32_bf16(a0l0, bk0, zl0, 0, 0, 0);
    zl0 = __builtin_amdgcn_mfma_f32_16x16x32_bf16(a0l1, bk1, zl0, 0, 0, 0);
    zh0 = __builtin_amdgcn_mfma_f32_16x16x32_bf16(a0h0, bk0, zh0, 0, 0, 0);
    zh0 = __builtin_amdgcn_mfma_f32_16x16x32_bf16(a0h1, bk1, zh0, 0, 0, 0);
    zl1 = __builtin_amdgcn_mfma_f32_16x16x32_bf16(a1l0, bk0, zl1, 0, 0, 0);
    zl1 = __builtin_amdgcn_mfma_f32_16x16x32_bf16(a1l1, bk1, zl1, 0, 0, 0);
    zh1 = __builtin_amdgcn_mfma_f32_16x16x32_bf16(a1h0, bk0, zh1, 0, 0, 0);
    zh1 = __builtin_amdgcn_mfma_f32_16x16x32_bf16(a1h1, bk1, zh1, 0, 0, 0);
    // relu + bias, back to bf16 as B-fragment of the reduce MFMA
    s16x8 zb0, zb1;
    zb0[0] = (short)f2b(fmaxf(zl0[0] + b0lo.x, 0.f));
    zb0[1] = (short)f2b(fmaxf(zl0[1] + b0lo.y, 0.f));
    zb0[2] = (short)f2b(fmaxf(zl0[2] + b0lo.z, 0.f));
    zb0[3] = (short)f2b(fmaxf(zl0[3] + b0lo.w, 0.f));
    zb0[4] = (short)f2b(fmaxf(zh0[0] + b0hi.x, 0.f));
    zb0[5] = (short)f2b(fmaxf(zh0[1] + b0hi.y, 0.f));
    zb0[6] = (short)f2b(fmaxf(zh0[2] + b0hi.z, 0.f));
    zb0[7] = (short)f2b(fmaxf(zh0[3] + b0hi.w, 0.f));
    zb1[0] = (short)f2b(fmaxf(zl1[0] + b1lo.x, 0.f));
    zb1[1] = (short)f2b(fmaxf(zl1[1] + b1lo.y, 0.f));
    zb1[2] = (short)f2b(fmaxf(zl1[2] + b1lo.z, 0.f));
    zb1[3] = (short)f2b(fmaxf(zl1[3] + b1lo.w, 0.f));
    zb1[4] = (short)f2b(fmaxf(zh1[0] + b1hi.x, 0.f));
    zb1[5] = (short)f2b(fmaxf(zh1[1] + b1hi.y, 0.f));
    zb1[6] = (short)f2b(fmaxf(zh1[2] + b1hi.z, 0.f));
    zb1[7] = (short)f2b(fmaxf(zh1[3] + b1hi.w, 0.f));
    f32x4 r0 = {0.f,0.f,0.f,0.f}, r1 = {0.f,0.f,0.f,0.f};
    r0 = __builtin_amdgcn_mfma_f32_16x16x32_bf16(mf0, zb0, r0, 0, 0, 0);
    r1 = __builtin_amdgcn_mfma_f32_16x16x32_bf16(mf1, zb1, r1, 0, 0, 0);
    // heads of edge l16 live in lane (0,l16) regs r0[0..3]; redistribute
    float t0 = __shfl(r0[0], l16);
    float t1 = __shfl(r0[1], l16);
    float t2 = __shfl(r0[2], l16);
    float t3 = __shfl(r0[3], l16);
    float myale0 = q == 0 ? t0 : (q == 1 ? t1 : (q == 2 ? t2 : t3));
    float myale1 = __shfl(r1[0], l16);
    int srcl = st * 16 + l16;
    int s = __shfl(sv, srcl);
    int d = __shfl(dv, srcl);
    int p = __shfl(pv, srcl);
    float alef = myale0 * escore0[s];
    float aa = al_src0[(size_t)s * 4 + q] + al_dst0[(size_t)d * 4 + q] + alef;
    float lr = aa > 0.f ? aa : 0.2f * aa;
    float ev = __expf(lr);
    if (e16 < E) {
      exv0[(size_t)p * 4 + q] = ev;
      alev0[(size_t)p * 4 + q] = alef;
      if (q == 0) ale1raw[p] = myale1;
    }
  }
}

// ---------- layer-1 edge finish: alpha/exp from stored raw ale (H=1) ----------
__global__ __launch_bounds__(256)
void edge_finish_kernel(const int* __restrict__ src_ord, const int* __restrict__ dst_ord,
                        const float* __restrict__ ale1raw,
                        const float* __restrict__ al_src, const float* __restrict__ al_dst,
                        const float* __restrict__ escore,
                        float* __restrict__ exv, float* __restrict__ alev, int E) {
  int p = blockIdx.x * 256 + threadIdx.x;
  if (p >= E) return;
  int s = src_ord[p], d = dst_ord[p];
  float alef = ale1raw[p] * escore[s];
  float aa = al_src[s] + al_dst[d] + alef;
  float lr = aa > 0.f ? aa : 0.2f * aa;
  exv[p] = __expf(lr);
  alev[p] = alef;
}

// ---------- CSR aggregation (4-unrolled gathers) + self-loop + bias + residual ----------
template<int H, bool RELU, bool ADD_ORIG>
__global__ __launch_bounds__(256)
void agg_kernel(const int* __restrict__ rowptr, const int* __restrict__ src_ord,
                const float* __restrict__ xs, const float* __restrict__ exv,
                const float* __restrict__ alev,
                const float* __restrict__ al_src, const float* __restrict__ al_dst,
                const float* __restrict__ bias, const float* __restrict__ xin,
                const float* __restrict__ orig, float* __restrict__ out, int n) {
  constexpr int C = D / H;
  int wid = blockIdx.x * 4 + (threadIdx.x >> 6);
  int lane = threadIdx.x & 63;
  if (wid >= n) return;
  int h0 = (2 * lane) / C;
  const float2* xs2 = (const float2*)xs;
  float ax = 0.f, ay = 0.f, den = 0.f, sale = 0.f;
  int b = rowptr[wid], e = rowptr[wid + 1];
  int idx = b;
  for (; idx + 4 <= e; idx += 4) {
    int s0 = src_ord[idx], s1 = src_ord[idx + 1];
    int s2 = src_ord[idx + 2], s3 = src_ord[idx + 3];
    float ev0 = exv[(size_t)(idx + 0) * H + h0];
    float ev1 = exv[(size_t)(idx + 1) * H + h0];
    float ev2 = exv[(size_t)(idx + 2) * H + h0];
    float ev3 = exv[(size_t)(idx + 3) * H + h0];
    float a0 = alev[(size_t)(idx + 0) * H + h0];
    float a1 = alev[(size_t)(idx + 1) * H + h0];
    float a2 = alev[(size_t)(idx + 2) * H + h0];
    float a3 = alev[(size_t)(idx + 3) * H + h0];
    float2 v0 = xs2[(size_t)s0 * 64 + lane];
    float2 v1 = xs2[(size_t)s1 * 64 + lane];
    float2 v2 = xs2[(size_t)s2 * 64 + lane];
    float2 v3 = xs2[(size_t)s3 * 64 + lane];
    ax = fmaf(ev0, v0.x, ax); ay = fmaf(ev0, v0.y, ay);
    ax = fmaf(ev1, v1.x, ax); ay = fmaf(ev1, v1.y, ay);
    ax = fmaf(ev2, v2.x, ax); ay = fmaf(ev2, v2.y, ay);
    ax = fmaf(ev3, v3.x, ax); ay = fmaf(ev3, v3.y, ay);
    den += (ev0 + ev1) + (ev2 + ev3);
    sale += (a0 + a1) + (a2 + a3);
  }
  for (; idx < e; ++idx) {
    int s = src_ord[idx];
    float ev = exv[(size_t)idx * H + h0];
    float al = alev[(size_t)idx * H + h0];
    float2 v = xs2[(size_t)s * 64 + lane];
    ax = fmaf(ev, v.x, ax); ay = fmaf(ev, v.y, ay);
    den += ev; sale += al;
  }
  // self-loop: attr = mean of incoming ale (linear in attr)
  int deg = e - b;
  float la = sale / (float)(deg > 1 ? deg : 1);
  float a = al_src[(size_t)wid * H + h0] + al_dst[(size_t)wid * H + h0] + la;
  float lr = a > 0.f ? a : 0.2f * a;
  float evl = expf(lr);
  {
    float2 v = xs2[(size_t)wid * 64 + lane];
    ax = fmaf(evl, v.x, ax); ay = fmaf(evl, v.y, ay);
  }
  float dinv = 1.f / (den + evl + 1e-16f);
  float2 bi = ((const float2*)bias)[lane];
  float2 xi = ((const float2*)xin)[(size_t)wid * 64 + lane];
  ax = ax * dinv + bi.x + xi.x;
  ay = ay * dinv + bi.y + xi.y;
  if (ADD_ORIG) {
    float2 og = ((const float2*)orig)[(size_t)wid * 64 + lane];
    ax += og.x; ay += og.y;
  }
  if (RELU) { ax = fmaxf(ax, 0.f); ay = fmaxf(ay, 0.f); }
  ((float2*)out)[(size_t)wid * 64 + lane] = make_float2(ax, ay);
}

extern "C" void kernel_launch(void* const* d_in, const int* in_sizes, int n_in,
                              void* d_out, int out_size, void* d_ws, size_t ws_size,
                              hipStream_t stream) {
  const float* x   = (const float*)d_in[0];
  const int*   ei  = (const int*)d_in[1];
  const float* ea  = (const float*)d_in[2];
  const float* ew0 = (const float*)d_in[3];
  const float* eb0 = (const float*)d_in[4];
  const float* ew1 = (const float*)d_in[5];
  const float* eb1 = (const float*)d_in[6];
  const float* ow0 = (const float*)d_in[7];
  const float* ob0 = (const float*)d_in[8];
  const float* ow1 = (const float*)d_in[9];
  const float* ob1 = (const float*)d_in[10];
  const float* g0W = (const float*)d_in[11];
  const float* g0as= (const float*)d_in[12];
  const float* g0ad= (const float*)d_in[13];
  const float* g0We= (const float*)d_in[14];
  const float* g0ae= (const float*)d_in[15];
  const float* g0b = (const float*)d_in[16];
  const float* g1W = (const float*)d_in[17];
  const float* g1as= (const float*)d_in[18];
  const float* g1ad= (const float*)d_in[19];
  const float* g1We= (const float*)d_in[20];
  const float* g1ae= (const float*)d_in[21];
  const float* g1b = (const float*)d_in[22];
  float* out = (float*)d_out;

  const int N = in_sizes[0] / D;
  const int E = in_sizes[1] / 2;
  const int* srcp = ei;
  const int* dstp = ei + E;

  char* w = (char*)d_ws;
  size_t off = 0;
  auto alloc = [&](size_t bytes) {
    void* p = w + off;
    off += (bytes + 255) & ~(size_t)255;
    return p;
  };
  float* xs      = (float*)alloc((size_t)N * D * 4);
  float* exv     = (float*)alloc((size_t)E * 4 * 4);
  float* alev    = (float*)alloc((size_t)E * 4 * 4);
  float* ale1raw = (float*)alloc((size_t)E * 4);
  float* al_src  = (float*)alloc((size_t)N * 4 * 4);
  float* al_dst  = (float*)alloc((size_t)N * 4 * 4);
  float* escore  = (float*)alloc((size_t)N * 4);
  float* M0      = (float*)alloc(HD * 4 * 4);
  float* M1      = (float*)alloc(HD * 4);
  unsigned short* Wt0 = (unsigned short*)alloc((size_t)D * D * 2);
  unsigned short* Wt1 = (unsigned short*)alloc((size_t)D * D * 2);
  unsigned short* ewt0 = (unsigned short*)alloc((size_t)HD * ED * 2);
  unsigned short* ewt1 = (unsigned short*)alloc((size_t)HD * ED * 2);
  int*   cnt     = (int*)alloc((size_t)N * 4);
  int*   rowptr  = (int*)alloc((size_t)(N + 1) * 4);
  int*   cursor  = (int*)alloc((size_t)N * 4);
  int*   perm    = (int*)alloc((size_t)E * 4);
  int*   src_ord = (int*)alloc((size_t)E * 4);
  int*   dst_ord = (int*)alloc((size_t)E * 4);

  int egrid  = (E + 255) / 256;
  int ngrid4 = (N + 3) / 4;
  int ggrid  = (N + 63) / 64;

  // ---- CSR build (shared by both layers) + weight prep ----
  hipMemsetAsync(cnt, 0, (size_t)N * 4, stream);
  hipMemsetAsync(cursor, 0, (size_t)N * 4, stream);
  count_kernel<<<egrid, 256, 0, stream>>>(dstp, cnt, E);
  scan_kernel<<<1, 1024, 0, stream>>>(cnt, rowptr, N);
  fill_kernel<<<egrid, 256, 0, stream>>>(srcp, dstp, rowptr, cursor, perm,
                                         src_ord, dst_ord, E);
  prep_M_kernel<4><<<1, 128, 0, stream>>>(g0We, g0ae, M0);
  prep_M_kernel<1><<<1, 32, 0, stream>>>(g1We, g1ae, M1);
  prep_Wt_kernel<<<64, 256, 0, stream>>>(g0W, Wt0);
  prep_Wt_kernel<<<64, 256, 0, stream>>>(g1W, Wt1);
  prep_ewt_kernel<<<8, 256, 0, stream>>>(ew0, ewt0);
  prep_ewt_kernel<<<8, 256, 0, stream>>>(ew1, ewt1);

  // ---- layer 0 (H=4): node GEMM, logits, fused edge pass (both encoders), agg ----
  node_gemm_mfma<<<ggrid, 256, 0, stream>>>(x, Wt0, xs, N);
  node_al_kernel<4><<<ngrid4, 256, 0, stream>>>(xs, x, g0as, g0ad, ow0, ob0,
                                                al_src, al_dst, escore, N);
  edge_fused_kernel<<<egrid, 256, 0, stream>>>(srcp, dstp, ea, ewt0, ewt1,
                                               eb0, eb1, M0, M1,
                                               al_src, al_dst, escore, perm,
                                               exv, alev, ale1raw, E);
  agg_kernel<4, true, false><<<ngrid4, 256, 0, stream>>>(rowptr, src_ord,
                                                         xs, exv, alev,
                                                         al_src, al_dst,
                                                         g0b, x, nullptr, out, N);

  // ---- layer 1 (H=1): node GEMM, logits, edge finish, agg ----
  node_gemm_mfma<<<ggrid, 256, 0, stream>>>(out, Wt1, xs, N);
  node_al_kernel<1><<<ngrid4, 256, 0, stream>>>(xs, out, g1as, g1ad, ow1, ob1,
                                                al_src, al_dst, escore, N);
  edge_finish_kernel<<<egrid, 256, 0, stream>>>(src_ord, dst_ord, ale1raw,
                                                al_src, al_dst, escore,
                                                exv, alev, E);
  agg_kernel<1, false, true><<<ngrid4, 256, 0, stream>>>(rowptr, src_ord,
                                                         xs, exv, alev,
                                                         al_src, al_dst,
                                                         g1b, out, x, out, N);
}

// Round 6
// 416.528 us; speedup vs baseline: 2.7461x; 1.0378x over previous
//
#include <hip/hip_runtime.h>
#include <math.h>

#define D 128
#define ED 64
#define HD 32

typedef short s16x8 __attribute__((ext_vector_type(8)));
typedef float f32x4 __attribute__((ext_vector_type(4)));

// f32 -> bf16 bits, round-to-nearest-even
static __device__ inline unsigned short f2b(float f) {
  unsigned int u = __float_as_uint(f);
  unsigned int r = (u + 0x7fff + ((u >> 16) & 1)) >> 16;
  return (unsigned short)r;
}

// ---------- CSR build ----------
__global__ __launch_bounds__(256)
void count_kernel(const int* __restrict__ dst, int* __restrict__ cnt, int E) {
  int e = blockIdx.x * 256 + threadIdx.x;
  if (e < E) atomicAdd(&cnt[dst[e]], 1);
}

__global__ __launch_bounds__(1024)
void scan_kernel(const int* __restrict__ cnt, int* __restrict__ rowptr, int n) {
  __shared__ int part[1024];
  int t = threadIdx.x;
  int chunk = (n + 1023) >> 10;
  int b = t * chunk, e = min(b + chunk, n);
  int s = 0;
  for (int i = b; i < e; ++i) s += cnt[i];
  part[t] = s;
  __syncthreads();
  for (int off = 1; off < 1024; off <<= 1) {
    int add = (t >= off) ? part[t - off] : 0;
    __syncthreads();
    part[t] += add;
    __syncthreads();
  }
  int run = part[t] - s;
  for (int i = b; i < e; ++i) { rowptr[i] = run; run += cnt[i]; }
  if (t == 1023) rowptr[n] = part[1023];
}

// fill: eorder[slot] = original edge id; src_ord[slot] = src[e]
__global__ __launch_bounds__(256)
void fill_kernel(const int* __restrict__ src, const int* __restrict__ dst,
                 const int* __restrict__ rowptr, int* __restrict__ cursor,
                 int* __restrict__ eorder, int* __restrict__ src_ord, int E) {
  int e = blockIdx.x * 256 + threadIdx.x;
  if (e < E) {
    int d = dst[e];
    int p = atomicAdd(&cursor[d], 1);
    int slot = rowptr[d] + p;
    eorder[slot] = e;
    src_ord[slot] = src[e];
  }
}

// ---------- M[d,h] = sum_c We[d, h*C+c] * ae[h,c] ----------
template<int H>
__global__ void prep_M_kernel(const float* __restrict__ We, const float* __restrict__ ae,
                              float* __restrict__ M) {
  constexpr int C = D / H;
  int t = threadIdx.x;
  if (t < HD * H) {
    int d = t / H, h = t - d * H;
    float s = 0.f;
    for (int c = 0; c < C; ++c) s += We[d * D + h * C + c] * ae[h * C + c];
    M[d * H + h] = s;
  }
}

// ---------- Wt[n][k] = bf16(W[k][n])  (transpose+convert, 128x128) ----------
__global__ __launch_bounds__(256)
void prep_Wt_kernel(const float* __restrict__ W, unsigned short* __restrict__ Wt) {
  int id = blockIdx.x * 256 + threadIdx.x;   // 0..16383
  int nn = id >> 7, k = id & 127;
  Wt[id] = f2b(W[k * D + nn]);
}

// ---------- permuted ewt: row i holds ew column ch(i) ----------
__global__ __launch_bounds__(256)
void prep_ewt_kernel(const float* __restrict__ ew, unsigned short* __restrict__ ewt) {
  int id = blockIdx.x * 256 + threadIdx.x;   // 0..2047
  if (id < HD * ED) {
    int i = id >> 6, k = id & 63;
    int ch = (i < 16) ? ((i >> 2) * 8 + (i & 3))
                      : (((i - 16) >> 2) * 8 + 4 + ((i - 16) & 3));
    ewt[id] = f2b(ew[k * HD + ch]);
  }
}

// ---------- fused: xs = x @ W (MFMA) + al_src/al_dst/escore epilogue ----------
// A: row=l16, k=(q)*8+j per 32-k step; D: row=base+q*4+r, col=nf*16+l16.
template<int H>
__global__ __launch_bounds__(256)
void node_gemm_al(const float* __restrict__ x, const unsigned short* __restrict__ Wt,
                  const float* __restrict__ a_s, const float* __restrict__ a_d,
                  const float* __restrict__ ow, const float* __restrict__ ob,
                  float* __restrict__ xs, float* __restrict__ al_src,
                  float* __restrict__ al_dst, float* __restrict__ escore, int n) {
  int wave = threadIdx.x >> 6;
  int lane = threadIdx.x & 63;
  int q = lane >> 4;
  int l16 = lane & 15;
  int base = blockIdx.x * 64 + wave * 16;
  int rowRaw = base + l16;
  int row = rowRaw < n ? rowRaw : n - 1;
  const float* xrow = x + (size_t)row * D;
  s16x8 a[4];
  float scp = 0.f;
#pragma unroll
  for (int kk = 0; kk < 4; ++kk) {
    int kb = kk * 32 + q * 8;
    float4 v0 = *(const float4*)(xrow + kb);
    float4 v1 = *(const float4*)(xrow + kb + 4);
    float4 o0 = *(const float4*)(ow + kb);
    float4 o1 = *(const float4*)(ow + kb + 4);
    scp += v0.x * o0.x + v0.y * o0.y + v0.z * o0.z + v0.w * o0.w
         + v1.x * o1.x + v1.y * o1.y + v1.z * o1.z + v1.w * o1.w;
    s16x8 t;
    t[0] = (short)f2b(v0.x); t[1] = (short)f2b(v0.y);
    t[2] = (short)f2b(v0.z); t[3] = (short)f2b(v0.w);
    t[4] = (short)f2b(v1.x); t[5] = (short)f2b(v1.y);
    t[6] = (short)f2b(v1.z); t[7] = (short)f2b(v1.w);
    a[kk] = t;
  }
  // escore: reduce across the 4 q-lanes sharing row base+l16
  scp += __shfl_xor(scp, 16);
  scp += __shfl_xor(scp, 32);
  if (q == 0 && rowRaw < n) escore[rowRaw] = __expf(scp + ob[0]);

  f32x4 acc[8];
#pragma unroll
  for (int nf = 0; nf < 8; ++nf) { f32x4 z = {0.f, 0.f, 0.f, 0.f}; acc[nf] = z; }
#pragma unroll
  for (int kk = 0; kk < 4; ++kk) {
    int kb = kk * 32 + q * 8;
#pragma unroll
    for (int nf = 0; nf < 8; ++nf) {
      s16x8 b = *(const s16x8*)(Wt + (size_t)(nf * 16 + l16) * D + kb);
      acc[nf] = __builtin_amdgcn_mfma_f32_16x16x32_bf16(a[kk], b, acc[nf], 0, 0, 0);
    }
  }
#pragma unroll
  for (int nf = 0; nf < 8; ++nf) {
#pragma unroll
    for (int r = 0; r < 4; ++r) {
      int rr = base + q * 4 + r;
      if (rr < n) xs[(size_t)rr * D + nf * 16 + l16] = acc[nf][r];
    }
  }
  // ---- attention-logit epilogue from acc fragments ----
  // col = nf*16+l16; flat index into a_s/a_d is nf*16+l16 for both H=4 and H=1
  float asv[8], adv[8];
#pragma unroll
  for (int nf = 0; nf < 8; ++nf) { asv[nf] = a_s[nf * 16 + l16]; adv[nf] = a_d[nf * 16 + l16]; }
  if (H == 4) {
    float mys = 0.f, myd = 0.f;
#pragma unroll
    for (int r = 0; r < 4; ++r) {
#pragma unroll
      for (int h = 0; h < 4; ++h) {
        float vs = acc[2 * h][r] * asv[2 * h] + acc[2 * h + 1][r] * asv[2 * h + 1];
        float vd = acc[2 * h][r] * adv[2 * h] + acc[2 * h + 1][r] * adv[2 * h + 1];
        vs += __shfl_xor(vs, 1); vd += __shfl_xor(vd, 1);
        vs += __shfl_xor(vs, 2); vd += __shfl_xor(vd, 2);
        vs += __shfl_xor(vs, 4); vd += __shfl_xor(vd, 4);
        vs += __shfl_xor(vs, 8); vd += __shfl_xor(vd, 8);
        if (l16 == r * 4 + h) { mys = vs; myd = vd; }
      }
    }
    int orow = base + q * 4 + (l16 >> 2);
    if (orow < n) {
      al_src[(size_t)orow * 4 + (l16 & 3)] = mys;   // = al_src[base*4 + lane], coalesced
      al_dst[(size_t)orow * 4 + (l16 & 3)] = myd;
    }
  } else {
    float mys = 0.f, myd = 0.f;
#pragma unroll
    for (int r = 0; r < 4; ++r) {
      float vs = 0.f, vd = 0.f;
#pragma unroll
      for (int nf = 0; nf < 8; ++nf) { vs = fmaf(acc[nf][r], asv[nf], vs); vd = fmaf(acc[nf][r], adv[nf], vd); }
      vs += __shfl_xor(vs, 1); vd += __shfl_xor(vd, 1);
      vs += __shfl_xor(vs, 2); vd += __shfl_xor(vd, 2);
      vs += __shfl_xor(vs, 4); vd += __shfl_xor(vd, 4);
      vs += __shfl_xor(vs, 8); vd += __shfl_xor(vd, 8);
      if (l16 == r) { mys = vs; myd = vd; }
    }
    int orow = base + q * 4 + l16;
    if (l16 < 4 && orow < n) { al_src[orow] = mys; al_dst[orow] = myd; }
  }
}

// ---------- fused edge pass: both encoders, edge-order streaming writes ----------
__global__ __launch_bounds__(256)
void edge_fused_kernel(const int* __restrict__ src, const int* __restrict__ dst,
                       const float* __restrict__ ea,
                       const unsigned short* __restrict__ ewt0p,
                       const unsigned short* __restrict__ ewt1p,
                       const float* __restrict__ eb0, const float* __restrict__ eb1,
                       const float* __restrict__ M0,   // [32][4]
                       const float* __restrict__ M1,   // [32]
                       const float* __restrict__ al_src0, const float* __restrict__ al_dst0,
                       const float* __restrict__ escore0,
                       float* __restrict__ exv0, float* __restrict__ alev0,
                       float* __restrict__ ale1raw, int E) {
  int wave = threadIdx.x >> 6, lane = threadIdx.x & 63;
  int q = lane >> 4, l16 = lane & 15;
  int ebase = (blockIdx.x * 4 + wave) * 64;
  if (ebase >= E) return;
  s16x8 a0l0 = *(const s16x8*)(ewt0p + l16 * 64 + q * 8);
  s16x8 a0l1 = *(const s16x8*)(ewt0p + l16 * 64 + 32 + q * 8);
  s16x8 a0h0 = *(const s16x8*)(ewt0p + (16 + l16) * 64 + q * 8);
  s16x8 a0h1 = *(const s16x8*)(ewt0p + (16 + l16) * 64 + 32 + q * 8);
  s16x8 a1l0 = *(const s16x8*)(ewt1p + l16 * 64 + q * 8);
  s16x8 a1l1 = *(const s16x8*)(ewt1p + l16 * 64 + 32 + q * 8);
  s16x8 a1h0 = *(const s16x8*)(ewt1p + (16 + l16) * 64 + q * 8);
  s16x8 a1h1 = *(const s16x8*)(ewt1p + (16 + l16) * 64 + 32 + q * 8);
  float4 b0lo = *(const float4*)(eb0 + q * 8);
  float4 b0hi = *(const float4*)(eb0 + q * 8 + 4);
  float4 b1lo = *(const float4*)(eb1 + q * 8);
  float4 b1hi = *(const float4*)(eb1 + q * 8 + 4);
  s16x8 mf0, mf1;
#pragma unroll
  for (int j = 0; j < 8; ++j) {
    mf0[j] = (l16 < 4) ? (short)f2b(M0[(q * 8 + j) * 4 + l16]) : (short)0;
    mf1[j] = (l16 == 0) ? (short)f2b(M1[q * 8 + j]) : (short)0;
  }
  int el = ebase + lane;
  int elc = el < E ? el : E - 1;
  int sv = src[elc], dv = dst[elc];

#pragma unroll
  for (int st = 0; st < 4; ++st) {
    int eb_t = ebase + st * 16;
    int e16 = eb_t + l16;
    int ec = e16 < E ? e16 : E - 1;
    const float* er = ea + (size_t)ec * ED;
    float4 u0 = *(const float4*)(er + q * 8);
    float4 u1 = *(const float4*)(er + q * 8 + 4);
    float4 u2 = *(const float4*)(er + 32 + q * 8);
    float4 u3 = *(const float4*)(er + 32 + q * 8 + 4);
    s16x8 bk0, bk1;
    bk0[0] = (short)f2b(u0.x); bk0[1] = (short)f2b(u0.y);
    bk0[2] = (short)f2b(u0.z); bk0[3] = (short)f2b(u0.w);
    bk0[4] = (short)f2b(u1.x); bk0[5] = (short)f2b(u1.y);
    bk0[6] = (short)f2b(u1.z); bk0[7] = (short)f2b(u1.w);
    bk1[0] = (short)f2b(u2.x); bk1[1] = (short)f2b(u2.y);
    bk1[2] = (short)f2b(u2.z); bk1[3] = (short)f2b(u2.w);
    bk1[4] = (short)f2b(u3.x); bk1[5] = (short)f2b(u3.y);
    bk1[6] = (short)f2b(u3.z); bk1[7] = (short)f2b(u3.w);
    f32x4 zl0 = {0.f,0.f,0.f,0.f}, zh0 = {0.f,0.f,0.f,0.f};
    f32x4 zl1 = {0.f,0.f,0.f,0.f}, zh1 = {0.f,0.f,0.f,0.f};
    zl0 = __builtin_amdgcn_mfma_f32_16x16x32_bf16(a0l0, bk0, zl0, 0, 0, 0);
    zl0 = __builtin_amdgcn_mfma_f32_16x16x32_bf16(a0l1, bk1, zl0, 0, 0, 0);
    zh0 = __builtin_amdgcn_mfma_f32_16x16x32_bf16(a0h0, bk0, zh0, 0, 0, 0);
    zh0 = __builtin_amdgcn_mfma_f32_16x16x32_bf16(a0h1, bk1, zh0, 0, 0, 0);
    zl1 = __builtin_amdgcn_mfma_f32_16x16x32_bf16(a1l0, bk0, zl1, 0, 0, 0);
    zl1 = __builtin_amdgcn_mfma_f32_16x16x32_bf16(a1l1, bk1, zl1, 0, 0, 0);
    zh1 = __builtin_amdgcn_mfma_f32_16x16x32_bf16(a1h0, bk0, zh1, 0, 0, 0);
    zh1 = __builtin_amdgcn_mfma_f32_16x16x32_bf16(a1h1, bk1, zh1, 0, 0, 0);
    s16x8 zb0, zb1;
    zb0[0] = (short)f2b(fmaxf(zl0[0] + b0lo.x, 0.f));
    zb0[1] = (short)f2b(fmaxf(zl0[1] + b0lo.y, 0.f));
    zb0[2] = (short)f2b(fmaxf(zl0[2] + b0lo.z, 0.f));
    zb0[3] = (short)f2b(fmaxf(zl0[3] + b0lo.w, 0.f));
    zb0[4] = (short)f2b(fmaxf(zh0[0] + b0hi.x, 0.f));
    zb0[5] = (short)f2b(fmaxf(zh0[1] + b0hi.y, 0.f));
    zb0[6] = (short)f2b(fmaxf(zh0[2] + b0hi.z, 0.f));
    zb0[7] = (short)f2b(fmaxf(zh0[3] + b0hi.w, 0.f));
    zb1[0] = (short)f2b(fmaxf(zl1[0] + b1lo.x, 0.f));
    zb1[1] = (short)f2b(fmaxf(zl1[1] + b1lo.y, 0.f));
    zb1[2] = (short)f2b(fmaxf(zl1[2] + b1lo.z, 0.f));
    zb1[3] = (short)f2b(fmaxf(zl1[3] + b1lo.w, 0.f));
    zb1[4] = (short)f2b(fmaxf(zh1[0] + b1hi.x, 0.f));
    zb1[5] = (short)f2b(fmaxf(zh1[1] + b1hi.y, 0.f));
    zb1[6] = (short)f2b(fmaxf(zh1[2] + b1hi.z, 0.f));
    zb1[7] = (short)f2b(fmaxf(zh1[3] + b1hi.w, 0.f));
    f32x4 r0 = {0.f,0.f,0.f,0.f}, r1 = {0.f,0.f,0.f,0.f};
    r0 = __builtin_amdgcn_mfma_f32_16x16x32_bf16(mf0, zb0, r0, 0, 0, 0);
    r1 = __builtin_amdgcn_mfma_f32_16x16x32_bf16(mf1, zb1, r1, 0, 0, 0);
    float t0 = __shfl(r0[0], l16);
    float t1 = __shfl(r0[1], l16);
    float t2 = __shfl(r0[2], l16);
    float t3 = __shfl(r0[3], l16);
    float myale0 = q == 0 ? t0 : (q == 1 ? t1 : (q == 2 ? t2 : t3));
    float myale1 = __shfl(r1[0], l16);
    int srcl = st * 16 + l16;
    int s = __shfl(sv, srcl);
    int d = __shfl(dv, srcl);
    float alef = myale0 * escore0[s];
    float aa = al_src0[(size_t)s * 4 + q] + al_dst0[(size_t)d * 4 + q] + alef;
    float lr = aa > 0.f ? aa : 0.2f * aa;
    float ev = __expf(lr);
    if (e16 < E) {
      exv0[(size_t)e16 * 4 + q] = ev;     // edge-order, coalesced
      alev0[(size_t)e16 * 4 + q] = alef;
      if (q == 0) ale1raw[e16] = myale1;
    }
  }
}

// ---------- layer-1 edge finish (edge order, fully streaming) ----------
__global__ __launch_bounds__(256)
void edge_finish_kernel(const int* __restrict__ src, const int* __restrict__ dst,
                        const float* __restrict__ ale1raw,
                        const float* __restrict__ al_src, const float* __restrict__ al_dst,
                        const float* __restrict__ escore,
                        float* __restrict__ exv, float* __restrict__ alev, int E) {
  int e = blockIdx.x * 256 + threadIdx.x;
  if (e >= E) return;
  int s = src[e], d = dst[e];
  float alef = ale1raw[e] * escore[s];
  float aa = al_src[s] + al_dst[d] + alef;
  float lr = aa > 0.f ? aa : 0.2f * aa;
  exv[e] = __expf(lr);
  alev[e] = alef;
}

// ---------- CSR aggregation (4-unrolled gathers) + self-loop + bias + residual ----------
template<int H, bool RELU, bool ADD_ORIG>
__global__ __launch_bounds__(256)
void agg_kernel(const int* __restrict__ rowptr, const int* __restrict__ src_ord,
                const int* __restrict__ eorder,
                const float* __restrict__ xs, const float* __restrict__ exv,
                const float* __restrict__ alev,
                const float* __restrict__ al_src, const float* __restrict__ al_dst,
                const float* __restrict__ bias, const float* __restrict__ xin,
                const float* __restrict__ orig, float* __restrict__ out, int n) {
  constexpr int C = D / H;
  int wid = blockIdx.x * 4 + (threadIdx.x >> 6);
  int lane = threadIdx.x & 63;
  if (wid >= n) return;
  int h0 = (2 * lane) / C;
  const float2* xs2 = (const float2*)xs;
  float ax = 0.f, ay = 0.f, den = 0.f, sale = 0.f;
  int b = rowptr[wid], e = rowptr[wid + 1];
  int idx = b;
  for (; idx + 4 <= e; idx += 4) {
    int s0 = src_ord[idx], s1 = src_ord[idx + 1];
    int s2 = src_ord[idx + 2], s3 = src_ord[idx + 3];
    int e0 = eorder[idx], e1 = eorder[idx + 1];
    int e2 = eorder[idx + 2], e3 = eorder[idx + 3];
    float ev0 = exv[(size_t)e0 * H + h0];
    float ev1 = exv[(size_t)e1 * H + h0];
    float ev2 = exv[(size_t)e2 * H + h0];
    float ev3 = exv[(size_t)e3 * H + h0];
    float a0 = alev[(size_t)e0 * H + h0];
    float a1 = alev[(size_t)e1 * H + h0];
    float a2 = alev[(size_t)e2 * H + h0];
    float a3 = alev[(size_t)e3 * H + h0];
    float2 v0 = xs2[(size_t)s0 * 64 + lane];
    float2 v1 = xs2[(size_t)s1 * 64 + lane];
    float2 v2 = xs2[(size_t)s2 * 64 + lane];
    float2 v3 = xs2[(size_t)s3 * 64 + lane];
    ax = fmaf(ev0, v0.x, ax); ay = fmaf(ev0, v0.y, ay);
    ax = fmaf(ev1, v1.x, ax); ay = fmaf(ev1, v1.y, ay);
    ax = fmaf(ev2, v2.x, ax); ay = fmaf(ev2, v2.y, ay);
    ax = fmaf(ev3, v3.x, ax); ay = fmaf(ev3, v3.y, ay);
    den += (ev0 + ev1) + (ev2 + ev3);
    sale += (a0 + a1) + (a2 + a3);
  }
  for (; idx < e; ++idx) {
    int s = src_ord[idx];
    int ed = eorder[idx];
    float ev = exv[(size_t)ed * H + h0];
    float al = alev[(size_t)ed * H + h0];
    float2 v = xs2[(size_t)s * 64 + lane];
    ax = fmaf(ev, v.x, ax); ay = fmaf(ev, v.y, ay);
    den += ev; sale += al;
  }
  int deg = e - b;
  float la = sale / (float)(deg > 1 ? deg : 1);
  float a = al_src[(size_t)wid * H + h0] + al_dst[(size_t)wid * H + h0] + la;
  float lr = a > 0.f ? a : 0.2f * a;
  float evl = expf(lr);
  {
    float2 v = xs2[(size_t)wid * 64 + lane];
    ax = fmaf(evl, v.x, ax); ay = fmaf(evl, v.y, ay);
  }
  float dinv = 1.f / (den + evl + 1e-16f);
  float2 bi = ((const float2*)bias)[lane];
  float2 xi = ((const float2*)xin)[(size_t)wid * 64 + lane];
  ax = ax * dinv + bi.x + xi.x;
  ay = ay * dinv + bi.y + xi.y;
  if (ADD_ORIG) {
    float2 og = ((const float2*)orig)[(size_t)wid * 64 + lane];
    ax += og.x; ay += og.y;
  }
  if (RELU) { ax = fmaxf(ax, 0.f); ay = fmaxf(ay, 0.f); }
  ((float2*)out)[(size_t)wid * 64 + lane] = make_float2(ax, ay);
}

extern "C" void kernel_launch(void* const* d_in, const int* in_sizes, int n_in,
                              void* d_out, int out_size, void* d_ws, size_t ws_size,
                              hipStream_t stream) {
  const float* x   = (const float*)d_in[0];
  const int*   ei  = (const int*)d_in[1];
  const float* ea  = (const float*)d_in[2];
  const float* ew0 = (const float*)d_in[3];
  const float* eb0 = (const float*)d_in[4];
  const float* ew1 = (const float*)d_in[5];
  const float* eb1 = (const float*)d_in[6];
  const float* ow0 = (const float*)d_in[7];
  const float* ob0 = (const float*)d_in[8];
  const float* ow1 = (const float*)d_in[9];
  const float* ob1 = (const float*)d_in[10];
  const float* g0W = (const float*)d_in[11];
  const float* g0as= (const float*)d_in[12];
  const float* g0ad= (const float*)d_in[13];
  const float* g0We= (const float*)d_in[14];
  const float* g0ae= (const float*)d_in[15];
  const float* g0b = (const float*)d_in[16];
  const float* g1W = (const float*)d_in[17];
  const float* g1as= (const float*)d_in[18];
  const float* g1ad= (const float*)d_in[19];
  const float* g1We= (const float*)d_in[20];
  const float* g1ae= (const float*)d_in[21];
  const float* g1b = (const float*)d_in[22];
  float* out = (float*)d_out;

  const int N = in_sizes[0] / D;
  const int E = in_sizes[1] / 2;
  const int* srcp = ei;
  const int* dstp = ei + E;

  char* w = (char*)d_ws;
  size_t off = 0;
  auto alloc = [&](size_t bytes) {
    void* p = w + off;
    off += (bytes + 255) & ~(size_t)255;
    return p;
  };
  float* xs      = (float*)alloc((size_t)N * D * 4);
  float* exv     = (float*)alloc((size_t)E * 4 * 4);
  float* alev    = (float*)alloc((size_t)E * 4 * 4);
  float* ale1raw = (float*)alloc((size_t)E * 4);
  float* al_src  = (float*)alloc((size_t)N * 4 * 4);
  float* al_dst  = (float*)alloc((size_t)N * 4 * 4);
  float* escore  = (float*)alloc((size_t)N * 4);
  float* M0      = (float*)alloc(HD * 4 * 4);
  float* M1      = (float*)alloc(HD * 4);
  unsigned short* Wt0 = (unsigned short*)alloc((size_t)D * D * 2);
  unsigned short* Wt1 = (unsigned short*)alloc((size_t)D * D * 2);
  unsigned short* ewt0 = (unsigned short*)alloc((size_t)HD * ED * 2);
  unsigned short* ewt1 = (unsigned short*)alloc((size_t)HD * ED * 2);
  int*   cnt     = (int*)alloc((size_t)N * 4);
  int*   rowptr  = (int*)alloc((size_t)(N + 1) * 4);
  int*   cursor  = (int*)alloc((size_t)N * 4);
  int*   eorder  = (int*)alloc((size_t)E * 4);
  int*   src_ord = (int*)alloc((size_t)E * 4);

  int egrid  = (E + 255) / 256;
  int ngrid4 = (N + 3) / 4;
  int ggrid  = (N + 63) / 64;

  // ---- CSR build (shared by both layers) + weight prep ----
  hipMemsetAsync(cnt, 0, (size_t)N * 4, stream);
  hipMemsetAsync(cursor, 0, (size_t)N * 4, stream);
  count_kernel<<<egrid, 256, 0, stream>>>(dstp, cnt, E);
  scan_kernel<<<1, 1024, 0, stream>>>(cnt, rowptr, N);
  fill_kernel<<<egrid, 256, 0, stream>>>(srcp, dstp, rowptr, cursor,
                                         eorder, src_ord, E);
  prep_M_kernel<4><<<1, 128, 0, stream>>>(g0We, g0ae, M0);
  prep_M_kernel<1><<<1, 32, 0, stream>>>(g1We, g1ae, M1);
  prep_Wt_kernel<<<64, 256, 0, stream>>>(g0W, Wt0);
  prep_Wt_kernel<<<64, 256, 0, stream>>>(g1W, Wt1);
  prep_ewt_kernel<<<8, 256, 0, stream>>>(ew0, ewt0);
  prep_ewt_kernel<<<8, 256, 0, stream>>>(ew1, ewt1);

  // ---- layer 0 (H=4): fused node GEMM+logits, fused edge pass, agg ----
  node_gemm_al<4><<<ggrid, 256, 0, stream>>>(x, Wt0, g0as, g0ad, ow0, ob0,
                                             xs, al_src, al_dst, escore, N);
  edge_fused_kernel<<<egrid, 256, 0, stream>>>(srcp, dstp, ea, ewt0, ewt1,
                                               eb0, eb1, M0, M1,
                                               al_src, al_dst, escore,
                                               exv, alev, ale1raw, E);
  agg_kernel<4, true, false><<<ngrid4, 256, 0, stream>>>(rowptr, src_ord, eorder,
                                                         xs, exv, alev,
                                                         al_src, al_dst,
                                                         g0b, x, nullptr, out, N);

  // ---- layer 1 (H=1): fused node GEMM+logits, edge finish, agg ----
  node_gemm_al<1><<<ggrid, 256, 0, stream>>>(out, Wt1, g1as, g1ad, ow1, ob1,
                                             xs, al_src, al_dst, escore, N);
  edge_finish_kernel<<<egrid, 256, 0, stream>>>(srcp, dstp, ale1raw,
                                                al_src, al_dst, escore,
                                                exv, alev, E);
  agg_kernel<1, false, true><<<ngrid4, 256, 0, stream>>>(rowptr, src_ord, eorder,
                                                         xs, exv, alev,
                                                         al_src, al_dst,
                                                         g1b, out, x, out, N);
}

// Round 7
// 356.225 us; speedup vs baseline: 3.2110x; 1.1693x over previous
//
#include <hip/hip_runtime.h>
#include <math.h>

#define D 128
#define ED 64
#define HD 32

typedef short s16x8 __attribute__((ext_vector_type(8)));
typedef float f32x4 __attribute__((ext_vector_type(4)));

// f32 -> bf16 bits, round-to-nearest-even
static __device__ inline unsigned short f2b(float f) {
  unsigned int u = __float_as_uint(f);
  unsigned int r = (u + 0x7fff + ((u >> 16) & 1)) >> 16;
  return (unsigned short)r;
}
static __device__ inline float b2f(unsigned short b) {
  return __uint_as_float(((unsigned int)b) << 16);
}

// ---------- CSR build ----------
__global__ __launch_bounds__(256)
void count_kernel(const int* __restrict__ dst, int* __restrict__ cnt, int E) {
  int e = blockIdx.x * 256 + threadIdx.x;
  if (e < E) atomicAdd(&cnt[dst[e]], 1);
}

__global__ __launch_bounds__(1024)
void scan_kernel(const int* __restrict__ cnt, int* __restrict__ rowptr, int n) {
  __shared__ int part[1024];
  int t = threadIdx.x;
  int chunk = (n + 1023) >> 10;
  int b = t * chunk, e = min(b + chunk, n);
  int s = 0;
  for (int i = b; i < e; ++i) s += cnt[i];
  part[t] = s;
  __syncthreads();
  for (int off = 1; off < 1024; off <<= 1) {
    int add = (t >= off) ? part[t - off] : 0;
    __syncthreads();
    part[t] += add;
    __syncthreads();
  }
  int run = part[t] - s;
  for (int i = b; i < e; ++i) { rowptr[i] = run; run += cnt[i]; }
  if (t == 1023) rowptr[n] = part[1023];
}

// fill: eorder[slot] = original edge id; src_ord[slot] = src[e]
__global__ __launch_bounds__(256)
void fill_kernel(const int* __restrict__ src, const int* __restrict__ dst,
                 const int* __restrict__ rowptr, int* __restrict__ cursor,
                 int* __restrict__ eorder, int* __restrict__ src_ord, int E) {
  int e = blockIdx.x * 256 + threadIdx.x;
  if (e < E) {
    int d = dst[e];
    int p = atomicAdd(&cursor[d], 1);
    int slot = rowptr[d] + p;
    eorder[slot] = e;
    src_ord[slot] = src[e];
  }
}

// ---------- M[d,h] = sum_c We[d, h*C+c] * ae[h,c] ----------
template<int H>
__global__ void prep_M_kernel(const float* __restrict__ We, const float* __restrict__ ae,
                              float* __restrict__ M) {
  constexpr int C = D / H;
  int t = threadIdx.x;
  if (t < HD * H) {
    int d = t / H, h = t - d * H;
    float s = 0.f;
    for (int c = 0; c < C; ++c) s += We[d * D + h * C + c] * ae[h * C + c];
    M[d * H + h] = s;
  }
}

// ---------- Wt[n][k] = bf16(W[k][n])  (transpose+convert, 128x128) ----------
__global__ __launch_bounds__(256)
void prep_Wt_kernel(const float* __restrict__ W, unsigned short* __restrict__ Wt) {
  int id = blockIdx.x * 256 + threadIdx.x;   // 0..16383
  int nn = id >> 7, k = id & 127;
  Wt[id] = f2b(W[k * D + nn]);
}

// ---------- permuted ewt: row i holds ew column ch(i) ----------
__global__ __launch_bounds__(256)
void prep_ewt_kernel(const float* __restrict__ ew, unsigned short* __restrict__ ewt) {
  int id = blockIdx.x * 256 + threadIdx.x;   // 0..2047
  if (id < HD * ED) {
    int i = id >> 6, k = id & 63;
    int ch = (i < 16) ? ((i >> 2) * 8 + (i & 3))
                      : (((i - 16) >> 2) * 8 + 4 + ((i - 16) & 3));
    ewt[id] = f2b(ew[k * HD + ch]);
  }
}

// ---------- fused: xs(bf16) = x @ W (MFMA) + attention-logit epilogue ----------
template<int H>
__global__ __launch_bounds__(256)
void node_gemm_al(const float* __restrict__ x, const unsigned short* __restrict__ Wt,
                  const float* __restrict__ a_s, const float* __restrict__ a_d,
                  const float* __restrict__ ow, const float* __restrict__ ob,
                  unsigned short* __restrict__ xs, float* __restrict__ al_src,
                  float* __restrict__ al_dst, float* __restrict__ escore,
                  float2* __restrict__ als1, int n) {
  int wave = threadIdx.x >> 6;
  int lane = threadIdx.x & 63;
  int q = lane >> 4;
  int l16 = lane & 15;
  int base = blockIdx.x * 64 + wave * 16;
  int rowRaw = base + l16;
  int row = rowRaw < n ? rowRaw : n - 1;
  const float* xrow = x + (size_t)row * D;
  s16x8 a[4];
  float scp = 0.f;
#pragma unroll
  for (int kk = 0; kk < 4; ++kk) {
    int kb = kk * 32 + q * 8;
    float4 v0 = *(const float4*)(xrow + kb);
    float4 v1 = *(const float4*)(xrow + kb + 4);
    float4 o0 = *(const float4*)(ow + kb);
    float4 o1 = *(const float4*)(ow + kb + 4);
    scp += v0.x * o0.x + v0.y * o0.y + v0.z * o0.z + v0.w * o0.w
         + v1.x * o1.x + v1.y * o1.y + v1.z * o1.z + v1.w * o1.w;
    s16x8 t;
    t[0] = (short)f2b(v0.x); t[1] = (short)f2b(v0.y);
    t[2] = (short)f2b(v0.z); t[3] = (short)f2b(v0.w);
    t[4] = (short)f2b(v1.x); t[5] = (short)f2b(v1.y);
    t[6] = (short)f2b(v1.z); t[7] = (short)f2b(v1.w);
    a[kk] = t;
  }
  // scp -> uniform over q; lane (q,l16) holds score of row base+l16
  scp += __shfl_xor(scp, 16);
  scp += __shfl_xor(scp, 32);
  if (H == 4) {
    if (q == 0 && rowRaw < n) escore[rowRaw] = __expf(scp + ob[0]);
  }

  f32x4 acc[8];
#pragma unroll
  for (int nf = 0; nf < 8; ++nf) { f32x4 z = {0.f, 0.f, 0.f, 0.f}; acc[nf] = z; }
#pragma unroll
  for (int kk = 0; kk < 4; ++kk) {
    int kb = kk * 32 + q * 8;
#pragma unroll
    for (int nf = 0; nf < 8; ++nf) {
      s16x8 b = *(const s16x8*)(Wt + (size_t)(nf * 16 + l16) * D + kb);
      acc[nf] = __builtin_amdgcn_mfma_f32_16x16x32_bf16(a[kk], b, acc[nf], 0, 0, 0);
    }
  }
#pragma unroll
  for (int nf = 0; nf < 8; ++nf) {
#pragma unroll
    for (int r = 0; r < 4; ++r) {
      int rr = base + q * 4 + r;
      if (rr < n) xs[(size_t)rr * D + nf * 16 + l16] = f2b(acc[nf][r]);
    }
  }
  // ---- attention-logit epilogue from acc fragments ----
  float asv[8], adv[8];
#pragma unroll
  for (int nf = 0; nf < 8; ++nf) { asv[nf] = a_s[nf * 16 + l16]; adv[nf] = a_d[nf * 16 + l16]; }
  if (H == 4) {
    float mys = 0.f, myd = 0.f;
#pragma unroll
    for (int r = 0; r < 4; ++r) {
#pragma unroll
      for (int h = 0; h < 4; ++h) {
        float vs = acc[2 * h][r] * asv[2 * h] + acc[2 * h + 1][r] * asv[2 * h + 1];
        float vd = acc[2 * h][r] * adv[2 * h] + acc[2 * h + 1][r] * adv[2 * h + 1];
        vs += __shfl_xor(vs, 1); vd += __shfl_xor(vd, 1);
        vs += __shfl_xor(vs, 2); vd += __shfl_xor(vd, 2);
        vs += __shfl_xor(vs, 4); vd += __shfl_xor(vd, 4);
        vs += __shfl_xor(vs, 8); vd += __shfl_xor(vd, 8);
        if (l16 == r * 4 + h) { mys = vs; myd = vd; }
      }
    }
    int orow = base + q * 4 + (l16 >> 2);
    if (orow < n) {
      al_src[(size_t)orow * 4 + (l16 & 3)] = mys;
      al_dst[(size_t)orow * 4 + (l16 & 3)] = myd;
    }
  } else {
    float mys = 0.f, myd = 0.f;
#pragma unroll
    for (int r = 0; r < 4; ++r) {
      float vs = 0.f, vd = 0.f;
#pragma unroll
      for (int nf = 0; nf < 8; ++nf) { vs = fmaf(acc[nf][r], asv[nf], vs); vd = fmaf(acc[nf][r], adv[nf], vd); }
      vs += __shfl_xor(vs, 1); vd += __shfl_xor(vd, 1);
      vs += __shfl_xor(vs, 2); vd += __shfl_xor(vd, 2);
      vs += __shfl_xor(vs, 4); vd += __shfl_xor(vd, 4);
      vs += __shfl_xor(vs, 8); vd += __shfl_xor(vd, 8);
      if (l16 == r) { mys = vs; myd = vd; }
    }
    // scp for row base + q*4 + l16  (q*4+l16 <= 15 when l16 < 4)
    float scr = __shfl(scp, q * 4 + l16);
    int orow = base + q * 4 + l16;
    if (l16 < 4 && orow < n) {
      al_dst[orow] = myd;
      als1[orow] = make_float2(mys, __expf(scr + ob[0]));
    }
  }
}

// ---------- edge pass: pure streaming MFMA, raw ale only (no gathers, no exp) ----------
__global__ __launch_bounds__(256)
void edge_fused_kernel(const float* __restrict__ ea,
                       const unsigned short* __restrict__ ewt0p,
                       const unsigned short* __restrict__ ewt1p,
                       const float* __restrict__ eb0, const float* __restrict__ eb1,
                       const float* __restrict__ M0,   // [32][4]
                       const float* __restrict__ M1,   // [32]
                       float* __restrict__ ale0raw,    // [E][4]
                       float* __restrict__ ale1raw, int E) {
  int wave = threadIdx.x >> 6, lane = threadIdx.x & 63;
  int q = lane >> 4, l16 = lane & 15;
  int ebase = (blockIdx.x * 4 + wave) * 64;
  if (ebase >= E) return;
  s16x8 a0l0 = *(const s16x8*)(ewt0p + l16 * 64 + q * 8);
  s16x8 a0l1 = *(const s16x8*)(ewt0p + l16 * 64 + 32 + q * 8);
  s16x8 a0h0 = *(const s16x8*)(ewt0p + (16 + l16) * 64 + q * 8);
  s16x8 a0h1 = *(const s16x8*)(ewt0p + (16 + l16) * 64 + 32 + q * 8);
  s16x8 a1l0 = *(const s16x8*)(ewt1p + l16 * 64 + q * 8);
  s16x8 a1l1 = *(const s16x8*)(ewt1p + l16 * 64 + 32 + q * 8);
  s16x8 a1h0 = *(const s16x8*)(ewt1p + (16 + l16) * 64 + q * 8);
  s16x8 a1h1 = *(const s16x8*)(ewt1p + (16 + l16) * 64 + 32 + q * 8);
  float4 b0lo = *(const float4*)(eb0 + q * 8);
  float4 b0hi = *(const float4*)(eb0 + q * 8 + 4);
  float4 b1lo = *(const float4*)(eb1 + q * 8);
  float4 b1hi = *(const float4*)(eb1 + q * 8 + 4);
  s16x8 mf0, mf1;
#pragma unroll
  for (int j = 0; j < 8; ++j) {
    mf0[j] = (l16 < 4) ? (short)f2b(M0[(q * 8 + j) * 4 + l16]) : (short)0;
    mf1[j] = (l16 == 0) ? (short)f2b(M1[q * 8 + j]) : (short)0;
  }

#pragma unroll
  for (int st = 0; st < 4; ++st) {
    int eb_t = ebase + st * 16;
    int e16 = eb_t + l16;
    int ec = e16 < E ? e16 : E - 1;
    const float* er = ea + (size_t)ec * ED;
    float4 u0 = *(const float4*)(er + q * 8);
    float4 u1 = *(const float4*)(er + q * 8 + 4);
    float4 u2 = *(const float4*)(er + 32 + q * 8);
    float4 u3 = *(const float4*)(er + 32 + q * 8 + 4);
    s16x8 bk0, bk1;
    bk0[0] = (short)f2b(u0.x); bk0[1] = (short)f2b(u0.y);
    bk0[2] = (short)f2b(u0.z); bk0[3] = (short)f2b(u0.w);
    bk0[4] = (short)f2b(u1.x); bk0[5] = (short)f2b(u1.y);
    bk0[6] = (short)f2b(u1.z); bk0[7] = (short)f2b(u1.w);
    bk1[0] = (short)f2b(u2.x); bk1[1] = (short)f2b(u2.y);
    bk1[2] = (short)f2b(u2.z); bk1[3] = (short)f2b(u2.w);
    bk1[4] = (short)f2b(u3.x); bk1[5] = (short)f2b(u3.y);
    bk1[6] = (short)f2b(u3.z); bk1[7] = (short)f2b(u3.w);
    f32x4 zl0 = {0.f,0.f,0.f,0.f}, zh0 = {0.f,0.f,0.f,0.f};
    f32x4 zl1 = {0.f,0.f,0.f,0.f}, zh1 = {0.f,0.f,0.f,0.f};
    zl0 = __builtin_amdgcn_mfma_f32_16x16x32_bf16(a0l0, bk0, zl0, 0, 0, 0);
    zl0 = __builtin_amdgcn_mfma_f32_16x16x32_bf16(a0l1, bk1, zl0, 0, 0, 0);
    zh0 = __builtin_amdgcn_mfma_f32_16x16x32_bf16(a0h0, bk0, zh0, 0, 0, 0);
    zh0 = __builtin_amdgcn_mfma_f32_16x16x32_bf16(a0h1, bk1, zh0, 0, 0, 0);
    zl1 = __builtin_amdgcn_mfma_f32_16x16x32_bf16(a1l0, bk0, zl1, 0, 0, 0);
    zl1 = __builtin_amdgcn_mfma_f32_16x16x32_bf16(a1l1, bk1, zl1, 0, 0, 0);
    zh1 = __builtin_amdgcn_mfma_f32_16x16x32_bf16(a1h0, bk0, zh1, 0, 0, 0);
    zh1 = __builtin_amdgcn_mfma_f32_16x16x32_bf16(a1h1, bk1, zh1, 0, 0, 0);
    s16x8 zb0, zb1;
    zb0[0] = (short)f2b(fmaxf(zl0[0] + b0lo.x, 0.f));
    zb0[1] = (short)f2b(fmaxf(zl0[1] + b0lo.y, 0.f));
    zb0[2] = (short)f2b(fmaxf(zl0[2] + b0lo.z, 0.f));
    zb0[3] = (short)f2b(fmaxf(zl0[3] + b0lo.w, 0.f));
    zb0[4] = (short)f2b(fmaxf(zh0[0] + b0hi.x, 0.f));
    zb0[5] = (short)f2b(fmaxf(zh0[1] + b0hi.y, 0.f));
    zb0[6] = (short)f2b(fmaxf(zh0[2] + b0hi.z, 0.f));
    zb0[7] = (short)f2b(fmaxf(zh0[3] + b0hi.w, 0.f));
    zb1[0] = (short)f2b(fmaxf(zl1[0] + b1lo.x, 0.f));
    zb1[1] = (short)f2b(fmaxf(zl1[1] + b1lo.y, 0.f));
    zb1[2] = (short)f2b(fmaxf(zl1[2] + b1lo.z, 0.f));
    zb1[3] = (short)f2b(fmaxf(zl1[3] + b1lo.w, 0.f));
    zb1[4] = (short)f2b(fmaxf(zh1[0] + b1hi.x, 0.f));
    zb1[5] = (short)f2b(fmaxf(zh1[1] + b1hi.y, 0.f));
    zb1[6] = (short)f2b(fmaxf(zh1[2] + b1hi.z, 0.f));
    zb1[7] = (short)f2b(fmaxf(zh1[3] + b1hi.w, 0.f));
    f32x4 r0 = {0.f,0.f,0.f,0.f}, r1 = {0.f,0.f,0.f,0.f};
    r0 = __builtin_amdgcn_mfma_f32_16x16x32_bf16(mf0, zb0, r0, 0, 0, 0);
    r1 = __builtin_amdgcn_mfma_f32_16x16x32_bf16(mf1, zb1, r1, 0, 0, 0);
    // D layout: lane (0,l16) holds ale0[edge e16][head r] in r0[r], ale1 in r1[0]
    if (q == 0 && e16 < E) {
      *(float4*)(ale0raw + (size_t)e16 * 4) = make_float4(r0[0], r0[1], r0[2], r0[3]);
      ale1raw[e16] = r1[0];
    }
  }
}

// ---------- CSR aggregation with inlined alpha finish + self-loop + bias + residual ----------
template<int H, bool RELU, bool ADD_ORIG>
__global__ __launch_bounds__(256)
void agg_kernel(const int* __restrict__ rowptr, const int* __restrict__ src_ord,
                const int* __restrict__ eorder,
                const unsigned short* __restrict__ xs, const float* __restrict__ aleraw,
                const float* __restrict__ al_src, const float* __restrict__ al_dst,
                const float* __restrict__ escore, const float2* __restrict__ als1,
                const float* __restrict__ bias, const float* __restrict__ xin,
                const float* __restrict__ orig, float* __restrict__ out, int n) {
  int wid = blockIdx.x * 4 + (threadIdx.x >> 6);
  int lane = threadIdx.x & 63;
  if (wid >= n) return;
  int h0 = (H == 4) ? (lane >> 4) : 0;
  const ushort2* xs2 = (const ushort2*)xs;
  float adst = al_dst[(size_t)wid * H + h0];
  float ax = 0.f, ay = 0.f, den = 0.f, sale = 0.f;
  int b = rowptr[wid], e = rowptr[wid + 1];
  int idx = b;

#define EDGE_TERM(S, ED_, EV, AL)                                        \
  float AL, EV;                                                          \
  {                                                                      \
    float aa_;                                                           \
    if (H == 4) {                                                        \
      AL = aleraw[(size_t)(ED_) * 4 + h0] * escore[S];                   \
      aa_ = al_src[(size_t)(S) * 4 + h0] + adst + AL;                    \
    } else {                                                             \
      float2 ae_ = als1[S];                                              \
      AL = aleraw[ED_] * ae_.y;                                          \
      aa_ = ae_.x + adst + AL;                                           \
    }                                                                    \
    EV = __expf(aa_ > 0.f ? aa_ : 0.2f * aa_);                           \
  }

  for (; idx + 4 <= e; idx += 4) {
    int s0 = src_ord[idx], s1 = src_ord[idx + 1];
    int s2 = src_ord[idx + 2], s3 = src_ord[idx + 3];
    int e0 = eorder[idx], e1 = eorder[idx + 1];
    int e2 = eorder[idx + 2], e3 = eorder[idx + 3];
    EDGE_TERM(s0, e0, ev0, al0)
    EDGE_TERM(s1, e1, ev1, al1)
    EDGE_TERM(s2, e2, ev2, al2)
    EDGE_TERM(s3, e3, ev3, al3)
    ushort2 u0 = xs2[(size_t)s0 * 64 + lane];
    ushort2 u1 = xs2[(size_t)s1 * 64 + lane];
    ushort2 u2 = xs2[(size_t)s2 * 64 + lane];
    ushort2 u3 = xs2[(size_t)s3 * 64 + lane];
    ax = fmaf(ev0, b2f(u0.x), ax); ay = fmaf(ev0, b2f(u0.y), ay);
    ax = fmaf(ev1, b2f(u1.x), ax); ay = fmaf(ev1, b2f(u1.y), ay);
    ax = fmaf(ev2, b2f(u2.x), ax); ay = fmaf(ev2, b2f(u2.y), ay);
    ax = fmaf(ev3, b2f(u3.x), ax); ay = fmaf(ev3, b2f(u3.y), ay);
    den += (ev0 + ev1) + (ev2 + ev3);
    sale += (al0 + al1) + (al2 + al3);
  }
  for (; idx < e; ++idx) {
    int s = src_ord[idx];
    int ed = eorder[idx];
    EDGE_TERM(s, ed, ev, al)
    ushort2 u = xs2[(size_t)s * 64 + lane];
    ax = fmaf(ev, b2f(u.x), ax); ay = fmaf(ev, b2f(u.y), ay);
    den += ev; sale += al;
  }
#undef EDGE_TERM

  // self-loop: attr = mean of incoming alef (linear in attr)
  int deg = e - b;
  float la = sale / (float)(deg > 1 ? deg : 1);
  float asrc_w = (H == 4) ? al_src[(size_t)wid * 4 + h0] : als1[wid].x;
  float a = asrc_w + adst + la;
  float lr = a > 0.f ? a : 0.2f * a;
  float evl = __expf(lr);
  {
    ushort2 u = xs2[(size_t)wid * 64 + lane];
    ax = fmaf(evl, b2f(u.x), ax); ay = fmaf(evl, b2f(u.y), ay);
  }
  float dinv = 1.f / (den + evl + 1e-16f);
  float2 bi = ((const float2*)bias)[lane];
  float2 xi = ((const float2*)xin)[(size_t)wid * 64 + lane];
  ax = ax * dinv + bi.x + xi.x;
  ay = ay * dinv + bi.y + xi.y;
  if (ADD_ORIG) {
    float2 og = ((const float2*)orig)[(size_t)wid * 64 + lane];
    ax += og.x; ay += og.y;
  }
  if (RELU) { ax = fmaxf(ax, 0.f); ay = fmaxf(ay, 0.f); }
  ((float2*)out)[(size_t)wid * 64 + lane] = make_float2(ax, ay);
}

extern "C" void kernel_launch(void* const* d_in, const int* in_sizes, int n_in,
                              void* d_out, int out_size, void* d_ws, size_t ws_size,
                              hipStream_t stream) {
  const float* x   = (const float*)d_in[0];
  const int*   ei  = (const int*)d_in[1];
  const float* ea  = (const float*)d_in[2];
  const float* ew0 = (const float*)d_in[3];
  const float* eb0 = (const float*)d_in[4];
  const float* ew1 = (const float*)d_in[5];
  const float* eb1 = (const float*)d_in[6];
  const float* ow0 = (const float*)d_in[7];
  const float* ob0 = (const float*)d_in[8];
  const float* ow1 = (const float*)d_in[9];
  const float* ob1 = (const float*)d_in[10];
  const float* g0W = (const float*)d_in[11];
  const float* g0as= (const float*)d_in[12];
  const float* g0ad= (const float*)d_in[13];
  const float* g0We= (const float*)d_in[14];
  const float* g0ae= (const float*)d_in[15];
  const float* g0b = (const float*)d_in[16];
  const float* g1W = (const float*)d_in[17];
  const float* g1as= (const float*)d_in[18];
  const float* g1ad= (const float*)d_in[19];
  const float* g1We= (const float*)d_in[20];
  const float* g1ae= (const float*)d_in[21];
  const float* g1b = (const float*)d_in[22];
  float* out = (float*)d_out;

  const int N = in_sizes[0] / D;
  const int E = in_sizes[1] / 2;
  const int* srcp = ei;
  const int* dstp = ei + E;

  char* w = (char*)d_ws;
  size_t off = 0;
  auto alloc = [&](size_t bytes) {
    void* p = w + off;
    off += (bytes + 255) & ~(size_t)255;
    return p;
  };
  unsigned short* xs = (unsigned short*)alloc((size_t)N * D * 2);
  float* ale0raw = (float*)alloc((size_t)E * 4 * 4);
  float* ale1raw = (float*)alloc((size_t)E * 4);
  float* al_src  = (float*)alloc((size_t)N * 4 * 4);
  float* al_dst  = (float*)alloc((size_t)N * 4 * 4);
  float* escore  = (float*)alloc((size_t)N * 4);
  float2* als1   = (float2*)alloc((size_t)N * 8);
  float* M0      = (float*)alloc(HD * 4 * 4);
  float* M1      = (float*)alloc(HD * 4);
  unsigned short* Wt0 = (unsigned short*)alloc((size_t)D * D * 2);
  unsigned short* Wt1 = (unsigned short*)alloc((size_t)D * D * 2);
  unsigned short* ewt0 = (unsigned short*)alloc((size_t)HD * ED * 2);
  unsigned short* ewt1 = (unsigned short*)alloc((size_t)HD * ED * 2);
  int*   cnt     = (int*)alloc((size_t)N * 4);
  int*   rowptr  = (int*)alloc((size_t)(N + 1) * 4);
  int*   cursor  = (int*)alloc((size_t)N * 4);
  int*   eorder  = (int*)alloc((size_t)E * 4);
  int*   src_ord = (int*)alloc((size_t)E * 4);

  int egrid  = (E + 255) / 256;
  int ngrid4 = (N + 3) / 4;
  int ggrid  = (N + 63) / 64;

  // ---- CSR build (shared by both layers) + weight prep ----
  hipMemsetAsync(cnt, 0, (size_t)N * 4, stream);
  hipMemsetAsync(cursor, 0, (size_t)N * 4, stream);
  count_kernel<<<egrid, 256, 0, stream>>>(dstp, cnt, E);
  scan_kernel<<<1, 1024, 0, stream>>>(cnt, rowptr, N);
  fill_kernel<<<egrid, 256, 0, stream>>>(srcp, dstp, rowptr, cursor,
                                         eorder, src_ord, E);
  prep_M_kernel<4><<<1, 128, 0, stream>>>(g0We, g0ae, M0);
  prep_M_kernel<1><<<1, 32, 0, stream>>>(g1We, g1ae, M1);
  prep_Wt_kernel<<<64, 256, 0, stream>>>(g0W, Wt0);
  prep_Wt_kernel<<<64, 256, 0, stream>>>(g1W, Wt1);
  prep_ewt_kernel<<<8, 256, 0, stream>>>(ew0, ewt0);
  prep_ewt_kernel<<<8, 256, 0, stream>>>(ew1, ewt1);

  // ---- layer 0 (H=4) ----
  node_gemm_al<4><<<ggrid, 256, 0, stream>>>(x, Wt0, g0as, g0ad, ow0, ob0,
                                             xs, al_src, al_dst, escore, nullptr, N);
  edge_fused_kernel<<<egrid, 256, 0, stream>>>(ea, ewt0, ewt1, eb0, eb1, M0, M1,
                                               ale0raw, ale1raw, E);
  agg_kernel<4, true, false><<<ngrid4, 256, 0, stream>>>(rowptr, src_ord, eorder,
                                                         xs, ale0raw,
                                                         al_src, al_dst, escore, nullptr,
                                                         g0b, x, nullptr, out, N);

  // ---- layer 1 (H=1) ----
  node_gemm_al<1><<<ggrid, 256, 0, stream>>>(out, Wt1, g1as, g1ad, ow1, ob1,
                                             xs, al_src, al_dst, nullptr, als1, N);
  agg_kernel<1, false, true><<<ngrid4, 256, 0, stream>>>(rowptr, src_ord, eorder,
                                                         xs, ale1raw,
                                                         nullptr, al_dst, nullptr, als1,
                                                         g1b, out, x, out, N);
}

// Round 8
// 326.316 us; speedup vs baseline: 3.5053x; 1.0917x over previous
//
#include <hip/hip_runtime.h>
#include <math.h>

#define D 128
#define ED 64
#define HD 32

typedef short s16x8 __attribute__((ext_vector_type(8)));
typedef float f32x4 __attribute__((ext_vector_type(4)));

// f32 -> bf16 bits, round-to-nearest-even
static __device__ inline unsigned short f2b(float f) {
  unsigned int u = __float_as_uint(f);
  unsigned int r = (u + 0x7fff + ((u >> 16) & 1)) >> 16;
  return (unsigned short)r;
}
static __device__ inline float b2f(unsigned short b) {
  return __uint_as_float(((unsigned int)b) << 16);
}

// ---------- K1: count + all weight preps (fused) ----------
__global__ __launch_bounds__(256)
void count_prep_kernel(const int* __restrict__ dst, int* __restrict__ cnt, int E, int egrid,
                       const float* __restrict__ g0W, unsigned short* __restrict__ Wt0,
                       const float* __restrict__ g1W, unsigned short* __restrict__ Wt1,
                       const float* __restrict__ ew0, unsigned short* __restrict__ ewt0,
                       const float* __restrict__ ew1, unsigned short* __restrict__ ewt1,
                       const float* __restrict__ g0We, const float* __restrict__ g0ae,
                       float* __restrict__ M0,
                       const float* __restrict__ g1We, const float* __restrict__ g1ae,
                       float* __restrict__ M1) {
  int b = blockIdx.x, t = threadIdx.x;
  if (b < egrid) {
    int e = b * 256 + t;
    if (e < E) atomicAdd(&cnt[dst[e]], 1);
    return;
  }
  int pb = b - egrid;
  if (pb < 128) {                      // Wt[n][k] = bf16(W[k][n])
    const float* W = pb < 64 ? g0W : g1W;
    unsigned short* Wt = pb < 64 ? Wt0 : Wt1;
    int id = (pb & 63) * 256 + t;
    int nn = id >> 7, k = id & 127;
    Wt[id] = f2b(W[k * D + nn]);
  } else if (pb < 144) {               // permuted ewt
    const float* ew = pb < 136 ? ew0 : ew1;
    unsigned short* ewt = pb < 136 ? ewt0 : ewt1;
    int id = ((pb - 128) & 7) * 256 + t;
    if (id < HD * ED) {
      int i = id >> 6, k = id & 63;
      int ch = (i < 16) ? ((i >> 2) * 8 + (i & 3))
                        : (((i - 16) >> 2) * 8 + 4 + ((i - 16) & 3));
      ewt[id] = f2b(ew[k * HD + ch]);
    }
  } else if (pb == 144) {              // M0 [32][4]
    if (t < HD * 4) {
      int d = t >> 2, h = t & 3;
      float s = 0.f;
      for (int c = 0; c < 32; ++c) s += g0We[d * D + h * 32 + c] * g0ae[h * 32 + c];
      M0[t] = s;
    }
  } else {                             // M1 [32]
    if (t < HD) {
      float s = 0.f;
      for (int c = 0; c < D; ++c) s += g1We[t * D + c] * g1ae[c];
      M1[t] = s;
    }
  }
}

__global__ __launch_bounds__(1024)
void scan_kernel(const int* __restrict__ cnt, int* __restrict__ rowptr, int n) {
  __shared__ int part[1024];
  int t = threadIdx.x;
  int chunk = (n + 1023) >> 10;
  int b = t * chunk, e = min(b + chunk, n);
  int s = 0;
  for (int i = b; i < e; ++i) s += cnt[i];
  part[t] = s;
  __syncthreads();
  for (int off = 1; off < 1024; off <<= 1) {
    int add = (t >= off) ? part[t - off] : 0;
    __syncthreads();
    part[t] += add;
    __syncthreads();
  }
  int run = part[t] - s;
  for (int i = b; i < e; ++i) { rowptr[i] = run; run += cnt[i]; }
  if (t == 1023) rowptr[n] = part[1023];
}

// ---------- node GEMM + attention-logit epilogue (device body) ----------
template<int H>
static __device__ void gemm_body(int gblk, int tid,
                                 const float* __restrict__ x,
                                 const unsigned short* __restrict__ Wt,
                                 const float* __restrict__ a_s, const float* __restrict__ a_d,
                                 const float* __restrict__ ow, const float* __restrict__ ob,
                                 unsigned short* __restrict__ xs, float* __restrict__ al_src,
                                 float* __restrict__ al_dst, float* __restrict__ escore,
                                 float2* __restrict__ als1, int n) {
  int wave = tid >> 6;
  int lane = tid & 63;
  int q = lane >> 4;
  int l16 = lane & 15;
  int base = gblk * 64 + wave * 16;
  int rowRaw = base + l16;
  int row = rowRaw < n ? rowRaw : n - 1;
  const float* xrow = x + (size_t)row * D;
  s16x8 a[4];
  float scp = 0.f;
#pragma unroll
  for (int kk = 0; kk < 4; ++kk) {
    int kb = kk * 32 + q * 8;
    float4 v0 = *(const float4*)(xrow + kb);
    float4 v1 = *(const float4*)(xrow + kb + 4);
    float4 o0 = *(const float4*)(ow + kb);
    float4 o1 = *(const float4*)(ow + kb + 4);
    scp += v0.x * o0.x + v0.y * o0.y + v0.z * o0.z + v0.w * o0.w
         + v1.x * o1.x + v1.y * o1.y + v1.z * o1.z + v1.w * o1.w;
    s16x8 t;
    t[0] = (short)f2b(v0.x); t[1] = (short)f2b(v0.y);
    t[2] = (short)f2b(v0.z); t[3] = (short)f2b(v0.w);
    t[4] = (short)f2b(v1.x); t[5] = (short)f2b(v1.y);
    t[6] = (short)f2b(v1.z); t[7] = (short)f2b(v1.w);
    a[kk] = t;
  }
  scp += __shfl_xor(scp, 16);
  scp += __shfl_xor(scp, 32);
  if (H == 4) {
    if (q == 0 && rowRaw < n) escore[rowRaw] = __expf(scp + ob[0]);
  }

  f32x4 acc[8];
#pragma unroll
  for (int nf = 0; nf < 8; ++nf) { f32x4 z = {0.f, 0.f, 0.f, 0.f}; acc[nf] = z; }
#pragma unroll
  for (int kk = 0; kk < 4; ++kk) {
    int kb = kk * 32 + q * 8;
#pragma unroll
    for (int nf = 0; nf < 8; ++nf) {
      s16x8 b = *(const s16x8*)(Wt + (size_t)(nf * 16 + l16) * D + kb);
      acc[nf] = __builtin_amdgcn_mfma_f32_16x16x32_bf16(a[kk], b, acc[nf], 0, 0, 0);
    }
  }
#pragma unroll
  for (int nf = 0; nf < 8; ++nf) {
#pragma unroll
    for (int r = 0; r < 4; ++r) {
      int rr = base + q * 4 + r;
      if (rr < n) xs[(size_t)rr * D + nf * 16 + l16] = f2b(acc[nf][r]);
    }
  }
  float asv[8], adv[8];
#pragma unroll
  for (int nf = 0; nf < 8; ++nf) { asv[nf] = a_s[nf * 16 + l16]; adv[nf] = a_d[nf * 16 + l16]; }
  if (H == 4) {
    float mys = 0.f, myd = 0.f;
#pragma unroll
    for (int r = 0; r < 4; ++r) {
#pragma unroll
      for (int h = 0; h < 4; ++h) {
        float vs = acc[2 * h][r] * asv[2 * h] + acc[2 * h + 1][r] * asv[2 * h + 1];
        float vd = acc[2 * h][r] * adv[2 * h] + acc[2 * h + 1][r] * adv[2 * h + 1];
        vs += __shfl_xor(vs, 1); vd += __shfl_xor(vd, 1);
        vs += __shfl_xor(vs, 2); vd += __shfl_xor(vd, 2);
        vs += __shfl_xor(vs, 4); vd += __shfl_xor(vd, 4);
        vs += __shfl_xor(vs, 8); vd += __shfl_xor(vd, 8);
        if (l16 == r * 4 + h) { mys = vs; myd = vd; }
      }
    }
    int orow = base + q * 4 + (l16 >> 2);
    if (orow < n) {
      al_src[(size_t)orow * 4 + (l16 & 3)] = mys;
      al_dst[(size_t)orow * 4 + (l16 & 3)] = myd;
    }
  } else {
    float mys = 0.f, myd = 0.f;
#pragma unroll
    for (int r = 0; r < 4; ++r) {
      float vs = 0.f, vd = 0.f;
#pragma unroll
      for (int nf = 0; nf < 8; ++nf) { vs = fmaf(acc[nf][r], asv[nf], vs); vd = fmaf(acc[nf][r], adv[nf], vd); }
      vs += __shfl_xor(vs, 1); vd += __shfl_xor(vd, 1);
      vs += __shfl_xor(vs, 2); vd += __shfl_xor(vd, 2);
      vs += __shfl_xor(vs, 4); vd += __shfl_xor(vd, 4);
      vs += __shfl_xor(vs, 8); vd += __shfl_xor(vd, 8);
      if (l16 == r) { mys = vs; myd = vd; }
    }
    float scr = __shfl(scp, q * 4 + l16);
    int orow = base + q * 4 + l16;
    if (l16 < 4 && orow < n) {
      al_dst[orow] = myd;
      als1[orow] = make_float2(mys, __expf(scr + ob[0]));
    }
  }
}

// ---------- K3: fill + gemm0 (fused, independent halves) ----------
__global__ __launch_bounds__(256)
void fill_gemm_kernel(const int* __restrict__ src, const int* __restrict__ dst,
                      const int* __restrict__ rowptr, int* __restrict__ cursor,
                      int* __restrict__ eorder, int* __restrict__ src_ord, int E, int fgrid,
                      const float* __restrict__ x, const unsigned short* __restrict__ Wt0,
                      const float* __restrict__ g0as, const float* __restrict__ g0ad,
                      const float* __restrict__ ow0, const float* __restrict__ ob0,
                      unsigned short* __restrict__ xs, float* __restrict__ al_src,
                      float* __restrict__ al_dst, float* __restrict__ escore, int n) {
  if ((int)blockIdx.x < fgrid) {
    int e = blockIdx.x * 256 + threadIdx.x;
    if (e < E) {
      int d = dst[e];
      int p = atomicAdd(&cursor[d], 1);
      int slot = rowptr[d] + p;
      eorder[slot] = e;
      src_ord[slot] = src[e];
    }
  } else {
    gemm_body<4>(blockIdx.x - fgrid, threadIdx.x, x, Wt0, g0as, g0ad, ow0, ob0,
                 xs, al_src, al_dst, escore, nullptr, n);
  }
}

__global__ __launch_bounds__(256)
void gemm1_kernel(const float* __restrict__ x, const unsigned short* __restrict__ Wt,
                  const float* __restrict__ a_s, const float* __restrict__ a_d,
                  const float* __restrict__ ow, const float* __restrict__ ob,
                  unsigned short* __restrict__ xs, float* __restrict__ al_dst,
                  float2* __restrict__ als1, int n) {
  gemm_body<1>(blockIdx.x, threadIdx.x, x, Wt, a_s, a_d, ow, ob,
               xs, nullptr, al_dst, nullptr, als1, n);
}

// ---------- K4: edge pass in CSR order (gathers ea rows, streams outputs) ----------
__global__ __launch_bounds__(256)
void edge_csr_kernel(const int* __restrict__ eorder, const int* __restrict__ src_ord,
                     const float* __restrict__ ea,
                     const unsigned short* __restrict__ ewt0p,
                     const unsigned short* __restrict__ ewt1p,
                     const float* __restrict__ eb0, const float* __restrict__ eb1,
                     const float* __restrict__ M0, const float* __restrict__ M1,
                     const float* __restrict__ escore0,
                     float* __restrict__ alef0,     // [E][4] CSR order, escore-premultiplied
                     float* __restrict__ ale1raw,   // [E]   CSR order, raw
                     int E) {
  int wave = threadIdx.x >> 6, lane = threadIdx.x & 63;
  int q = lane >> 4, l16 = lane & 15;
  int ebase = (blockIdx.x * 4 + wave) * 64;
  if (ebase >= E) return;
  s16x8 a0l0 = *(const s16x8*)(ewt0p + l16 * 64 + q * 8);
  s16x8 a0l1 = *(const s16x8*)(ewt0p + l16 * 64 + 32 + q * 8);
  s16x8 a0h0 = *(const s16x8*)(ewt0p + (16 + l16) * 64 + q * 8);
  s16x8 a0h1 = *(const s16x8*)(ewt0p + (16 + l16) * 64 + 32 + q * 8);
  s16x8 a1l0 = *(const s16x8*)(ewt1p + l16 * 64 + q * 8);
  s16x8 a1l1 = *(const s16x8*)(ewt1p + l16 * 64 + 32 + q * 8);
  s16x8 a1h0 = *(const s16x8*)(ewt1p + (16 + l16) * 64 + q * 8);
  s16x8 a1h1 = *(const s16x8*)(ewt1p + (16 + l16) * 64 + 32 + q * 8);
  float4 b0lo = *(const float4*)(eb0 + q * 8);
  float4 b0hi = *(const float4*)(eb0 + q * 8 + 4);
  float4 b1lo = *(const float4*)(eb1 + q * 8);
  float4 b1hi = *(const float4*)(eb1 + q * 8 + 4);
  s16x8 mf0, mf1;
#pragma unroll
  for (int j = 0; j < 8; ++j) {
    mf0[j] = (l16 < 4) ? (short)f2b(M0[(q * 8 + j) * 4 + l16]) : (short)0;
    mf1[j] = (l16 == 0) ? (short)f2b(M1[q * 8 + j]) : (short)0;
  }
  int el = ebase + lane;
  int elc = el < E ? el : E - 1;
  int eo = eorder[elc];                    // original edge id for my CSR slot
  float esc = escore0[src_ord[elc]];       // escore of my slot's src

#pragma unroll
  for (int st = 0; st < 4; ++st) {
    int slot16 = st * 16 + l16;
    int e16 = ebase + slot16;
    int row = __shfl(eo, slot16);
    const float* er = ea + (size_t)row * ED;
    float4 u0 = *(const float4*)(er + q * 8);
    float4 u1 = *(const float4*)(er + q * 8 + 4);
    float4 u2 = *(const float4*)(er + 32 + q * 8);
    float4 u3 = *(const float4*)(er + 32 + q * 8 + 4);
    s16x8 bk0, bk1;
    bk0[0] = (short)f2b(u0.x); bk0[1] = (short)f2b(u0.y);
    bk0[2] = (short)f2b(u0.z); bk0[3] = (short)f2b(u0.w);
    bk0[4] = (short)f2b(u1.x); bk0[5] = (short)f2b(u1.y);
    bk0[6] = (short)f2b(u1.z); bk0[7] = (short)f2b(u1.w);
    bk1[0] = (short)f2b(u2.x); bk1[1] = (short)f2b(u2.y);
    bk1[2] = (short)f2b(u2.z); bk1[3] = (short)f2b(u2.w);
    bk1[4] = (short)f2b(u3.x); bk1[5] = (short)f2b(u3.y);
    bk1[6] = (short)f2b(u3.z); bk1[7] = (short)f2b(u3.w);
    f32x4 zl0 = {0.f,0.f,0.f,0.f}, zh0 = {0.f,0.f,0.f,0.f};
    f32x4 zl1 = {0.f,0.f,0.f,0.f}, zh1 = {0.f,0.f,0.f,0.f};
    zl0 = __builtin_amdgcn_mfma_f32_16x16x32_bf16(a0l0, bk0, zl0, 0, 0, 0);
    zl0 = __builtin_amdgcn_mfma_f32_16x16x32_bf16(a0l1, bk1, zl0, 0, 0, 0);
    zh0 = __builtin_amdgcn_mfma_f32_16x16x32_bf16(a0h0, bk0, zh0, 0, 0, 0);
    zh0 = __builtin_amdgcn_mfma_f32_16x16x32_bf16(a0h1, bk1, zh0, 0, 0, 0);
    zl1 = __builtin_amdgcn_mfma_f32_16x16x32_bf16(a1l0, bk0, zl1, 0, 0, 0);
    zl1 = __builtin_amdgcn_mfma_f32_16x16x32_bf16(a1l1, bk1, zl1, 0, 0, 0);
    zh1 = __builtin_amdgcn_mfma_f32_16x16x32_bf16(a1h0, bk0, zh1, 0, 0, 0);
    zh1 = __builtin_amdgcn_mfma_f32_16x16x32_bf16(a1h1, bk1, zh1, 0, 0, 0);
    s16x8 zb0, zb1;
    zb0[0] = (short)f2b(fmaxf(zl0[0] + b0lo.x, 0.f));
    zb0[1] = (short)f2b(fmaxf(zl0[1] + b0lo.y, 0.f));
    zb0[2] = (short)f2b(fmaxf(zl0[2] + b0lo.z, 0.f));
    zb0[3] = (short)f2b(fmaxf(zl0[3] + b0lo.w, 0.f));
    zb0[4] = (short)f2b(fmaxf(zh0[0] + b0hi.x, 0.f));
    zb0[5] = (short)f2b(fmaxf(zh0[1] + b0hi.y, 0.f));
    zb0[6] = (short)f2b(fmaxf(zh0[2] + b0hi.z, 0.f));
    zb0[7] = (short)f2b(fmaxf(zh0[3] + b0hi.w, 0.f));
    zb1[0] = (short)f2b(fmaxf(zl1[0] + b1lo.x, 0.f));
    zb1[1] = (short)f2b(fmaxf(zl1[1] + b1lo.y, 0.f));
    zb1[2] = (short)f2b(fmaxf(zl1[2] + b1lo.z, 0.f));
    zb1[3] = (short)f2b(fmaxf(zl1[3] + b1lo.w, 0.f));
    zb1[4] = (short)f2b(fmaxf(zh1[0] + b1hi.x, 0.f));
    zb1[5] = (short)f2b(fmaxf(zh1[1] + b1hi.y, 0.f));
    zb1[6] = (short)f2b(fmaxf(zh1[2] + b1hi.z, 0.f));
    zb1[7] = (short)f2b(fmaxf(zh1[3] + b1hi.w, 0.f));
    f32x4 r0 = {0.f,0.f,0.f,0.f}, r1 = {0.f,0.f,0.f,0.f};
    r0 = __builtin_amdgcn_mfma_f32_16x16x32_bf16(mf0, zb0, r0, 0, 0, 0);
    r1 = __builtin_amdgcn_mfma_f32_16x16x32_bf16(mf1, zb1, r1, 0, 0, 0);
    float esc_e = __shfl(esc, slot16);
    if (q == 0 && e16 < E) {
      *(float4*)(alef0 + (size_t)e16 * 4) =
          make_float4(r0[0] * esc_e, r0[1] * esc_e, r0[2] * esc_e, r0[3] * esc_e);
      ale1raw[e16] = r1[0];
    }
  }
}

// ---------- CSR aggregation: streaming alef + xs/al gather + self-loop + epilogue ----------
template<int H, bool RELU, bool ADD_ORIG>
__global__ __launch_bounds__(256)
void agg_kernel(const int* __restrict__ rowptr, const int* __restrict__ src_ord,
                const unsigned short* __restrict__ xs, const float* __restrict__ alef,
                const float* __restrict__ al_src, const float* __restrict__ al_dst,
                const float2* __restrict__ als1,
                const float* __restrict__ bias, const float* __restrict__ xin,
                const float* __restrict__ orig, float* __restrict__ out, int n) {
  int wid = blockIdx.x * 4 + (threadIdx.x >> 6);
  int lane = threadIdx.x & 63;
  if (wid >= n) return;
  int h0 = (H == 4) ? (lane >> 4) : 0;
  const ushort2* xs2 = (const ushort2*)xs;
  float adst = al_dst[(size_t)wid * H + h0];
  float ax = 0.f, ay = 0.f, den = 0.f, sale = 0.f;
  int b = rowptr[wid], e = rowptr[wid + 1];
  int idx = b;

#define EDGE_TERM(S, I_, EV, AL)                                         \
  float AL, EV;                                                          \
  {                                                                      \
    float aa_;                                                           \
    if (H == 4) {                                                        \
      AL = alef[(size_t)(I_) * 4 + h0];                                  \
      aa_ = al_src[(size_t)(S) * 4 + h0] + adst + AL;                    \
    } else {                                                             \
      float2 ae_ = als1[S];                                              \
      AL = alef[I_] * ae_.y;                                             \
      aa_ = ae_.x + adst + AL;                                           \
    }                                                                    \
    EV = __expf(aa_ > 0.f ? aa_ : 0.2f * aa_);                           \
  }

  for (; idx + 4 <= e; idx += 4) {
    int s0 = src_ord[idx], s1 = src_ord[idx + 1];
    int s2 = src_ord[idx + 2], s3 = src_ord[idx + 3];
    EDGE_TERM(s0, idx + 0, ev0, al0)
    EDGE_TERM(s1, idx + 1, ev1, al1)
    EDGE_TERM(s2, idx + 2, ev2, al2)
    EDGE_TERM(s3, idx + 3, ev3, al3)
    ushort2 u0 = xs2[(size_t)s0 * 64 + lane];
    ushort2 u1 = xs2[(size_t)s1 * 64 + lane];
    ushort2 u2 = xs2[(size_t)s2 * 64 + lane];
    ushort2 u3 = xs2[(size_t)s3 * 64 + lane];
    ax = fmaf(ev0, b2f(u0.x), ax); ay = fmaf(ev0, b2f(u0.y), ay);
    ax = fmaf(ev1, b2f(u1.x), ax); ay = fmaf(ev1, b2f(u1.y), ay);
    ax = fmaf(ev2, b2f(u2.x), ax); ay = fmaf(ev2, b2f(u2.y), ay);
    ax = fmaf(ev3, b2f(u3.x), ax); ay = fmaf(ev3, b2f(u3.y), ay);
    den += (ev0 + ev1) + (ev2 + ev3);
    sale += (al0 + al1) + (al2 + al3);
  }
  for (; idx < e; ++idx) {
    int s = src_ord[idx];
    EDGE_TERM(s, idx, ev, al)
    ushort2 u = xs2[(size_t)s * 64 + lane];
    ax = fmaf(ev, b2f(u.x), ax); ay = fmaf(ev, b2f(u.y), ay);
    den += ev; sale += al;
  }
#undef EDGE_TERM

  int deg = e - b;
  float la = sale / (float)(deg > 1 ? deg : 1);
  float asrc_w = (H == 4) ? al_src[(size_t)wid * 4 + h0] : als1[wid].x;
  float a = asrc_w + adst + la;
  float lr = a > 0.f ? a : 0.2f * a;
  float evl = __expf(lr);
  {
    ushort2 u = xs2[(size_t)wid * 64 + lane];
    ax = fmaf(evl, b2f(u.x), ax); ay = fmaf(evl, b2f(u.y), ay);
  }
  float dinv = 1.f / (den + evl + 1e-16f);
  float2 bi = ((const float2*)bias)[lane];
  float2 xi = ((const float2*)xin)[(size_t)wid * 64 + lane];
  ax = ax * dinv + bi.x + xi.x;
  ay = ay * dinv + bi.y + xi.y;
  if (ADD_ORIG) {
    float2 og = ((const float2*)orig)[(size_t)wid * 64 + lane];
    ax += og.x; ay += og.y;
  }
  if (RELU) { ax = fmaxf(ax, 0.f); ay = fmaxf(ay, 0.f); }
  ((float2*)out)[(size_t)wid * 64 + lane] = make_float2(ax, ay);
}

extern "C" void kernel_launch(void* const* d_in, const int* in_sizes, int n_in,
                              void* d_out, int out_size, void* d_ws, size_t ws_size,
                              hipStream_t stream) {
  const float* x   = (const float*)d_in[0];
  const int*   ei  = (const int*)d_in[1];
  const float* ea  = (const float*)d_in[2];
  const float* ew0 = (const float*)d_in[3];
  const float* eb0 = (const float*)d_in[4];
  const float* ew1 = (const float*)d_in[5];
  const float* eb1 = (const float*)d_in[6];
  const float* ow0 = (const float*)d_in[7];
  const float* ob0 = (const float*)d_in[8];
  const float* ow1 = (const float*)d_in[9];
  const float* ob1 = (const float*)d_in[10];
  const float* g0W = (const float*)d_in[11];
  const float* g0as= (const float*)d_in[12];
  const float* g0ad= (const float*)d_in[13];
  const float* g0We= (const float*)d_in[14];
  const float* g0ae= (const float*)d_in[15];
  const float* g0b = (const float*)d_in[16];
  const float* g1W = (const float*)d_in[17];
  const float* g1as= (const float*)d_in[18];
  const float* g1ad= (const float*)d_in[19];
  const float* g1We= (const float*)d_in[20];
  const float* g1ae= (const float*)d_in[21];
  const float* g1b = (const float*)d_in[22];
  float* out = (float*)d_out;

  const int N = in_sizes[0] / D;
  const int E = in_sizes[1] / 2;
  const int* srcp = ei;
  const int* dstp = ei + E;

  char* w = (char*)d_ws;
  size_t off = 0;
  auto alloc = [&](size_t bytes) {
    void* p = w + off;
    off += (bytes + 255) & ~(size_t)255;
    return p;
  };
  size_t Nb = ((size_t)N * 4 + 255) & ~(size_t)255;
  int*   cnt     = (int*)alloc(2 * Nb);          // cnt + cursor contiguous (one memset)
  int*   cursor  = (int*)((char*)cnt + Nb);
  unsigned short* xs = (unsigned short*)alloc((size_t)N * D * 2);
  float* alef0   = (float*)alloc((size_t)E * 4 * 4);
  float* ale1raw = (float*)alloc((size_t)E * 4);
  float* al_src  = (float*)alloc((size_t)N * 4 * 4);
  float* al_dst  = (float*)alloc((size_t)N * 4 * 4);
  float* escore  = (float*)alloc((size_t)N * 4);
  float2* als1   = (float2*)alloc((size_t)N * 8);
  float* M0      = (float*)alloc(HD * 4 * 4);
  float* M1      = (float*)alloc(HD * 4);
  unsigned short* Wt0 = (unsigned short*)alloc((size_t)D * D * 2);
  unsigned short* Wt1 = (unsigned short*)alloc((size_t)D * D * 2);
  unsigned short* ewt0 = (unsigned short*)alloc((size_t)HD * ED * 2);
  unsigned short* ewt1 = (unsigned short*)alloc((size_t)HD * ED * 2);
  int*   rowptr  = (int*)alloc((size_t)(N + 1) * 4);
  int*   eorder  = (int*)alloc((size_t)E * 4);
  int*   src_ord = (int*)alloc((size_t)E * 4);

  int egrid  = (E + 255) / 256;
  int ngrid4 = (N + 3) / 4;
  int ggrid  = (N + 63) / 64;

  hipMemsetAsync(cnt, 0, 2 * Nb, stream);
  count_prep_kernel<<<egrid + 146, 256, 0, stream>>>(dstp, cnt, E, egrid,
                                                     g0W, Wt0, g1W, Wt1,
                                                     ew0, ewt0, ew1, ewt1,
                                                     g0We, g0ae, M0, g1We, g1ae, M1);
  scan_kernel<<<1, 1024, 0, stream>>>(cnt, rowptr, N);
  fill_gemm_kernel<<<egrid + ggrid, 256, 0, stream>>>(srcp, dstp, rowptr, cursor,
                                                      eorder, src_ord, E, egrid,
                                                      x, Wt0, g0as, g0ad, ow0, ob0,
                                                      xs, al_src, al_dst, escore, N);
  edge_csr_kernel<<<egrid, 256, 0, stream>>>(eorder, src_ord, ea, ewt0, ewt1,
                                             eb0, eb1, M0, M1, escore,
                                             alef0, ale1raw, E);
  agg_kernel<4, true, false><<<ngrid4, 256, 0, stream>>>(rowptr, src_ord,
                                                         xs, alef0,
                                                         al_src, al_dst, nullptr,
                                                         g0b, x, nullptr, out, N);
  gemm1_kernel<<<ggrid, 256, 0, stream>>>(out, Wt1, g1as, g1ad, ow1, ob1,
                                          xs, al_dst, als1, N);
  agg_kernel<1, false, true><<<ngrid4, 256, 0, stream>>>(rowptr, src_ord,
                                                         xs, ale1raw,
                                                         nullptr, al_dst, als1,
                                                         g1b, out, x, out, N);
}

// Round 9
// 241.821 us; speedup vs baseline: 4.7301x; 1.3494x over previous
//
#include <hip/hip_runtime.h>
#include <math.h>

#define D 128
#define ED 64
#define HD 32

typedef short s16x8 __attribute__((ext_vector_type(8)));
typedef float f32x4 __attribute__((ext_vector_type(4)));

// f32 -> bf16 bits, round-to-nearest-even
static __device__ inline unsigned short f2b(float f) {
  unsigned int u = __float_as_uint(f);
  unsigned int r = (u + 0x7fff + ((u >> 16) & 1)) >> 16;
  return (unsigned short)r;
}
static __device__ inline float b2f(unsigned short b) {
  return __uint_as_float(((unsigned int)b) << 16);
}

// ---------- K1: count + all weight preps (fused) ----------
__global__ __launch_bounds__(256)
void count_prep_kernel(const int* __restrict__ dst, int* __restrict__ cnt, int E, int egrid,
                       const float* __restrict__ g0W, unsigned short* __restrict__ Wt0,
                       const float* __restrict__ g1W, unsigned short* __restrict__ Wt1,
                       const float* __restrict__ ew0, unsigned short* __restrict__ ewt0,
                       const float* __restrict__ ew1, unsigned short* __restrict__ ewt1,
                       const float* __restrict__ g0We, const float* __restrict__ g0ae,
                       float* __restrict__ M0,
                       const float* __restrict__ g1We, const float* __restrict__ g1ae,
                       float* __restrict__ M1) {
  int b = blockIdx.x, t = threadIdx.x;
  if (b < egrid) {
    int e = b * 256 + t;
    if (e < E) atomicAdd(&cnt[dst[e]], 1);
    return;
  }
  int pb = b - egrid;
  if (pb < 128) {                      // Wt[n][k] = bf16(W[k][n])
    const float* W = pb < 64 ? g0W : g1W;
    unsigned short* Wt = pb < 64 ? Wt0 : Wt1;
    int id = (pb & 63) * 256 + t;
    int nn = id >> 7, k = id & 127;
    Wt[id] = f2b(W[k * D + nn]);
  } else if (pb < 144) {               // permuted ewt
    const float* ew = pb < 136 ? ew0 : ew1;
    unsigned short* ewt = pb < 136 ? ewt0 : ewt1;
    int id = ((pb - 128) & 7) * 256 + t;
    if (id < HD * ED) {
      int i = id >> 6, k = id & 63;
      int ch = (i < 16) ? ((i >> 2) * 8 + (i & 3))
                        : (((i - 16) >> 2) * 8 + 4 + ((i - 16) & 3));
      ewt[id] = f2b(ew[k * HD + ch]);
    }
  } else if (pb == 144) {              // M0 [32][4]
    if (t < HD * 4) {
      int d = t >> 2, h = t & 3;
      float s = 0.f;
      for (int c = 0; c < 32; ++c) s += g0We[d * D + h * 32 + c] * g0ae[h * 32 + c];
      M0[t] = s;
    }
  } else {                             // M1 [32]
    if (t < HD) {
      float s = 0.f;
      for (int c = 0; c < D; ++c) s += g1We[t * D + c] * g1ae[c];
      M1[t] = s;
    }
  }
}

// ---------- hierarchical scan (coalesced, parallel) ----------
__global__ __launch_bounds__(256)
void scan_a_kernel(const int* __restrict__ cnt, int* __restrict__ bsum, int n) {
  __shared__ int sh[256];
  int t = threadIdx.x;
  int i = blockIdx.x * 256 + t;
  sh[t] = (i < n) ? cnt[i] : 0;
  __syncthreads();
  for (int off = 128; off >= 1; off >>= 1) {
    if (t < off) sh[t] += sh[t + off];
    __syncthreads();
  }
  if (t == 0) bsum[blockIdx.x] = sh[0];
}

__global__ __launch_bounds__(256)
void scan_b_kernel(const int* __restrict__ bsum, int* __restrict__ boff, int nb,
                   int* __restrict__ rowptr_n, int E) {
  __shared__ int sh[256];
  int t = threadIdx.x;
  int v = (t < nb) ? bsum[t] : 0;
  sh[t] = v;
  __syncthreads();
  for (int off = 1; off < 256; off <<= 1) {
    int add = (t >= off) ? sh[t - off] : 0;
    __syncthreads();
    sh[t] += add;
    __syncthreads();
  }
  if (t < nb) boff[t] = sh[t] - v;   // exclusive
  if (t == 0) *rowptr_n = E;
}

__global__ __launch_bounds__(256)
void scan_c_kernel(const int* __restrict__ cnt, const int* __restrict__ boff,
                   int* __restrict__ rowptr, int n) {
  __shared__ int sh[256];
  int t = threadIdx.x;
  int i = blockIdx.x * 256 + t;
  int v = (i < n) ? cnt[i] : 0;
  sh[t] = v;
  __syncthreads();
  for (int off = 1; off < 256; off <<= 1) {
    int add = (t >= off) ? sh[t - off] : 0;
    __syncthreads();
    sh[t] += add;
    __syncthreads();
  }
  if (i < n) rowptr[i] = boff[blockIdx.x] + sh[t] - v;  // exclusive prefix
}

// ---------- node GEMM + attention-logit epilogue (device body) ----------
template<int H>
static __device__ void gemm_body(int gblk, int tid,
                                 const float* __restrict__ x,
                                 const unsigned short* __restrict__ Wt,
                                 const float* __restrict__ a_s, const float* __restrict__ a_d,
                                 const float* __restrict__ ow, const float* __restrict__ ob,
                                 unsigned short* __restrict__ xs, float* __restrict__ al_src,
                                 float* __restrict__ al_dst, float* __restrict__ escore,
                                 float2* __restrict__ als1, int n) {
  int wave = tid >> 6;
  int lane = tid & 63;
  int q = lane >> 4;
  int l16 = lane & 15;
  int base = gblk * 64 + wave * 16;
  int rowRaw = base + l16;
  int row = rowRaw < n ? rowRaw : n - 1;
  const float* xrow = x + (size_t)row * D;
  s16x8 a[4];
  float scp = 0.f;
#pragma unroll
  for (int kk = 0; kk < 4; ++kk) {
    int kb = kk * 32 + q * 8;
    float4 v0 = *(const float4*)(xrow + kb);
    float4 v1 = *(const float4*)(xrow + kb + 4);
    float4 o0 = *(const float4*)(ow + kb);
    float4 o1 = *(const float4*)(ow + kb + 4);
    scp += v0.x * o0.x + v0.y * o0.y + v0.z * o0.z + v0.w * o0.w
         + v1.x * o1.x + v1.y * o1.y + v1.z * o1.z + v1.w * o1.w;
    s16x8 t;
    t[0] = (short)f2b(v0.x); t[1] = (short)f2b(v0.y);
    t[2] = (short)f2b(v0.z); t[3] = (short)f2b(v0.w);
    t[4] = (short)f2b(v1.x); t[5] = (short)f2b(v1.y);
    t[6] = (short)f2b(v1.z); t[7] = (short)f2b(v1.w);
    a[kk] = t;
  }
  scp += __shfl_xor(scp, 16);
  scp += __shfl_xor(scp, 32);
  if (H == 4) {
    if (q == 0 && rowRaw < n) escore[rowRaw] = __expf(scp + ob[0]);
  }

  f32x4 acc[8];
#pragma unroll
  for (int nf = 0; nf < 8; ++nf) { f32x4 z = {0.f, 0.f, 0.f, 0.f}; acc[nf] = z; }
#pragma unroll
  for (int kk = 0; kk < 4; ++kk) {
    int kb = kk * 32 + q * 8;
#pragma unroll
    for (int nf = 0; nf < 8; ++nf) {
      s16x8 b = *(const s16x8*)(Wt + (size_t)(nf * 16 + l16) * D + kb);
      acc[nf] = __builtin_amdgcn_mfma_f32_16x16x32_bf16(a[kk], b, acc[nf], 0, 0, 0);
    }
  }
#pragma unroll
  for (int nf = 0; nf < 8; ++nf) {
#pragma unroll
    for (int r = 0; r < 4; ++r) {
      int rr = base + q * 4 + r;
      if (rr < n) xs[(size_t)rr * D + nf * 16 + l16] = f2b(acc[nf][r]);
    }
  }
  float asv[8], adv[8];
#pragma unroll
  for (int nf = 0; nf < 8; ++nf) { asv[nf] = a_s[nf * 16 + l16]; adv[nf] = a_d[nf * 16 + l16]; }
  if (H == 4) {
    float mys = 0.f, myd = 0.f;
#pragma unroll
    for (int r = 0; r < 4; ++r) {
#pragma unroll
      for (int h = 0; h < 4; ++h) {
        float vs = acc[2 * h][r] * asv[2 * h] + acc[2 * h + 1][r] * asv[2 * h + 1];
        float vd = acc[2 * h][r] * adv[2 * h] + acc[2 * h + 1][r] * adv[2 * h + 1];
        vs += __shfl_xor(vs, 1); vd += __shfl_xor(vd, 1);
        vs += __shfl_xor(vs, 2); vd += __shfl_xor(vd, 2);
        vs += __shfl_xor(vs, 4); vd += __shfl_xor(vd, 4);
        vs += __shfl_xor(vs, 8); vd += __shfl_xor(vd, 8);
        if (l16 == r * 4 + h) { mys = vs; myd = vd; }
      }
    }
    int orow = base + q * 4 + (l16 >> 2);
    if (orow < n) {
      al_src[(size_t)orow * 4 + (l16 & 3)] = mys;
      al_dst[(size_t)orow * 4 + (l16 & 3)] = myd;
    }
  } else {
    float mys = 0.f, myd = 0.f;
#pragma unroll
    for (int r = 0; r < 4; ++r) {
      float vs = 0.f, vd = 0.f;
#pragma unroll
      for (int nf = 0; nf < 8; ++nf) { vs = fmaf(acc[nf][r], asv[nf], vs); vd = fmaf(acc[nf][r], adv[nf], vd); }
      vs += __shfl_xor(vs, 1); vd += __shfl_xor(vd, 1);
      vs += __shfl_xor(vs, 2); vd += __shfl_xor(vd, 2);
      vs += __shfl_xor(vs, 4); vd += __shfl_xor(vd, 4);
      vs += __shfl_xor(vs, 8); vd += __shfl_xor(vd, 8);
      if (l16 == r) { mys = vs; myd = vd; }
    }
    float scr = __shfl(scp, q * 4 + l16);
    int orow = base + q * 4 + l16;
    if (l16 < 4 && orow < n) {
      al_dst[orow] = myd;
      als1[orow] = make_float2(mys, __expf(scr + ob[0]));
    }
  }
}

// ---------- K3: fill + gemm0 (fused, independent halves) ----------
__global__ __launch_bounds__(256)
void fill_gemm_kernel(const int* __restrict__ src, const int* __restrict__ dst,
                      const int* __restrict__ rowptr, int* __restrict__ cursor,
                      int2* __restrict__ slotmap, int E, int fgrid,
                      const float* __restrict__ x, const unsigned short* __restrict__ Wt0,
                      const float* __restrict__ g0as, const float* __restrict__ g0ad,
                      const float* __restrict__ ow0, const float* __restrict__ ob0,
                      unsigned short* __restrict__ xs, float* __restrict__ al_src,
                      float* __restrict__ al_dst, float* __restrict__ escore, int n) {
  if ((int)blockIdx.x < fgrid) {
    int e = blockIdx.x * 256 + threadIdx.x;
    if (e < E) {
      int d = dst[e];
      int p = atomicAdd(&cursor[d], 1);
      slotmap[rowptr[d] + p] = make_int2(e, src[e]);   // one 8B store per edge
    }
  } else {
    gemm_body<4>(blockIdx.x - fgrid, threadIdx.x, x, Wt0, g0as, g0ad, ow0, ob0,
                 xs, al_src, al_dst, escore, nullptr, n);
  }
}

__global__ __launch_bounds__(256)
void gemm1_kernel(const float* __restrict__ x, const unsigned short* __restrict__ Wt,
                  const float* __restrict__ a_s, const float* __restrict__ a_d,
                  const float* __restrict__ ow, const float* __restrict__ ob,
                  unsigned short* __restrict__ xs, float* __restrict__ al_dst,
                  float2* __restrict__ als1, int n) {
  gemm_body<1>(blockIdx.x, threadIdx.x, x, Wt, a_s, a_d, ow, ob,
               xs, nullptr, al_dst, nullptr, als1, n);
}

// ---------- K4: edge pass in CSR order (gathers ea rows, streams outputs) ----------
__global__ __launch_bounds__(256)
void edge_csr_kernel(const int2* __restrict__ slotmap,
                     const float* __restrict__ ea,
                     const unsigned short* __restrict__ ewt0p,
                     const unsigned short* __restrict__ ewt1p,
                     const float* __restrict__ eb0, const float* __restrict__ eb1,
                     const float* __restrict__ M0, const float* __restrict__ M1,
                     const float* __restrict__ escore0,
                     float* __restrict__ alef0,     // [E][4] CSR order, escore-premultiplied
                     float* __restrict__ ale1raw,   // [E]   CSR order, raw
                     int E) {
  int wave = threadIdx.x >> 6, lane = threadIdx.x & 63;
  int q = lane >> 4, l16 = lane & 15;
  int ebase = (blockIdx.x * 4 + wave) * 64;
  if (ebase >= E) return;
  s16x8 a0l0 = *(const s16x8*)(ewt0p + l16 * 64 + q * 8);
  s16x8 a0l1 = *(const s16x8*)(ewt0p + l16 * 64 + 32 + q * 8);
  s16x8 a0h0 = *(const s16x8*)(ewt0p + (16 + l16) * 64 + q * 8);
  s16x8 a0h1 = *(const s16x8*)(ewt0p + (16 + l16) * 64 + 32 + q * 8);
  s16x8 a1l0 = *(const s16x8*)(ewt1p + l16 * 64 + q * 8);
  s16x8 a1l1 = *(const s16x8*)(ewt1p + l16 * 64 + 32 + q * 8);
  s16x8 a1h0 = *(const s16x8*)(ewt1p + (16 + l16) * 64 + q * 8);
  s16x8 a1h1 = *(const s16x8*)(ewt1p + (16 + l16) * 64 + 32 + q * 8);
  float4 b0lo = *(const float4*)(eb0 + q * 8);
  float4 b0hi = *(const float4*)(eb0 + q * 8 + 4);
  float4 b1lo = *(const float4*)(eb1 + q * 8);
  float4 b1hi = *(const float4*)(eb1 + q * 8 + 4);
  s16x8 mf0, mf1;
#pragma unroll
  for (int j = 0; j < 8; ++j) {
    mf0[j] = (l16 < 4) ? (short)f2b(M0[(q * 8 + j) * 4 + l16]) : (short)0;
    mf1[j] = (l16 == 0) ? (short)f2b(M1[q * 8 + j]) : (short)0;
  }
  int el = ebase + lane;
  int elc = el < E ? el : E - 1;
  int2 sm = slotmap[elc];
  int eo = sm.x;                           // original edge id for my CSR slot
  float esc = escore0[sm.y];               // escore of my slot's src

#pragma unroll
  for (int st = 0; st < 4; ++st) {
    int slot16 = st * 16 + l16;
    int e16 = ebase + slot16;
    int row = __shfl(eo, slot16);
    const float* er = ea + (size_t)row * ED;
    float4 u0 = *(const float4*)(er + q * 8);
    float4 u1 = *(const float4*)(er + q * 8 + 4);
    float4 u2 = *(const float4*)(er + 32 + q * 8);
    float4 u3 = *(const float4*)(er + 32 + q * 8 + 4);
    s16x8 bk0, bk1;
    bk0[0] = (short)f2b(u0.x); bk0[1] = (short)f2b(u0.y);
    bk0[2] = (short)f2b(u0.z); bk0[3] = (short)f2b(u0.w);
    bk0[4] = (short)f2b(u1.x); bk0[5] = (short)f2b(u1.y);
    bk0[6] = (short)f2b(u1.z); bk0[7] = (short)f2b(u1.w);
    bk1[0] = (short)f2b(u2.x); bk1[1] = (short)f2b(u2.y);
    bk1[2] = (short)f2b(u2.z); bk1[3] = (short)f2b(u2.w);
    bk1[4] = (short)f2b(u3.x); bk1[5] = (short)f2b(u3.y);
    bk1[6] = (short)f2b(u3.z); bk1[7] = (short)f2b(u3.w);
    f32x4 zl0 = {0.f,0.f,0.f,0.f}, zh0 = {0.f,0.f,0.f,0.f};
    f32x4 zl1 = {0.f,0.f,0.f,0.f}, zh1 = {0.f,0.f,0.f,0.f};
    zl0 = __builtin_amdgcn_mfma_f32_16x16x32_bf16(a0l0, bk0, zl0, 0, 0, 0);
    zl0 = __builtin_amdgcn_mfma_f32_16x16x32_bf16(a0l1, bk1, zl0, 0, 0, 0);
    zh0 = __builtin_amdgcn_mfma_f32_16x16x32_bf16(a0h0, bk0, zh0, 0, 0, 0);
    zh0 = __builtin_amdgcn_mfma_f32_16x16x32_bf16(a0h1, bk1, zh0, 0, 0, 0);
    zl1 = __builtin_amdgcn_mfma_f32_16x16x32_bf16(a1l0, bk0, zl1, 0, 0, 0);
    zl1 = __builtin_amdgcn_mfma_f32_16x16x32_bf16(a1l1, bk1, zl1, 0, 0, 0);
    zh1 = __builtin_amdgcn_mfma_f32_16x16x32_bf16(a1h0, bk0, zh1, 0, 0, 0);
    zh1 = __builtin_amdgcn_mfma_f32_16x16x32_bf16(a1h1, bk1, zh1, 0, 0, 0);
    s16x8 zb0, zb1;
    zb0[0] = (short)f2b(fmaxf(zl0[0] + b0lo.x, 0.f));
    zb0[1] = (short)f2b(fmaxf(zl0[1] + b0lo.y, 0.f));
    zb0[2] = (short)f2b(fmaxf(zl0[2] + b0lo.z, 0.f));
    zb0[3] = (short)f2b(fmaxf(zl0[3] + b0lo.w, 0.f));
    zb0[4] = (short)f2b(fmaxf(zh0[0] + b0hi.x, 0.f));
    zb0[5] = (short)f2b(fmaxf(zh0[1] + b0hi.y, 0.f));
    zb0[6] = (short)f2b(fmaxf(zh0[2] + b0hi.z, 0.f));
    zb0[7] = (short)f2b(fmaxf(zh0[3] + b0hi.w, 0.f));
    zb1[0] = (short)f2b(fmaxf(zl1[0] + b1lo.x, 0.f));
    zb1[1] = (short)f2b(fmaxf(zl1[1] + b1lo.y, 0.f));
    zb1[2] = (short)f2b(fmaxf(zl1[2] + b1lo.z, 0.f));
    zb1[3] = (short)f2b(fmaxf(zl1[3] + b1lo.w, 0.f));
    zb1[4] = (short)f2b(fmaxf(zh1[0] + b1hi.x, 0.f));
    zb1[5] = (short)f2b(fmaxf(zh1[1] + b1hi.y, 0.f));
    zb1[6] = (short)f2b(fmaxf(zh1[2] + b1hi.z, 0.f));
    zb1[7] = (short)f2b(fmaxf(zh1[3] + b1hi.w, 0.f));
    f32x4 r0 = {0.f,0.f,0.f,0.f}, r1 = {0.f,0.f,0.f,0.f};
    r0 = __builtin_amdgcn_mfma_f32_16x16x32_bf16(mf0, zb0, r0, 0, 0, 0);
    r1 = __builtin_amdgcn_mfma_f32_16x16x32_bf16(mf1, zb1, r1, 0, 0, 0);
    float esc_e = __shfl(esc, slot16);
    if (q == 0 && e16 < E) {
      *(float4*)(alef0 + (size_t)e16 * 4) =
          make_float4(r0[0] * esc_e, r0[1] * esc_e, r0[2] * esc_e, r0[3] * esc_e);
      ale1raw[e16] = r1[0];
    }
  }
}

// ---------- CSR aggregation: half-wave per edge (8 gathers in flight) ----------
template<int H, bool RELU, bool ADD_ORIG>
__global__ __launch_bounds__(256)
void agg_kernel(const int* __restrict__ rowptr, const int2* __restrict__ slotmap,
                const unsigned short* __restrict__ xs, const float* __restrict__ alef,
                const float* __restrict__ al_src, const float* __restrict__ al_dst,
                const float2* __restrict__ als1,
                const float* __restrict__ bias, const float* __restrict__ xin,
                const float* __restrict__ orig, float* __restrict__ out, int n) {
  int wid = blockIdx.x * 4 + (threadIdx.x >> 6);
  int lane = threadIdx.x & 63;
  if (wid >= n) return;
  int half = lane >> 5;
  int l32 = lane & 31;
  int h0 = (H == 4) ? (l32 >> 3) : 0;   // lane covers channels 4*l32..4*l32+3
  const ushort4* xs4 = (const ushort4*)xs;
  float adst = al_dst[(size_t)wid * H + h0];
  float ax0 = 0.f, ax1 = 0.f, ax2 = 0.f, ax3 = 0.f, den = 0.f, sale = 0.f;
  int b = rowptr[wid], e = rowptr[wid + 1];
  int m = e - b;

#define EDGE_ACC(I_)                                                     \
  {                                                                      \
    int s_ = slotmap[I_].y;                                              \
    float al_, ev_;                                                      \
    if (H == 4) {                                                        \
      al_ = alef[(size_t)(I_) * 4 + h0];                                 \
      float aa_ = al_src[(size_t)s_ * 4 + h0] + adst + al_;              \
      ev_ = __expf(aa_ > 0.f ? aa_ : 0.2f * aa_);                        \
    } else {                                                             \
      float2 ae_ = als1[s_];                                             \
      al_ = alef[I_] * ae_.y;                                            \
      float aa_ = ae_.x + adst + al_;                                    \
      ev_ = __expf(aa_ > 0.f ? aa_ : 0.2f * aa_);                        \
    }                                                                    \
    ushort4 u_ = xs4[(size_t)s_ * 32 + l32];                             \
    ax0 = fmaf(ev_, b2f(u_.x), ax0); ax1 = fmaf(ev_, b2f(u_.y), ax1);    \
    ax2 = fmaf(ev_, b2f(u_.z), ax2); ax3 = fmaf(ev_, b2f(u_.w), ax3);    \
    den += ev_; sale += al_;                                             \
  }

  int k = 0;
  for (; k + 8 <= m; k += 8) {
    int i0 = b + k + half;
    EDGE_ACC(i0)
    EDGE_ACC(i0 + 2)
    EDGE_ACC(i0 + 4)
    EDGE_ACC(i0 + 6)
  }
  for (int idx = b + k + half; idx < e; idx += 2) EDGE_ACC(idx)
#undef EDGE_ACC

  // cross-half combine (partner lane has same l32/h0)
  ax0 += __shfl_xor(ax0, 32); ax1 += __shfl_xor(ax1, 32);
  ax2 += __shfl_xor(ax2, 32); ax3 += __shfl_xor(ax3, 32);
  den += __shfl_xor(den, 32); sale += __shfl_xor(sale, 32);

  // self-loop: attr = mean of incoming alef (linear in attr)
  float la = sale / (float)(m > 1 ? m : 1);
  float asrc_w = (H == 4) ? al_src[(size_t)wid * 4 + h0] : als1[wid].x;
  float a = asrc_w + adst + la;
  float lr = a > 0.f ? a : 0.2f * a;
  float evl = __expf(lr);
  ushort4 us = xs4[(size_t)wid * 32 + l32];
  ax0 = fmaf(evl, b2f(us.x), ax0); ax1 = fmaf(evl, b2f(us.y), ax1);
  ax2 = fmaf(evl, b2f(us.z), ax2); ax3 = fmaf(evl, b2f(us.w), ax3);
  float dinv = 1.f / (den + evl + 1e-16f);
  if (half == 0) {
    float4 bi = ((const float4*)bias)[l32];
    float4 xi = ((const float4*)xin)[(size_t)wid * 32 + l32];
    float4 o;
    o.x = ax0 * dinv + bi.x + xi.x;
    o.y = ax1 * dinv + bi.y + xi.y;
    o.z = ax2 * dinv + bi.z + xi.z;
    o.w = ax3 * dinv + bi.w + xi.w;
    if (ADD_ORIG) {
      float4 og = ((const float4*)orig)[(size_t)wid * 32 + l32];
      o.x += og.x; o.y += og.y; o.z += og.z; o.w += og.w;
    }
    if (RELU) {
      o.x = fmaxf(o.x, 0.f); o.y = fmaxf(o.y, 0.f);
      o.z = fmaxf(o.z, 0.f); o.w = fmaxf(o.w, 0.f);
    }
    ((float4*)out)[(size_t)wid * 32 + l32] = o;
  }
}

extern "C" void kernel_launch(void* const* d_in, const int* in_sizes, int n_in,
                              void* d_out, int out_size, void* d_ws, size_t ws_size,
                              hipStream_t stream) {
  const float* x   = (const float*)d_in[0];
  const int*   ei  = (const int*)d_in[1];
  const float* ea  = (const float*)d_in[2];
  const float* ew0 = (const float*)d_in[3];
  const float* eb0 = (const float*)d_in[4];
  const float* ew1 = (const float*)d_in[5];
  const float* eb1 = (const float*)d_in[6];
  const float* ow0 = (const float*)d_in[7];
  const float* ob0 = (const float*)d_in[8];
  const float* ow1 = (const float*)d_in[9];
  const float* ob1 = (const float*)d_in[10];
  const float* g0W = (const float*)d_in[11];
  const float* g0as= (const float*)d_in[12];
  const float* g0ad= (const float*)d_in[13];
  const float* g0We= (const float*)d_in[14];
  const float* g0ae= (const float*)d_in[15];
  const float* g0b = (const float*)d_in[16];
  const float* g1W = (const float*)d_in[17];
  const float* g1as= (const float*)d_in[18];
  const float* g1ad= (const float*)d_in[19];
  const float* g1We= (const float*)d_in[20];
  const float* g1ae= (const float*)d_in[21];
  const float* g1b = (const float*)d_in[22];
  float* out = (float*)d_out;

  const int N = in_sizes[0] / D;
  const int E = in_sizes[1] / 2;
  const int* srcp = ei;
  const int* dstp = ei + E;

  char* w = (char*)d_ws;
  size_t off = 0;
  auto alloc = [&](size_t bytes) {
    void* p = w + off;
    off += (bytes + 255) & ~(size_t)255;
    return p;
  };
  size_t Nb = ((size_t)N * 4 + 255) & ~(size_t)255;
  int*   cnt     = (int*)alloc(2 * Nb);          // cnt + cursor contiguous (one memset)
  int*   cursor  = (int*)((char*)cnt + Nb);
  unsigned short* xs = (unsigned short*)alloc((size_t)N * D * 2);
  float* alef0   = (float*)alloc((size_t)E * 4 * 4);
  float* ale1raw = (float*)alloc((size_t)E * 4);
  float* al_src  = (float*)alloc((size_t)N * 4 * 4);
  float* al_dst  = (float*)alloc((size_t)N * 4 * 4);
  float* escore  = (float*)alloc((size_t)N * 4);
  float2* als1   = (float2*)alloc((size_t)N * 8);
  float* M0      = (float*)alloc(HD * 4 * 4);
  float* M1      = (float*)alloc(HD * 4);
  unsigned short* Wt0 = (unsigned short*)alloc((size_t)D * D * 2);
  unsigned short* Wt1 = (unsigned short*)alloc((size_t)D * D * 2);
  unsigned short* ewt0 = (unsigned short*)alloc((size_t)HD * ED * 2);
  unsigned short* ewt1 = (unsigned short*)alloc((size_t)HD * ED * 2);
  int*   rowptr  = (int*)alloc((size_t)(N + 1) * 4);
  int2*  slotmap = (int2*)alloc((size_t)E * 8);
  int*   bsum    = (int*)alloc(1024);
  int*   boff    = (int*)alloc(1024);

  int egrid  = (E + 255) / 256;
  int ngrid4 = (N + 3) / 4;
  int ggrid  = (N + 63) / 64;
  int nsb    = (N + 255) / 256;

  hipMemsetAsync(cnt, 0, 2 * Nb, stream);
  count_prep_kernel<<<egrid + 146, 256, 0, stream>>>(dstp, cnt, E, egrid,
                                                     g0W, Wt0, g1W, Wt1,
                                                     ew0, ewt0, ew1, ewt1,
                                                     g0We, g0ae, M0, g1We, g1ae, M1);
  scan_a_kernel<<<nsb, 256, 0, stream>>>(cnt, bsum, N);
  scan_b_kernel<<<1, 256, 0, stream>>>(bsum, boff, nsb, rowptr + N, E);
  scan_c_kernel<<<nsb, 256, 0, stream>>>(cnt, boff, rowptr, N);
  fill_gemm_kernel<<<egrid + ggrid, 256, 0, stream>>>(srcp, dstp, rowptr, cursor,
                                                      slotmap, E, egrid,
                                                      x, Wt0, g0as, g0ad, ow0, ob0,
                                                      xs, al_src, al_dst, escore, N);
  edge_csr_kernel<<<egrid, 256, 0, stream>>>(slotmap, ea, ewt0, ewt1,
                                             eb0, eb1, M0, M1, escore,
                                             alef0, ale1raw, E);
  agg_kernel<4, true, false><<<ngrid4, 256, 0, stream>>>(rowptr, slotmap,
                                                         xs, alef0,
                                                         al_src, al_dst, nullptr,
                                                         g0b, x, nullptr, out, N);
  gemm1_kernel<<<ggrid, 256, 0, stream>>>(out, Wt1, g1as, g1ad, ow1, ob1,
                                          xs, al_dst, als1, N);
  agg_kernel<1, false, true><<<ngrid4, 256, 0, stream>>>(rowptr, slotmap,
                                                         xs, ale1raw,
                                                         nullptr, al_dst, als1,
                                                         g1b, out, x, out, N);
}